// Round 4
// baseline (399.293 us; speedup 1.0000x reference)
//
#include <hip/hip_runtime.h>
#include <math.h>

#define NN 20000
#define NE 256000
#define IN_DIM 64
#define HID 128
#define DE 289     // 2*HID + 1 + 32
#define D0 320     // IN_DIM + 2*HID
#define TILE_E 64
#define NB64 313   // ceil(NN/64)
#define NPW 4      // nodes per wave (edge_agg)
#define SRCMASK 0x3FFFFFFF

typedef unsigned short u16;
typedef unsigned int u32;
typedef unsigned long long u64;
typedef __attribute__((ext_vector_type(8))) short short8;
typedef __attribute__((ext_vector_type(4))) float float4v;

// Bpack layout offsets (u16 elements)
#define OFF_WE   0          // 3 x 40960 (K=289 pad 320, N=128) — tiles 0..3 = We rows 0..255
#define OFF_W0   122880     // 40960 (K=320, N=128)
#define OFF_W1   163840     // 16384 (K=128, N=128)
#define OFF_W2   180224     // 16384
#define OFF_WH   196608     // 3 x 32768 (K=256, N=128)
#define OFF_H2I  294912     // 8192 (K=128, N=64)
#define PACK_TOT 303104

static __device__ __forceinline__ u16 f2bf(float f) {
    unsigned int u = __float_as_uint(f);
    u += 0x7fffu + ((u >> 16) & 1u);
    return (u16)(u >> 16);
}
static __device__ __forceinline__ float bf2f(u16 s) {
    return __uint_as_float(((unsigned int)s) << 16);
}
static __device__ __forceinline__ float bflo(u32 u) { return bf2f((u16)(u & 0xffffu)); }
static __device__ __forceinline__ float bfhi(u32 u) { return bf2f((u16)(u >> 16)); }
static __device__ __forceinline__ u32 pack2(float a, float b) {
    return (u32)f2bf(a) | ((u32)f2bf(b) << 16);
}
static __device__ __forceinline__ uint4 pack8(const float* v) {
    uint4 r;
    r.x = (u32)f2bf(v[0]) | ((u32)f2bf(v[1]) << 16);
    r.y = (u32)f2bf(v[2]) | ((u32)f2bf(v[3]) << 16);
    r.z = (u32)f2bf(v[4]) | ((u32)f2bf(v[5]) << 16);
    r.w = (u32)f2bf(v[6]) | ((u32)f2bf(v[7]) << 16);
    return r;
}
static __device__ __forceinline__ float silu(float v) {
    return v * (1.f / (1.f + __expf(-v)));
}
static __device__ __forceinline__ float rdlane_f(float v, int j) {
    return __int_as_float(__builtin_amdgcn_readlane(__float_as_int(v), j));
}

// ================= CSR build =================
__global__ __launch_bounds__(256) void hist_kernel(
    const float* __restrict__ X_t, const int* __restrict__ edges,
    float* __restrict__ x, int* __restrict__ deg)
{
    int gid = blockIdx.x * blockDim.x + threadIdx.x;
    int stride = gridDim.x * blockDim.x;
    for (int i = gid; i < NN * 3; i += stride) x[i] = X_t[i];
    for (int e = gid; e < NE; e += stride)
        atomicAdd(&deg[edges[NE + e]], 1);
}

__global__ __launch_bounds__(1024) void scan_kernel(
    const int* __restrict__ deg, int* __restrict__ row_start, int* __restrict__ head)
{
    __shared__ int s[1024];
    int tx = threadIdx.x;
    const int per = (NN + 1023) / 1024;
    int st = tx * per, en = st + per;
    if (st > NN) st = NN;
    if (en > NN) en = NN;
    int sum = 0;
    for (int i = st; i < en; ++i) sum += deg[i];
    s[tx] = sum;
    __syncthreads();
    for (int off = 1; off < 1024; off <<= 1) {
        int t = (tx >= off) ? s[tx - off] : 0;
        __syncthreads();
        s[tx] += t;
        __syncthreads();
    }
    int run = (tx == 0) ? 0 : s[tx - 1];
    for (int i = st; i < en; ++i) {
        row_start[i] = run; head[i] = run; run += deg[i];
    }
    if (tx == 1023) row_start[NN] = run;
}

// permute edges into dst-sorted order; pack etype into src bit 30
__global__ __launch_bounds__(256) void scatter_kernel(
    const int* __restrict__ edges, const int* __restrict__ etype,
    int* __restrict__ head,
    int* __restrict__ src_s)
{
    int gid = blockIdx.x * blockDim.x + threadIdx.x;
    int stride = gridDim.x * blockDim.x;
    for (int e = gid; e < NE; e += stride) {
        int d = edges[NE + e];
        int p = atomicAdd(&head[d], 1);
        src_s[p] = edges[e] | (etype[e] << 30);
    }
}

// ================= weight frag-order packing =================
__global__ __launch_bounds__(256) void pack_all_kernel(
    const float* __restrict__ We, const float* __restrict__ W0,
    const float* __restrict__ W1, const float* __restrict__ W2,
    const float* __restrict__ Wh, const float* __restrict__ h2i,
    u16* __restrict__ Bp)
{
    int idx = blockIdx.x * 256 + threadIdx.x;
    if (idx >= PACK_TOT) return;
    const float* src; int N = 128, Ksrc; int r;
    if (idx < OFF_W0) {
        int layer = idx / 40960; r = idx - layer * 40960;
        src = We + (size_t)layer * DE * HID; Ksrc = DE;
    } else if (idx < OFF_W1) { r = idx - OFF_W0; src = W0; Ksrc = 320; }
    else if (idx < OFF_W2)   { r = idx - OFF_W1; src = W1; Ksrc = 128; }
    else if (idx < OFF_WH)   { r = idx - OFF_W2; src = W2; Ksrc = 128; }
    else if (idx < OFF_H2I) {
        int t = idx - OFF_WH; int layer = t / 32768; r = t - layer * 32768;
        src = Wh + (size_t)layer * 256 * HID; Ksrc = 256;
    } else { r = idx - OFF_H2I; src = h2i; Ksrc = 128; N = 64; }
    int ntc = N / 16;
    int j = r & 7, lane = (r >> 3) & 63;
    int rem = r >> 9;
    int nt = rem % ntc, ks = rem / ntc;
    int k = ks * 32 + ((lane >> 4) << 3) + j;
    int c = nt * 16 + (lane & 15);
    Bp[idx] = f2bf((k < Ksrc) ? src[(size_t)k * N + c] : 0.f);
}

// ================= edge tail precompute (f32) =================
__global__ __launch_bounds__(256) void precomp_tv_kernel(
    const float* __restrict__ edge_table, const float* __restrict__ We,
    const float* __restrict__ be, float* __restrict__ tv, float* __restrict__ wed2)
{
    int idx = blockIdx.x * 256 + threadIdx.x;
    if (idx < 768) {
        int f = idx & 127, t = (idx >> 7) & 1, l = idx >> 8;
        float acc = be[l * 128 + f];
        const float* W = We + (size_t)l * DE * HID;
        #pragma unroll
        for (int k = 0; k < 32; ++k)
            acc += edge_table[t * 32 + k] * W[(size_t)(257 + k) * HID + f];
        tv[l * 256 + t * 128 + f] = acc;
    } else if (idx < 1152) {
        int r = idx - 768;
        int f = r & 127, l = r >> 7;
        wed2[l * 128 + f] = We[(size_t)l * DE * HID + (size_t)256 * HID + f];
    }
}

// ================= node MLP: MFMA, 64 nodes/block + fused cvec layer-0 =================
// Cbf dst-half gets tv0(layer0) folded in.
__global__ __launch_bounds__(256) void node_mlp_mfma_kernel(
    const float* __restrict__ H_t, const float* __restrict__ cond,
    const float* __restrict__ t_in,
    const u16* __restrict__ W0p, const float* __restrict__ b0,
    const u16* __restrict__ W1p, const float* __restrict__ b1,
    const u16* __restrict__ W2p, const float* __restrict__ b2,
    const u16* __restrict__ WEp, const float* __restrict__ tv0,
    u16* __restrict__ Cbf,
    float* __restrict__ h, u16* __restrict__ h_bf)
{
    __shared__ u16 s_A[64 * 64];
    __shared__ u16 s_B[64 * 128];
    __shared__ u16 s_h[64 * 128];
    __shared__ float s_t[64];

    int tx = threadIdx.x;
    int n0 = blockIdx.x * 64;
    int l = tx & 63, w = tx >> 6;
    int mt_base = (w & 1) * 2, nt_base = (w >> 1) * 4;
    const float cfr = -logf(10000.f) / 63.f;

    if (tx < 64) s_t[tx] = (n0 + tx < NN) ? t_in[n0 + tx] : 0.f;

    float4v acc[2][4];
    #pragma unroll
    for (int mi = 0; mi < 2; ++mi)
        #pragma unroll
        for (int ni = 0; ni < 4; ++ni) acc[mi][ni] = (float4v){0.f,0.f,0.f,0.f};

    for (int t = 0; t < 5; ++t) {
        __syncthreads();
        #pragma unroll
        for (int it = 0; it < 2; ++it) {
            int flat = it * 256 + tx;
            int n = flat >> 3, sl = flat & 7;
            int c = sl ^ (n & 7);
            int k0 = t * 64 + c * 8;
            float tv8[8];
            int gn = n0 + n;
            if (gn < NN) {
                if (k0 < 192) {
                    const float* src = (k0 < 64) ? &H_t[(size_t)gn * IN_DIM + k0]
                                                 : &cond[(size_t)gn * HID + (k0 - 64)];
                    float4 a = *(const float4*)src;
                    float4 b = *(const float4*)(src + 4);
                    tv8[0]=a.x; tv8[1]=a.y; tv8[2]=a.z; tv8[3]=a.w;
                    tv8[4]=b.x; tv8[5]=b.y; tv8[6]=b.z; tv8[7]=b.w;
                } else {
                    float tvv = s_t[n];
                    int jj = (k0 - 192) & 63;
                    bool is_sin = (k0 < 256);
                    #pragma unroll
                    for (int jx = 0; jx < 8; ++jx) {
                        float ang = tvv * __expf(cfr * (float)(jj + jx));
                        tv8[jx] = is_sin ? __sinf(ang) : __cosf(ang);
                    }
                }
            } else {
                #pragma unroll
                for (int jx = 0; jx < 8; ++jx) tv8[jx] = 0.f;
            }
            *(uint4*)&s_A[n * 64 + sl * 8] = pack8(tv8);
        }
        #pragma unroll
        for (int it = 0; it < 4; ++it) {
            int flat = it * 256 + tx;
            ((uint4*)s_B)[flat] = ((const uint4*)(W0p + (size_t)t * 8192))[flat];
        }
        __syncthreads();
        #pragma unroll
        for (int s = 0; s < 2; ++s) {
            short8 af[2], bfv[4];
            #pragma unroll
            for (int mi = 0; mi < 2; ++mi) {
                int m = (mt_base + mi) * 16 + (l & 15);
                int c = s * 4 + (l >> 4);
                int slot = c ^ (l & 7);
                af[mi] = *(const short8*)(s_A + m * 64 + slot * 8);
            }
            #pragma unroll
            for (int ni = 0; ni < 4; ++ni)
                bfv[ni] = *(const short8*)(s_B + ((s * 8 + nt_base + ni) * 64 + l) * 8);
            #pragma unroll
            for (int mi = 0; mi < 2; ++mi)
                #pragma unroll
                for (int ni = 0; ni < 4; ++ni)
                    acc[mi][ni] = __builtin_amdgcn_mfma_f32_16x16x32_bf16(
                        af[mi], bfv[ni], acc[mi][ni], 0, 0, 0);
        }
    }
    #pragma unroll
    for (int mi = 0; mi < 2; ++mi) {
        #pragma unroll
        for (int ni = 0; ni < 4; ++ni) {
            int f = (nt_base + ni) * 16 + (l & 15);
            float bv = b0[f];
            #pragma unroll
            for (int r = 0; r < 4; ++r) {
                int m = (mt_base + mi) * 16 + (l >> 4) * 4 + r;
                float v = fmaxf(acc[mi][ni][r] + bv, 0.f);
                int slot = (f >> 3) ^ (m & 7);
                s_h[m * 128 + slot * 8 + (f & 7)] = f2bf(v);
            }
            acc[mi][ni] = (float4v){0.f,0.f,0.f,0.f};
        }
    }
    for (int t = 0; t < 2; ++t) {
        __syncthreads();
        #pragma unroll
        for (int it = 0; it < 4; ++it) {
            int flat = it * 256 + tx;
            ((uint4*)s_B)[flat] = ((const uint4*)(W1p + (size_t)t * 8192))[flat];
        }
        __syncthreads();
        #pragma unroll
        for (int s = 0; s < 2; ++s) {
            short8 af[2], bfv[4];
            #pragma unroll
            for (int mi = 0; mi < 2; ++mi) {
                int m = (mt_base + mi) * 16 + (l & 15);
                int c = t * 8 + s * 4 + (l >> 4);
                int slot = c ^ (l & 7);
                af[mi] = *(const short8*)(s_h + m * 128 + slot * 8);
            }
            #pragma unroll
            for (int ni = 0; ni < 4; ++ni)
                bfv[ni] = *(const short8*)(s_B + ((s * 8 + nt_base + ni) * 64 + l) * 8);
            #pragma unroll
            for (int mi = 0; mi < 2; ++mi)
                #pragma unroll
                for (int ni = 0; ni < 4; ++ni)
                    acc[mi][ni] = __builtin_amdgcn_mfma_f32_16x16x32_bf16(
                        af[mi], bfv[ni], acc[mi][ni], 0, 0, 0);
        }
    }
    __syncthreads();
    #pragma unroll
    for (int mi = 0; mi < 2; ++mi) {
        #pragma unroll
        for (int ni = 0; ni < 4; ++ni) {
            int f = (nt_base + ni) * 16 + (l & 15);
            float bv = b1[f];
            #pragma unroll
            for (int r = 0; r < 4; ++r) {
                int m = (mt_base + mi) * 16 + (l >> 4) * 4 + r;
                float v = fmaxf(acc[mi][ni][r] + bv, 0.f);
                int slot = (f >> 3) ^ (m & 7);
                s_h[m * 128 + slot * 8 + (f & 7)] = f2bf(v);
            }
            acc[mi][ni] = (float4v){0.f,0.f,0.f,0.f};
        }
    }
    for (int t = 0; t < 2; ++t) {
        __syncthreads();
        #pragma unroll
        for (int it = 0; it < 4; ++it) {
            int flat = it * 256 + tx;
            ((uint4*)s_B)[flat] = ((const uint4*)(W2p + (size_t)t * 8192))[flat];
        }
        __syncthreads();
        #pragma unroll
        for (int s = 0; s < 2; ++s) {
            short8 af[2], bfv[4];
            #pragma unroll
            for (int mi = 0; mi < 2; ++mi) {
                int m = (mt_base + mi) * 16 + (l & 15);
                int c = t * 8 + s * 4 + (l >> 4);
                int slot = c ^ (l & 7);
                af[mi] = *(const short8*)(s_h + m * 128 + slot * 8);
            }
            #pragma unroll
            for (int ni = 0; ni < 4; ++ni)
                bfv[ni] = *(const short8*)(s_B + ((s * 8 + nt_base + ni) * 64 + l) * 8);
            #pragma unroll
            for (int mi = 0; mi < 2; ++mi)
                #pragma unroll
                for (int ni = 0; ni < 4; ++ni)
                    acc[mi][ni] = __builtin_amdgcn_mfma_f32_16x16x32_bf16(
                        af[mi], bfv[ni], acc[mi][ni], 0, 0, 0);
        }
    }
    // final h: write globals AND store into s_h (swizzled) for the fused cvec
    __syncthreads();   // protect s_h against pending W2-stage reads
    #pragma unroll
    for (int mi = 0; mi < 2; ++mi) {
        #pragma unroll
        for (int ni = 0; ni < 4; ++ni) {
            int f = (nt_base + ni) * 16 + (l & 15);
            float bv = b2[f];
            #pragma unroll
            for (int r = 0; r < 4; ++r) {
                int m = (mt_base + mi) * 16 + (l >> 4) * 4 + r;
                int gn = n0 + m;
                float v = acc[mi][ni][r] + bv;
                int slot = (f >> 3) ^ (m & 7);
                s_h[m * 128 + slot * 8 + (f & 7)] = f2bf(v);
                if (gn < NN) {
                    h[(size_t)gn * HID + f] = v;
                    h_bf[(size_t)gn * HID + f] = f2bf(v);
                }
            }
        }
    }

    // ---- fused cvec (layer 0): Cbf[n][0:128]=h@We_src, [128:256]=h@We_dst + tv0 ----
    for (int sd = 0; sd < 2; ++sd) {
        #pragma unroll
        for (int mi = 0; mi < 2; ++mi)
            #pragma unroll
            for (int ni = 0; ni < 4; ++ni) acc[mi][ni] = (float4v){0.f,0.f,0.f,0.f};
        #pragma unroll
        for (int th = 0; th < 2; ++th) {
            int t = sd * 2 + th;
            __syncthreads();
            #pragma unroll
            for (int it = 0; it < 4; ++it) {
                int flat = it * 256 + tx;
                ((uint4*)s_B)[flat] = ((const uint4*)(WEp + (size_t)t * 8192))[flat];
            }
            __syncthreads();
            #pragma unroll
            for (int s = 0; s < 2; ++s) {
                short8 af[2], bfv[4];
                #pragma unroll
                for (int mi = 0; mi < 2; ++mi) {
                    int m = (mt_base + mi) * 16 + (l & 15);
                    int c = th * 8 + s * 4 + (l >> 4);
                    int slot = c ^ (l & 7);
                    af[mi] = *(const short8*)(s_h + m * 128 + slot * 8);
                }
                #pragma unroll
                for (int ni = 0; ni < 4; ++ni)
                    bfv[ni] = *(const short8*)(s_B + ((s * 8 + nt_base + ni) * 64 + l) * 8);
                #pragma unroll
                for (int mi = 0; mi < 2; ++mi)
                    #pragma unroll
                    for (int ni = 0; ni < 4; ++ni)
                        acc[mi][ni] = __builtin_amdgcn_mfma_f32_16x16x32_bf16(
                            af[mi], bfv[ni], acc[mi][ni], 0, 0, 0);
            }
        }
        #pragma unroll
        for (int mi = 0; mi < 2; ++mi) {
            #pragma unroll
            for (int ni = 0; ni < 4; ++ni) {
                int fq = (nt_base + ni) * 16 + (l & 15);
                int f = sd * 128 + fq;
                float tadd = (sd == 1) ? tv0[fq] : 0.f;
                #pragma unroll
                for (int r = 0; r < 4; ++r) {
                    int m = (mt_base + mi) * 16 + (l >> 4) * 4 + r;
                    int gn = n0 + m;
                    if (gn < NN)
                        Cbf[(size_t)gn * 256 + f] = f2bf(acc[mi][ni][r] + tadd);
                }
            }
        }
    }
}

// ================= edge aggregation: barrier-free, 1 wave = NPW nodes =================
// feat-per-lane (64 lanes x 2 feats), broadcasts via v_readlane -> SGPR,
// 4-deep Cbf gather pipeline, continuous edge stream across the wave's nodes,
// agg written to global bf16, x updated per node at flush.
__global__ __launch_bounds__(256) void edge_agg_kernel(
    const float* __restrict__ x_in, float* __restrict__ x_out,
    const u16* __restrict__ Cbf, u16* __restrict__ agg_bf,
    const int* __restrict__ src_s,
    const int* __restrict__ row_start,
    const float* __restrict__ tv_l, const float* __restrict__ wed2_l,
    const float* __restrict__ Wx_l, const float* __restrict__ bx_l)
{
    int tx = threadIdx.x;
    int l = tx & 63;
    int wg = blockIdx.x * 4 + (tx >> 6);   // wave id 0..4999
    int n0w = wg * NPW;

    // per-lane constants (feats 2l, 2l+1)
    float2 wed = *(const float2*)(wed2_l + 2 * l);
    float2 wxv = *(const float2*)(Wx_l + 2 * l);
    float tva0 = tv_l[2 * l],       tva1 = tv_l[2 * l + 1];
    float tvb0 = tv_l[128 + 2 * l], tvb1 = tv_l[128 + 2 * l + 1];
    float d01_0 = tvb0 - tva0, d01_1 = tvb1 - tva1;
    float bx64 = bx_l[0] * (1.f / 64.f);

    int rsv = row_start[n0w + (l < NPW ? l : NPW)];  // lanes 0..NPW hold boundaries
    int rs0w = __builtin_amdgcn_readlane(rsv, 0);
    int reN  = __builtin_amdgcn_readlane(rsv, NPW);
    int b1 = __builtin_amdgcn_readlane(rsv, 1);
    int b2 = __builtin_amdgcn_readlane(rsv, 2);
    int b3 = __builtin_amdgcn_readlane(rsv, 3);

    // cd shift register: Cbf dst-half (incl folded tv0), 2 bf16 per node
    u32 cdA = *(const u32*)(Cbf + (size_t)(n0w + 0) * 256 + 128 + 2 * l);
    u32 cdB = *(const u32*)(Cbf + (size_t)(n0w + 1) * 256 + 128 + 2 * l);
    u32 cdC = *(const u32*)(Cbf + (size_t)(n0w + 2) * 256 + 128 + 2 * l);
    u32 cdD = *(const u32*)(Cbf + (size_t)(n0w + 3) * 256 + 128 + 2 * l);

    int cur = 0;
    int nstart = rs0w;
    int bnext = b1;
    float c0f0 = bflo(cdA), c0f1 = bfhi(cdA);
    float ag0 = 0.f, ag1 = 0.f, sx = 0.f, sy = 0.f, sz = 0.f;

    auto FLUSH = [&]() {
        float rx = sx, ry = sy, rz = sz;
        #pragma unroll
        for (int off = 1; off < 64; off <<= 1) {
            rx += __shfl_xor(rx, off);
            ry += __shfl_xor(ry, off);
            rz += __shfl_xor(rz, off);
        }
        int gn = n0w + cur;
        *(u32*)(agg_bf + (size_t)gn * 128 + 2 * l) = pack2(ag0, ag1);
        if (l == 0) {
            float inv = 1.f / ((float)(bnext - nstart) + 1.f);
            x_out[gn * 3 + 0] = x_in[gn * 3 + 0] + rx * inv;
            x_out[gn * 3 + 1] = x_in[gn * 3 + 1] + ry * inv;
            x_out[gn * 3 + 2] = x_in[gn * 3 + 2] + rz * inv;
        }
        ag0 = 0.f; ag1 = 0.f; sx = 0.f; sy = 0.f; sz = 0.f;
        nstart = bnext;
        cur++;
        cdA = cdB; cdB = cdC; cdC = cdD;
        c0f0 = bflo(cdA); c0f1 = bfhi(cdA);
        if (cur < NPW) bnext = __builtin_amdgcn_readlane(rsv, cur + 1);
    };

    const char* cb = (const char*)Cbf;
    int lx4 = l << 2;

    for (int base = rs0w; base < reN; base += 64) {
        int nch = reN - base; if (nch > 64) nch = 64;
        int voff_l = 0;
        float et_l = 0.f, gx_l = 0.f, gy_l = 0.f, gz_l = 0.f, d2_l = 0.f;
        if (l < nch) {
            int pos_l = base + l;
            int sp = src_s[pos_l];
            int sm = sp & SRCMASK;
            int k = (pos_l >= b1) + (pos_l >= b2) + (pos_l >= b3);
            int dn = n0w + k;
            voff_l = sm * 512;             // byte offset of Cbf row (256 u16)
            et_l = (float)((u32)sp >> 30);
            gx_l = x_in[sm * 3 + 0] - x_in[dn * 3 + 0];
            gy_l = x_in[sm * 3 + 1] - x_in[dn * 3 + 1];
            gz_l = x_in[sm * 3 + 2] - x_in[dn * 3 + 2];
            d2_l = gx_l * gx_l + gy_l * gy_l + gz_l * gz_l;
        }
        auto LD = [&](int t) -> u32 {
            int so = __builtin_amdgcn_readlane(voff_l, t & 63);
            return *(const u32*)(cb + (u32)so + lx4);
        };
        auto BODY = [&](int j, u32 cc) {
            int pos = base + j;
            while (pos == bnext) FLUSH();
            float s_et = rdlane_f(et_l, j);
            float s_dx = rdlane_f(gx_l, j);
            float s_dy = rdlane_f(gy_l, j);
            float s_dz = rdlane_f(gz_l, j);
            float s_d2 = rdlane_f(d2_l, j);
            float av0 = bflo(cc), av1 = bfhi(cc);
            float t0 = __fmaf_rn(s_d2, wed.x, c0f0);
            t0 = __fmaf_rn(s_et, d01_0, t0) + av0;
            float t1 = __fmaf_rn(s_d2, wed.y, c0f1);
            t1 = __fmaf_rn(s_et, d01_1, t1) + av1;
            float m0 = silu(t0), m1 = silu(t1);
            ag0 += m0; ag1 += m1;
            float wpart = __fmaf_rn(m1, wxv.y, __fmaf_rn(m0, wxv.x, bx64));
            sx = __fmaf_rn(s_dx, wpart, sx);
            sy = __fmaf_rn(s_dy, wpart, sy);
            sz = __fmaf_rn(s_dz, wpart, sz);
        };

        u32 cA = LD(0), cB = LD(1), cC = LD(2), cD = LD(3);
        int j = 0;
        while (j < nch) {
            BODY(j, cA); cA = LD(j + 4); if (++j >= nch) break;
            BODY(j, cB); cB = LD(j + 4); if (++j >= nch) break;
            BODY(j, cC); cC = LD(j + 4); if (++j >= nch) break;
            BODY(j, cD); cD = LD(j + 4); ++j;
        }
    }
    // drain remaining nodes (including empty ones)
    while (cur < NPW) FLUSH();
}

// ================= Wh GEMM (64 nodes/block) + fused cvec for next layer =================
__global__ __launch_bounds__(256) void wh_cvec_kernel(
    float* __restrict__ h, u16* __restrict__ h_bf,
    const u16* __restrict__ agg_bf,
    const u16* __restrict__ Whp_l, const float* __restrict__ bh_l,
    const u16* __restrict__ WEp_next, const float* __restrict__ tv_next,
    u16* __restrict__ Cbf, int do_cvec)
{
    __shared__ u16 s_A[64 * 64];
    __shared__ u16 s_B[64 * 128];
    __shared__ u16 s_h[64 * 128];

    int tx = threadIdx.x;
    int n0 = blockIdx.x * 64;
    int l = tx & 63, w = tx >> 6;
    int mt_base = (w & 1) * 2, nt_base = (w >> 1) * 4;

    float4v acc[2][4];
    #pragma unroll
    for (int mi = 0; mi < 2; ++mi)
        #pragma unroll
        for (int ni = 0; ni < 4; ++ni) acc[mi][ni] = (float4v){0.f,0.f,0.f,0.f};

    for (int t = 0; t < 4; ++t) {
        __syncthreads();
        const u16* Asrc = (t < 2) ? h_bf : agg_bf;
        int koff = (t & 1) * 64;
        #pragma unroll
        for (int it = 0; it < 2; ++it) {
            int flat = it * 256 + tx;
            int n = flat >> 3, sl = flat & 7;
            int c = sl ^ (n & 7);
            int gn = n0 + n;
            uint4 v = make_uint4(0, 0, 0, 0);
            if (gn < NN) v = *(const uint4*)(Asrc + (size_t)gn * 128 + koff + c * 8);
            *(uint4*)&s_A[n * 64 + sl * 8] = v;
        }
        #pragma unroll
        for (int it = 0; it < 4; ++it) {
            int flat = it * 256 + tx;
            ((uint4*)s_B)[flat] = ((const uint4*)(Whp_l + (size_t)t * 8192))[flat];
        }
        __syncthreads();
        #pragma unroll
        for (int s = 0; s < 2; ++s) {
            short8 af[2], bfv[4];
            #pragma unroll
            for (int mi = 0; mi < 2; ++mi) {
                int m = (mt_base + mi) * 16 + (l & 15);
                int c = s * 4 + (l >> 4);
                int slot = c ^ (l & 7);
                af[mi] = *(const short8*)(s_A + m * 64 + slot * 8);
            }
            #pragma unroll
            for (int ni = 0; ni < 4; ++ni)
                bfv[ni] = *(const short8*)(s_B + ((s * 8 + nt_base + ni) * 64 + l) * 8);
            #pragma unroll
            for (int mi = 0; mi < 2; ++mi)
                #pragma unroll
                for (int ni = 0; ni < 4; ++ni)
                    acc[mi][ni] = __builtin_amdgcn_mfma_f32_16x16x32_bf16(
                        af[mi], bfv[ni], acc[mi][ni], 0, 0, 0);
        }
    }
    // epilogue: hn = h + silu(acc + bh); write h, h_bf, and s_h (swizzled)
    __syncthreads();
    #pragma unroll
    for (int mi = 0; mi < 2; ++mi) {
        #pragma unroll
        for (int ni = 0; ni < 4; ++ni) {
            int f = (nt_base + ni) * 16 + (l & 15);
            float bv = bh_l[f];
            #pragma unroll
            for (int r = 0; r < 4; ++r) {
                int m = (mt_base + mi) * 16 + (l >> 4) * 4 + r;
                int gn = n0 + m;
                float v = acc[mi][ni][r] + bv;
                float hold = (gn < NN) ? h[(size_t)gn * HID + f] : 0.f;
                float hn = hold + silu(v);
                int slot = (f >> 3) ^ (m & 7);
                s_h[m * 128 + slot * 8 + (f & 7)] = f2bf(hn);
                if (gn < NN) {
                    h[(size_t)gn * HID + f] = hn;
                    h_bf[(size_t)gn * HID + f] = f2bf(hn);
                }
            }
            acc[mi][ni] = (float4v){0.f,0.f,0.f,0.f};
        }
    }
    if (!do_cvec) return;
    // fused cvec: Cbf = hn@We_src | hn@We_dst + tv0(next layer)
    for (int sd = 0; sd < 2; ++sd) {
        if (sd == 1) {
            #pragma unroll
            for (int mi = 0; mi < 2; ++mi)
                #pragma unroll
                for (int ni = 0; ni < 4; ++ni) acc[mi][ni] = (float4v){0.f,0.f,0.f,0.f};
        }
        #pragma unroll
        for (int th = 0; th < 2; ++th) {
            int t = sd * 2 + th;
            __syncthreads();
            #pragma unroll
            for (int it = 0; it < 4; ++it) {
                int flat = it * 256 + tx;
                ((uint4*)s_B)[flat] = ((const uint4*)(WEp_next + (size_t)t * 8192))[flat];
            }
            __syncthreads();
            #pragma unroll
            for (int s = 0; s < 2; ++s) {
                short8 af[2], bfv[4];
                #pragma unroll
                for (int mi = 0; mi < 2; ++mi) {
                    int m = (mt_base + mi) * 16 + (l & 15);
                    int c = th * 8 + s * 4 + (l >> 4);
                    int slot = c ^ (l & 7);
                    af[mi] = *(const short8*)(s_h + m * 128 + slot * 8);
                }
                #pragma unroll
                for (int ni = 0; ni < 4; ++ni)
                    bfv[ni] = *(const short8*)(s_B + ((s * 8 + nt_base + ni) * 64 + l) * 8);
                #pragma unroll
                for (int mi = 0; mi < 2; ++mi)
                    #pragma unroll
                    for (int ni = 0; ni < 4; ++ni)
                        acc[mi][ni] = __builtin_amdgcn_mfma_f32_16x16x32_bf16(
                            af[mi], bfv[ni], acc[mi][ni], 0, 0, 0);
            }
        }
        #pragma unroll
        for (int mi = 0; mi < 2; ++mi) {
            #pragma unroll
            for (int ni = 0; ni < 4; ++ni) {
                int fq = (nt_base + ni) * 16 + (l & 15);
                int f = sd * 128 + fq;
                float tadd = (sd == 1) ? tv_next[fq] : 0.f;
                #pragma unroll
                for (int r = 0; r < 4; ++r) {
                    int m = (mt_base + mi) * 16 + (l >> 4) * 4 + r;
                    int gn = n0 + m;
                    if (gn < NN)
                        Cbf[(size_t)gn * 256 + f] = f2bf(acc[mi][ni][r] + tadd);
                }
            }
        }
    }
}

// ================= final: MFMA h2i, 64 nodes/block =================
__global__ __launch_bounds__(256) void final_mfma_kernel(
    const u16* __restrict__ h_bf, const float* __restrict__ x,
    const int* __restrict__ gmask,
    const u16* __restrict__ h2ip, const float* __restrict__ b,
    float* __restrict__ out)
{
    __shared__ u16 s_A[64 * 128];
    __shared__ u16 s_B[4096];

    int tx = threadIdx.x;
    int n0 = blockIdx.x * 64;
    int l = tx & 63, w = tx >> 6;
    int mt_base = (w & 1) * 2, nt_base = (w >> 1) * 2;

    #pragma unroll
    for (int it = 0; it < 4; ++it) {
        int flat = it * 256 + tx;
        int n = flat >> 4, c = flat & 15;
        int slot = c ^ (n & 7);
        int gn = n0 + n;
        uint4 v = make_uint4(0,0,0,0);
        if (gn < NN) v = *(const uint4*)(h_bf + (size_t)gn * 128 + c * 8);
        *(uint4*)&s_A[n * 128 + slot * 8] = v;
    }

    float4v acc[2][2];
    #pragma unroll
    for (int mi = 0; mi < 2; ++mi)
        #pragma unroll
        for (int ni = 0; ni < 2; ++ni) acc[mi][ni] = (float4v){0.f,0.f,0.f,0.f};

    for (int t = 0; t < 2; ++t) {
        __syncthreads();
        #pragma unroll
        for (int it = 0; it < 2; ++it) {
            int flat = it * 256 + tx;
            ((uint4*)s_B)[flat] = ((const uint4*)(h2ip + (size_t)t * 4096))[flat];
        }
        __syncthreads();
        #pragma unroll
        for (int s = 0; s < 2; ++s) {
            short8 af[2], bfv[2];
            #pragma unroll
            for (int mi = 0; mi < 2; ++mi) {
                int m = (mt_base + mi) * 16 + (l & 15);
                int c = t * 8 + s * 4 + (l >> 4);
                int slot = c ^ (l & 7);
                af[mi] = *(const short8*)(s_A + m * 128 + slot * 8);
            }
            #pragma unroll
            for (int ni = 0; ni < 2; ++ni)
                bfv[ni] = *(const short8*)(s_B + ((s * 4 + nt_base + ni) * 64 + l) * 8);
            #pragma unroll
            for (int mi = 0; mi < 2; ++mi)
                #pragma unroll
                for (int ni = 0; ni < 2; ++ni)
                    acc[mi][ni] = __builtin_amdgcn_mfma_f32_16x16x32_bf16(
                        af[mi], bfv[ni], acc[mi][ni], 0, 0, 0);
        }
    }
    #pragma unroll
    for (int mi = 0; mi < 2; ++mi) {
        #pragma unroll
        for (int ni = 0; ni < 2; ++ni) {
            int f = (nt_base + ni) * 16 + (l & 15);
            float bv = b[f];
            #pragma unroll
            for (int r = 0; r < 4; ++r) {
                int m = (mt_base + mi) * 16 + (l >> 4) * 4 + r;
                int gn = n0 + m;
                if (gn < NN)
                    out[(size_t)gn * IN_DIM + f] = gmask[gn] ? (acc[mi][ni][r] + bv) : 0.f;
            }
        }
    }
    if (tx < 192) {
        int i = tx / 3, c = tx % 3;
        int gn = n0 + i;
        if (gn < NN)
            out[(size_t)NN * IN_DIM + gn * 3 + c] = gmask[gn] ? x[gn * 3 + c] : 0.f;
    }
}

// ================= fallback path (atomic, scalar; used only if ws too small) =================
__global__ __launch_bounds__(256) void init_fb_kernel(
    const float* __restrict__ X_t, const int* __restrict__ edges,
    float* __restrict__ x, float* __restrict__ cnt)
{
    int gid = blockIdx.x * blockDim.x + threadIdx.x;
    int stride = gridDim.x * blockDim.x;
    for (int i = gid; i < NN * 3; i += stride) x[i] = X_t[i];
    for (int e = gid; e < NE; e += stride)
        atomicAdd(&cnt[edges[NE + e]], 1.0f);
}

__global__ __launch_bounds__(128) void node_mlp_kernel(
    const float* __restrict__ H_t, const float* __restrict__ cond,
    const float* __restrict__ t_in,
    const float* __restrict__ W0, const float* __restrict__ b0,
    const float* __restrict__ W1, const float* __restrict__ b1,
    const float* __restrict__ W2, const float* __restrict__ b2,
    float* __restrict__ h)
{
    __shared__ float s_feat[D0][20];
    __shared__ float s_h0[HID][20];
    __shared__ float s_h1[HID][20];
    int n0 = blockIdx.x * 16;
    int tx = threadIdx.x;

    for (int idx = tx; idx < 16 * IN_DIM; idx += 128) {
        int i = idx >> 6, k = idx & 63;
        s_feat[k][i] = H_t[(n0 + i) * IN_DIM + k];
    }
    for (int idx = tx; idx < 16 * HID; idx += 128) {
        int i = idx >> 7, k = idx & 127;
        s_feat[IN_DIM + k][i] = cond[(n0 + i) * HID + k];
    }
    const float cfr = -logf(10000.f) / 63.f;
    for (int idx = tx; idx < 16 * HID; idx += 128) {
        int i = idx >> 7, k = idx & 127;
        float tv = t_in[n0 + i];
        int jj = k & 63;
        float ang = tv * __expf(cfr * (float)jj);
        s_feat[IN_DIM + HID + k][i] = (k < 64) ? __sinf(ang) : __cosf(ang);
    }
    __syncthreads();

    float acc[16];
    {
        float bv = b0[tx];
        #pragma unroll
        for (int i = 0; i < 16; ++i) acc[i] = bv;
        for (int k = 0; k < D0; ++k) {
            float w = W0[k * HID + tx];
            float4 f0 = *(const float4*)&s_feat[k][0];
            float4 f1 = *(const float4*)&s_feat[k][4];
            float4 f2 = *(const float4*)&s_feat[k][8];
            float4 f3 = *(const float4*)&s_feat[k][12];
            acc[0] += f0.x*w; acc[1] += f0.y*w; acc[2] += f0.z*w; acc[3] += f0.w*w;
            acc[4] += f1.x*w; acc[5] += f1.y*w; acc[6] += f1.z*w; acc[7] += f1.w*w;
            acc[8] += f2.x*w; acc[9] += f2.y*w; acc[10]+= f2.z*w; acc[11]+= f2.w*w;
            acc[12]+= f3.x*w; acc[13]+= f3.y*w; acc[14]+= f3.z*w; acc[15]+= f3.w*w;
        }
        #pragma unroll
        for (int i = 0; i < 16; ++i) s_h0[tx][i] = fmaxf(acc[i], 0.f);
    }
    __syncthreads();
    {
        float bv = b1[tx];
        #pragma unroll
        for (int i = 0; i < 16; ++i) acc[i] = bv;
        for (int k = 0; k < HID; ++k) {
            float w = W1[k * HID + tx];
            float4 f0 = *(const float4*)&s_h0[k][0];
            float4 f1 = *(const float4*)&s_h0[k][4];
            float4 f2 = *(const float4*)&s_h0[k][8];
            float4 f3 = *(const float4*)&s_h0[k][12];
            acc[0] += f0.x*w; acc[1] += f0.y*w; acc[2] += f0.z*w; acc[3] += f0.w*w;
            acc[4] += f1.x*w; acc[5] += f1.y*w; acc[6] += f1.z*w; acc[7] += f1.w*w;
            acc[8] += f2.x*w; acc[9] += f2.y*w; acc[10]+= f2.z*w; acc[11]+= f2.w*w;
            acc[12]+= f3.x*w; acc[13]+= f3.y*w; acc[14]+= f3.z*w; acc[15]+= f3.w*w;
        }
        #pragma unroll
        for (int i = 0; i < 16; ++i) s_h1[tx][i] = fmaxf(acc[i], 0.f);
    }
    __syncthreads();
    {
        float bv = b2[tx];
        #pragma unroll
        for (int i = 0; i < 16; ++i) acc[i] = bv;
        for (int k = 0; k < HID; ++k) {
            float w = W2[k * HID + tx];
            float4 f0 = *(const float4*)&s_h1[k][0];
            float4 f1 = *(const float4*)&s_h1[k][4];
            float4 f2 = *(const float4*)&s_h1[k][8];
            float4 f3 = *(const float4*)&s_h1[k][12];
            acc[0] += f0.x*w; acc[1] += f0.y*w; acc[2] += f0.z*w; acc[3] += f0.w*w;
            acc[4] += f1.x*w; acc[5] += f1.y*w; acc[6] += f1.z*w; acc[7] += f1.w*w;
            acc[8] += f2.x*w; acc[9] += f2.y*w; acc[10]+= f2.z*w; acc[11]+= f2.w*w;
            acc[12]+= f3.x*w; acc[13]+= f3.y*w; acc[14]+= f3.z*w; acc[15]+= f3.w*w;
        }
        #pragma unroll
        for (int i = 0; i < 16; ++i) h[(n0 + i) * HID + tx] = acc[i];
    }
}

__global__ __launch_bounds__(256) void edge_gemm_fb_kernel(
    const float* __restrict__ h, const float* __restrict__ x,
    const int* __restrict__ edges, const int* __restrict__ etype,
    const float* __restrict__ edge_table,
    const float* __restrict__ We_l, const float* __restrict__ be_l,
    const float* __restrict__ Wx_l, const float* __restrict__ bx_l,
    float* __restrict__ agg_m, float* __restrict__ agg_x)
{
    __shared__ int s_src[TILE_E], s_dst[TILE_E];
    __shared__ float s_diff[TILE_E][3];
    __shared__ float s_tail[TILE_E][36];
    __shared__ float s_Af[TILE_E][36];
    __shared__ float s_Bf[33][HID];
    __shared__ float s_wx[HID];

    int e0 = blockIdx.x * TILE_E;
    int tx = threadIdx.x;
    int tf = tx & 15;
    int te = tx >> 4;

    if (tx < TILE_E) {
        int s = edges[e0 + tx];
        int d = edges[NE + e0 + tx];
        s_src[tx] = s; s_dst[tx] = d;
        float dx = x[s * 3 + 0] - x[d * 3 + 0];
        float dy = x[s * 3 + 1] - x[d * 3 + 1];
        float dz = x[s * 3 + 2] - x[d * 3 + 2];
        s_diff[tx][0] = dx; s_diff[tx][1] = dy; s_diff[tx][2] = dz;
        s_tail[tx][0] = dx * dx + dy * dy + dz * dz;
        int et = etype[e0 + tx];
        #pragma unroll
        for (int j = 0; j < 32; ++j) s_tail[tx][1 + j] = edge_table[et * 32 + j];
    }
    if (tx < HID) s_wx[tx] = Wx_l[tx];
    __syncthreads();

    float acc[4][8];
    #pragma unroll
    for (int i = 0; i < 4; ++i)
        #pragma unroll
        for (int j = 0; j < 8; ++j) acc[i][j] = 0.f;

    for (int t = 0; t < 9; ++t) {
        int k0 = t * 32;
        int klen = (t == 8) ? 33 : 32;
        __syncthreads();
        if (t < 8) {
            const bool use_src = (t < 4);
            int kbase = (t & 3) * 32;
            for (int q4 = tx; q4 < TILE_E * 8; q4 += 256) {
                int e = q4 >> 3, q = q4 & 7;
                int row = use_src ? s_src[e] : s_dst[e];
                float4 v = *(const float4*)&h[row * HID + kbase + q * 4];
                *(float4*)&s_Af[e][q * 4] = v;
            }
        }
        for (int q4 = tx; q4 < klen * 32; q4 += 256) {
            int kk = q4 >> 5, c4 = q4 & 31;
            float4 v = *(const float4*)&We_l[(k0 + kk) * HID + c4 * 4];
            *(float4*)&s_Bf[kk][c4 * 4] = v;
        }
        __syncthreads();
        const float (*Asrc)[36] = (t == 8) ? (const float (*)[36])s_tail
                                           : (const float (*)[36])s_Af;
        for (int kk = 0; kk < klen; ++kk) {
            float a0 = Asrc[te * 4 + 0][kk];
            float a1 = Asrc[te * 4 + 1][kk];
            float a2 = Asrc[te * 4 + 2][kk];
            float a3 = Asrc[te * 4 + 3][kk];
            float4 bv0 = *(const float4*)&s_Bf[kk][tf * 8];
            float4 bv1 = *(const float4*)&s_Bf[kk][tf * 8 + 4];
            float b[8] = {bv0.x, bv0.y, bv0.z, bv0.w, bv1.x, bv1.y, bv1.z, bv1.w};
            #pragma unroll
            for (int j = 0; j < 8; ++j) {
                acc[0][j] += a0 * b[j];
                acc[1][j] += a1 * b[j];
                acc[2][j] += a2 * b[j];
                acc[3][j] += a3 * b[j];
            }
        }
    }

    float wsum[4];
    #pragma unroll
    for (int i = 0; i < 4; ++i) {
        float p = 0.f;
        #pragma unroll
        for (int j = 0; j < 8; ++j) {
            int f = tf * 8 + j;
            float v = acc[i][j] + be_l[f];
            float m = silu(v);
            acc[i][j] = m;
            p += m * s_wx[f];
        }
        wsum[i] = p;
    }
    #pragma unroll
    for (int off = 1; off < 16; off <<= 1) {
        #pragma unroll
        for (int i = 0; i < 4; ++i) wsum[i] += __shfl_xor(wsum[i], off);
    }
    float bxv = bx_l[0];
    if (tf < 3) {
        #pragma unroll
        for (int i = 0; i < 4; ++i) {
            int e = te * 4 + i;
            float w2 = wsum[i] + bxv;
            atomicAdd(&agg_x[s_dst[e] * 3 + tf], s_diff[e][tf] * w2);
        }
    }
    #pragma unroll
    for (int i = 0; i < 4; ++i) {
        int d = s_dst[te * 4 + i];
        #pragma unroll
        for (int j = 0; j < 8; ++j)
            atomicAdd(&agg_m[d * HID + tf * 8 + j], acc[i][j]);
    }
}

__global__ __launch_bounds__(128) void node_update_fb_kernel(
    float* __restrict__ h, float* __restrict__ x,
    const float* __restrict__ agg_m, const float* __restrict__ agg_x,
    const float* __restrict__ cnt,
    const float* __restrict__ Wh_l, const float* __restrict__ bh_l)
{
    __shared__ float s_in[256][20];
    int n0 = blockIdx.x * 16;
    int tx = threadIdx.x;
    for (int idx = tx; idx < 16 * HID; idx += 128) {
        int i = idx >> 7, k = idx & 127;
        s_in[k][i] = h[(n0 + i) * HID + k];
    }
    for (int idx = tx; idx < 16 * HID; idx += 128) {
        int i = idx >> 7, k = idx & 127;
        s_in[HID + k][i] = agg_m[(n0 + i) * HID + k];
    }
    __syncthreads();
    float acc[16];
    float bv = bh_l[tx];
    #pragma unroll
    for (int i = 0; i < 16; ++i) acc[i] = bv;
    for (int k = 0; k < 256; ++k) {
        float w = Wh_l[k * HID + tx];
        float4 f0 = *(const float4*)&s_in[k][0];
        float4 f1 = *(const float4*)&s_in[k][4];
        float4 f2 = *(const float4*)&s_in[k][8];
        float4 f3 = *(const float4*)&s_in[k][12];
        acc[0] += f0.x*w; acc[1] += f0.y*w; acc[2] += f0.z*w; acc[3] += f0.w*w;
        acc[4] += f1.x*w; acc[5] += f1.y*w; acc[6] += f1.z*w; acc[7] += f1.w*w;
        acc[8] += f2.x*w; acc[9] += f2.y*w; acc[10]+= f2.z*w; acc[11]+= f2.w*w;
        acc[12]+= f3.x*w; acc[13]+= f3.y*w; acc[14]+= f3.z*w; acc[15]+= f3.w*w;
    }
    #pragma unroll
    for (int i = 0; i < 16; ++i) {
        float v = acc[i];
        h[(n0 + i) * HID + tx] = s_in[tx][i] + silu(v);
    }
    if (tx < 48) {
        int i = tx / 3, c = tx % 3;
        int n = n0 + i;
        x[n * 3 + c] += agg_x[n * 3 + c] / (cnt[n] + 1.f);
    }
}

__global__ __launch_bounds__(64) void final_fb_kernel(
    const float* __restrict__ h, const float* __restrict__ x,
    const int* __restrict__ gmask,
    const float* __restrict__ W, const float* __restrict__ b,
    float* __restrict__ out)
{
    __shared__ float s_h[8][HID];
    int n0 = blockIdx.x * 8;
    int tx = threadIdx.x;
    for (int idx = tx; idx < 8 * HID; idx += 64) {
        int i = idx >> 7, k = idx & 127;
        s_h[i][k] = h[(n0 + i) * HID + k];
    }
    __syncthreads();
    float acc[8];
    float bv = b[tx];
    #pragma unroll
    for (int i = 0; i < 8; ++i) acc[i] = bv;
    for (int k = 0; k < HID; ++k) {
        float w = W[k * IN_DIM + tx];
        #pragma unroll
        for (int i = 0; i < 8; ++i) acc[i] += s_h[i][k] * w;
    }
    #pragma unroll
    for (int i = 0; i < 8; ++i) {
        int n = n0 + i;
        out[n * IN_DIM + tx] = gmask[n] ? acc[i] : 0.f;
    }
    if (tx < 24) {
        int i = tx / 3, c = tx % 3;
        int n = n0 + i;
        out[NN * IN_DIM + n * 3 + c] = gmask[n] ? x[n * 3 + c] : 0.f;
    }
}

extern "C" void kernel_launch(void* const* d_in, const int* in_sizes, int n_in,
                              void* d_out, int out_size, void* d_ws, size_t ws_size,
                              hipStream_t stream) {
    const float* H_t   = (const float*)d_in[0];
    const float* X_t   = (const float*)d_in[1];
    const float* cond  = (const float*)d_in[2];
    const float* t_in  = (const float*)d_in[3];
    const int*   edges = (const int*)d_in[4];
    const int*   etype = (const int*)d_in[5];
    const int*   gmask = (const int*)d_in[6];
    const float* W0 = (const float*)d_in[8];
    const float* b0 = (const float*)d_in[9];
    const float* W1 = (const float*)d_in[10];
    const float* b1 = (const float*)d_in[11];
    const float* W2 = (const float*)d_in[12];
    const float* b2 = (const float*)d_in[13];
    const float* edge_table = (const float*)d_in[14];
    const float* We = (const float*)d_in[15];
    const float* be = (const float*)d_in[16];
    const float* Wx = (const float*)d_in[17];
    const float* bx = (const float*)d_in[18];
    const float* Wh = (const float*)d_in[19];
    const float* bh = (const float*)d_in[20];
    const float* h2i_W = (const float*)d_in[21];
    const float* h2i_b = (const float*)d_in[22];

    char* p = (char*)d_ws;
    float* h = (float*)p;           p += (size_t)NN * HID * 4;
    u16* h_bf = (u16*)p;            p += (size_t)NN * HID * 2;
    float* xa = (float*)p;          p += (size_t)NN * 3 * 4;
    float* xb = (float*)p;          p += (size_t)NN * 3 * 4;
    u16* Cbf = (u16*)p;             p += (size_t)NN * 256 * 2;
    u16* agg_bf = (u16*)p;          p += (size_t)NN * HID * 2;
    u16* Bpack = (u16*)p;           p += (size_t)PACK_TOT * 2;
    float* tv = (float*)p;          p += (size_t)768 * 4;
    float* wed2 = (float*)p;        p += (size_t)384 * 4;
    int* row_start = (int*)p;       p += (size_t)(NN + 4) * 4;
    int* deg = (int*)p;             p += (size_t)NN * 4;
    int* head = (int*)p;            p += (size_t)NN * 4;
    int* src_s = (int*)p;           p += (size_t)NE * 4;
    size_t need = (size_t)(p - (char*)d_ws);

    if (ws_size >= need) {
        hipMemsetAsync(deg, 0, NN * sizeof(int), stream);
        hist_kernel<<<256, 256, 0, stream>>>(X_t, edges, xa, deg);
        scan_kernel<<<1, 1024, 0, stream>>>(deg, row_start, head);
        scatter_kernel<<<256, 256, 0, stream>>>(edges, etype, head, src_s);
        pack_all_kernel<<<(PACK_TOT + 255) / 256, 256, 0, stream>>>(
            We, W0, W1, W2, Wh, h2i_W, Bpack);
        precomp_tv_kernel<<<5, 256, 0, stream>>>(edge_table, We, be, tv, wed2);
        node_mlp_mfma_kernel<<<NB64, 256, 0, stream>>>(
            H_t, cond, t_in,
            Bpack + OFF_W0, b0, Bpack + OFF_W1, b1, Bpack + OFF_W2, b2,
            Bpack + OFF_WE, tv, Cbf,
            h, h_bf);
        for (int l = 0; l < 3; ++l) {
            const float* xin = (l & 1) ? xb : xa;
            float* xout = (l & 1) ? xa : xb;
            edge_agg_kernel<<<NN / NPW / 4, 256, 0, stream>>>(
                xin, xout, Cbf, agg_bf, src_s, row_start,
                tv + (size_t)l * 256, wed2 + (size_t)l * 128,
                Wx + l * HID, bx + l);
            int do_cvec = (l < 2) ? 1 : 0;
            wh_cvec_kernel<<<NB64, 256, 0, stream>>>(
                h, h_bf, agg_bf,
                Bpack + OFF_WH + (size_t)l * 32768, bh + l * HID,
                Bpack + OFF_WE + (size_t)(do_cvec ? (l + 1) : 0) * 40960,
                tv + (size_t)(do_cvec ? (l + 1) : 0) * 256,
                Cbf, do_cvec);
        }
        // layers: l0 xa->xb, l1 xb->xa, l2 xa->xb  => final x lives in xb
        final_mfma_kernel<<<NB64, 256, 0, stream>>>(
            h_bf, xb, gmask, Bpack + OFF_H2I, h2i_b, (float*)d_out);
    } else {
        // fallback: scalar atomic path (~21 MB)
        float* ws    = (float*)d_ws;
        float* fh    = ws;
        float* fx    = fh + NN * HID;
        float* cnt   = fx + NN * 3;
        float* fagg_m = cnt + NN;
        float* fagg_x = fagg_m + NN * HID;

        hipMemsetAsync(cnt, 0, NN * sizeof(float), stream);
        init_fb_kernel<<<256, 256, 0, stream>>>(X_t, edges, fx, cnt);
        node_mlp_kernel<<<NN / 16, 128, 0, stream>>>(H_t, cond, t_in,
                                                     W0, b0, W1, b1, W2, b2, fh);
        for (int l = 0; l < 3; ++l) {
            hipMemsetAsync(fagg_m, 0, (size_t)NN * 131 * sizeof(float), stream);
            edge_gemm_fb_kernel<<<NE / TILE_E, 256, 0, stream>>>(
                fh, fx, edges, etype, edge_table,
                We + (size_t)l * DE * HID, be + l * HID,
                Wx + l * HID, bx + l, fagg_m, fagg_x);
            node_update_fb_kernel<<<NN / 16, 128, 0, stream>>>(
                fh, fx, fagg_m, fagg_x, cnt,
                Wh + (size_t)l * 256 * HID, bh + l * HID);
        }
        final_fb_kernel<<<NN / 8, 64, 0, stream>>>(fh, fx, gmask, h2i_W, h2i_b, (float*)d_out);
    }
}

// Round 5
// 376.693 us; speedup vs baseline: 1.0600x; 1.0600x over previous
//
#include <hip/hip_runtime.h>
#include <math.h>

#define NN 20000
#define NE 256000
#define IN_DIM 64
#define HID 128
#define DE 289     // 2*HID + 1 + 32
#define D0 320     // IN_DIM + 2*HID
#define TILE_E 64
#define NB64 313   // ceil(NN/64)
#define NUB 8      // nodes per block (fused node kernel)
#define SRCMASK 0x3FFFFFFF

typedef unsigned short u16;
typedef unsigned int u32;
typedef unsigned long long u64;
typedef __attribute__((ext_vector_type(8))) short short8;
typedef __attribute__((ext_vector_type(4))) float float4v;

// Bpack layout offsets (u16 elements)
#define OFF_WE   0          // 3 x 40960 (K=289 pad 320, N=128) — tiles 0..3 = We rows 0..255
#define OFF_W0   122880     // 40960 (K=320, N=128)
#define OFF_W1   163840     // 16384 (K=128, N=128)
#define OFF_W2   180224     // 16384
#define OFF_WH   196608     // 3 x 32768 (K=256, N=128)
#define OFF_H2I  294912     // 8192 (K=128, N=64)
#define PACK_TOT 303104

static __device__ __forceinline__ u16 f2bf(float f) {
    unsigned int u = __float_as_uint(f);
    u += 0x7fffu + ((u >> 16) & 1u);
    return (u16)(u >> 16);
}
static __device__ __forceinline__ float bf2f(u16 s) {
    return __uint_as_float(((unsigned int)s) << 16);
}
static __device__ __forceinline__ float bflo(u32 u) { return bf2f((u16)(u & 0xffffu)); }
static __device__ __forceinline__ float bfhi(u32 u) { return bf2f((u16)(u >> 16)); }
static __device__ __forceinline__ u32 pack2(float a, float b) {
    return (u32)f2bf(a) | ((u32)f2bf(b) << 16);
}
static __device__ __forceinline__ uint4 pack8(const float* v) {
    uint4 r;
    r.x = (u32)f2bf(v[0]) | ((u32)f2bf(v[1]) << 16);
    r.y = (u32)f2bf(v[2]) | ((u32)f2bf(v[3]) << 16);
    r.z = (u32)f2bf(v[4]) | ((u32)f2bf(v[5]) << 16);
    r.w = (u32)f2bf(v[6]) | ((u32)f2bf(v[7]) << 16);
    return r;
}
static __device__ __forceinline__ float silu(float v) {
    return v * (1.f / (1.f + __expf(-v)));
}

// ================= CSR build =================
__global__ __launch_bounds__(256) void hist_kernel(
    const float* __restrict__ X_t, const int* __restrict__ edges,
    float* __restrict__ x, int* __restrict__ deg)
{
    int gid = blockIdx.x * blockDim.x + threadIdx.x;
    int stride = gridDim.x * blockDim.x;
    for (int i = gid; i < NN * 3; i += stride) x[i] = X_t[i];
    for (int e = gid; e < NE; e += stride)
        atomicAdd(&deg[edges[NE + e]], 1);
}

__global__ __launch_bounds__(1024) void scan_kernel(
    const int* __restrict__ deg, int* __restrict__ row_start, int* __restrict__ head)
{
    __shared__ int s[1024];
    int tx = threadIdx.x;
    const int per = (NN + 1023) / 1024;
    int st = tx * per, en = st + per;
    if (st > NN) st = NN;
    if (en > NN) en = NN;
    int sum = 0;
    for (int i = st; i < en; ++i) sum += deg[i];
    s[tx] = sum;
    __syncthreads();
    for (int off = 1; off < 1024; off <<= 1) {
        int t = (tx >= off) ? s[tx - off] : 0;
        __syncthreads();
        s[tx] += t;
        __syncthreads();
    }
    int run = (tx == 0) ? 0 : s[tx - 1];
    for (int i = st; i < en; ++i) {
        row_start[i] = run; head[i] = run; run += deg[i];
    }
    if (tx == 1023) row_start[NN] = run;
}

// permute edges into dst-sorted order; pack etype into src bit 30
__global__ __launch_bounds__(256) void scatter_kernel(
    const int* __restrict__ edges, const int* __restrict__ etype,
    int* __restrict__ head,
    int* __restrict__ src_s)
{
    int gid = blockIdx.x * blockDim.x + threadIdx.x;
    int stride = gridDim.x * blockDim.x;
    for (int e = gid; e < NE; e += stride) {
        int d = edges[NE + e];
        int p = atomicAdd(&head[d], 1);
        src_s[p] = edges[e] | (etype[e] << 30);
    }
}

// ================= weight frag-order packing =================
__global__ __launch_bounds__(256) void pack_all_kernel(
    const float* __restrict__ We, const float* __restrict__ W0,
    const float* __restrict__ W1, const float* __restrict__ W2,
    const float* __restrict__ Wh, const float* __restrict__ h2i,
    u16* __restrict__ Bp)
{
    int idx = blockIdx.x * 256 + threadIdx.x;
    if (idx >= PACK_TOT) return;
    const float* src; int N = 128, Ksrc; int r;
    if (idx < OFF_W0) {
        int layer = idx / 40960; r = idx - layer * 40960;
        src = We + (size_t)layer * DE * HID; Ksrc = DE;
    } else if (idx < OFF_W1) { r = idx - OFF_W0; src = W0; Ksrc = 320; }
    else if (idx < OFF_W2)   { r = idx - OFF_W1; src = W1; Ksrc = 128; }
    else if (idx < OFF_WH)   { r = idx - OFF_W2; src = W2; Ksrc = 128; }
    else if (idx < OFF_H2I) {
        int t = idx - OFF_WH; int layer = t / 32768; r = t - layer * 32768;
        src = Wh + (size_t)layer * 256 * HID; Ksrc = 256;
    } else { r = idx - OFF_H2I; src = h2i; Ksrc = 128; N = 64; }
    int ntc = N / 16;
    int j = r & 7, lane = (r >> 3) & 63;
    int rem = r >> 9;
    int nt = rem % ntc, ks = rem / ntc;
    int k = ks * 32 + ((lane >> 4) << 3) + j;
    int c = nt * 16 + (lane & 15);
    Bp[idx] = f2bf((k < Ksrc) ? src[(size_t)k * N + c] : 0.f);
}

// ================= edge tail precompute (f32) =================
__global__ __launch_bounds__(256) void precomp_tv_kernel(
    const float* __restrict__ edge_table, const float* __restrict__ We,
    const float* __restrict__ be, float* __restrict__ tv, float* __restrict__ wed2)
{
    int idx = blockIdx.x * 256 + threadIdx.x;
    if (idx < 768) {
        int f = idx & 127, t = (idx >> 7) & 1, l = idx >> 8;
        float acc = be[l * 128 + f];
        const float* W = We + (size_t)l * DE * HID;
        #pragma unroll
        for (int k = 0; k < 32; ++k)
            acc += edge_table[t * 32 + k] * W[(size_t)(257 + k) * HID + f];
        tv[l * 256 + t * 128 + f] = acc;
    } else if (idx < 1152) {
        int r = idx - 768;
        int f = r & 127, l = r >> 7;
        wed2[l * 128 + f] = We[(size_t)l * DE * HID + (size_t)256 * HID + f];
    }
}

// ================= node MLP: MFMA, 64 nodes/block + fused cvec layer-0 =================
__global__ __launch_bounds__(256) void node_mlp_mfma_kernel(
    const float* __restrict__ H_t, const float* __restrict__ cond,
    const float* __restrict__ t_in,
    const u16* __restrict__ W0p, const float* __restrict__ b0,
    const u16* __restrict__ W1p, const float* __restrict__ b1,
    const u16* __restrict__ W2p, const float* __restrict__ b2,
    const u16* __restrict__ WEp,
    u16* __restrict__ Csrc, u16* __restrict__ Cdst,
    float* __restrict__ h, u16* __restrict__ h_bf)
{
    __shared__ u16 s_A[64 * 64];
    __shared__ u16 s_B[64 * 128];
    __shared__ u16 s_h[64 * 128];
    __shared__ float s_t[64];

    int tx = threadIdx.x;
    int n0 = blockIdx.x * 64;
    int l = tx & 63, w = tx >> 6;
    int mt_base = (w & 1) * 2, nt_base = (w >> 1) * 4;
    const float cfr = -logf(10000.f) / 63.f;

    if (tx < 64) s_t[tx] = (n0 + tx < NN) ? t_in[n0 + tx] : 0.f;

    float4v acc[2][4];
    #pragma unroll
    for (int mi = 0; mi < 2; ++mi)
        #pragma unroll
        for (int ni = 0; ni < 4; ++ni) acc[mi][ni] = (float4v){0.f,0.f,0.f,0.f};

    for (int t = 0; t < 5; ++t) {
        __syncthreads();
        #pragma unroll
        for (int it = 0; it < 2; ++it) {
            int flat = it * 256 + tx;
            int n = flat >> 3, sl = flat & 7;
            int c = sl ^ (n & 7);
            int k0 = t * 64 + c * 8;
            float tv8[8];
            int gn = n0 + n;
            if (gn < NN) {
                if (k0 < 192) {
                    const float* src = (k0 < 64) ? &H_t[(size_t)gn * IN_DIM + k0]
                                                 : &cond[(size_t)gn * HID + (k0 - 64)];
                    float4 a = *(const float4*)src;
                    float4 b = *(const float4*)(src + 4);
                    tv8[0]=a.x; tv8[1]=a.y; tv8[2]=a.z; tv8[3]=a.w;
                    tv8[4]=b.x; tv8[5]=b.y; tv8[6]=b.z; tv8[7]=b.w;
                } else {
                    float tvv = s_t[n];
                    int jj = (k0 - 192) & 63;
                    bool is_sin = (k0 < 256);
                    #pragma unroll
                    for (int jx = 0; jx < 8; ++jx) {
                        float ang = tvv * __expf(cfr * (float)(jj + jx));
                        tv8[jx] = is_sin ? __sinf(ang) : __cosf(ang);
                    }
                }
            } else {
                #pragma unroll
                for (int jx = 0; jx < 8; ++jx) tv8[jx] = 0.f;
            }
            *(uint4*)&s_A[n * 64 + sl * 8] = pack8(tv8);
        }
        #pragma unroll
        for (int it = 0; it < 4; ++it) {
            int flat = it * 256 + tx;
            ((uint4*)s_B)[flat] = ((const uint4*)(W0p + (size_t)t * 8192))[flat];
        }
        __syncthreads();
        #pragma unroll
        for (int s = 0; s < 2; ++s) {
            short8 af[2], bfv[4];
            #pragma unroll
            for (int mi = 0; mi < 2; ++mi) {
                int m = (mt_base + mi) * 16 + (l & 15);
                int c = s * 4 + (l >> 4);
                int slot = c ^ (l & 7);
                af[mi] = *(const short8*)(s_A + m * 64 + slot * 8);
            }
            #pragma unroll
            for (int ni = 0; ni < 4; ++ni)
                bfv[ni] = *(const short8*)(s_B + ((s * 8 + nt_base + ni) * 64 + l) * 8);
            #pragma unroll
            for (int mi = 0; mi < 2; ++mi)
                #pragma unroll
                for (int ni = 0; ni < 4; ++ni)
                    acc[mi][ni] = __builtin_amdgcn_mfma_f32_16x16x32_bf16(
                        af[mi], bfv[ni], acc[mi][ni], 0, 0, 0);
        }
    }
    #pragma unroll
    for (int mi = 0; mi < 2; ++mi) {
        #pragma unroll
        for (int ni = 0; ni < 4; ++ni) {
            int f = (nt_base + ni) * 16 + (l & 15);
            float bv = b0[f];
            #pragma unroll
            for (int r = 0; r < 4; ++r) {
                int m = (mt_base + mi) * 16 + (l >> 4) * 4 + r;
                float v = fmaxf(acc[mi][ni][r] + bv, 0.f);
                int slot = (f >> 3) ^ (m & 7);
                s_h[m * 128 + slot * 8 + (f & 7)] = f2bf(v);
            }
            acc[mi][ni] = (float4v){0.f,0.f,0.f,0.f};
        }
    }
    for (int t = 0; t < 2; ++t) {
        __syncthreads();
        #pragma unroll
        for (int it = 0; it < 4; ++it) {
            int flat = it * 256 + tx;
            ((uint4*)s_B)[flat] = ((const uint4*)(W1p + (size_t)t * 8192))[flat];
        }
        __syncthreads();
        #pragma unroll
        for (int s = 0; s < 2; ++s) {
            short8 af[2], bfv[4];
            #pragma unroll
            for (int mi = 0; mi < 2; ++mi) {
                int m = (mt_base + mi) * 16 + (l & 15);
                int c = t * 8 + s * 4 + (l >> 4);
                int slot = c ^ (l & 7);
                af[mi] = *(const short8*)(s_h + m * 128 + slot * 8);
            }
            #pragma unroll
            for (int ni = 0; ni < 4; ++ni)
                bfv[ni] = *(const short8*)(s_B + ((s * 8 + nt_base + ni) * 64 + l) * 8);
            #pragma unroll
            for (int mi = 0; mi < 2; ++mi)
                #pragma unroll
                for (int ni = 0; ni < 4; ++ni)
                    acc[mi][ni] = __builtin_amdgcn_mfma_f32_16x16x32_bf16(
                        af[mi], bfv[ni], acc[mi][ni], 0, 0, 0);
        }
    }
    __syncthreads();
    #pragma unroll
    for (int mi = 0; mi < 2; ++mi) {
        #pragma unroll
        for (int ni = 0; ni < 4; ++ni) {
            int f = (nt_base + ni) * 16 + (l & 15);
            float bv = b1[f];
            #pragma unroll
            for (int r = 0; r < 4; ++r) {
                int m = (mt_base + mi) * 16 + (l >> 4) * 4 + r;
                float v = fmaxf(acc[mi][ni][r] + bv, 0.f);
                int slot = (f >> 3) ^ (m & 7);
                s_h[m * 128 + slot * 8 + (f & 7)] = f2bf(v);
            }
            acc[mi][ni] = (float4v){0.f,0.f,0.f,0.f};
        }
    }
    for (int t = 0; t < 2; ++t) {
        __syncthreads();
        #pragma unroll
        for (int it = 0; it < 4; ++it) {
            int flat = it * 256 + tx;
            ((uint4*)s_B)[flat] = ((const uint4*)(W2p + (size_t)t * 8192))[flat];
        }
        __syncthreads();
        #pragma unroll
        for (int s = 0; s < 2; ++s) {
            short8 af[2], bfv[4];
            #pragma unroll
            for (int mi = 0; mi < 2; ++mi) {
                int m = (mt_base + mi) * 16 + (l & 15);
                int c = t * 8 + s * 4 + (l >> 4);
                int slot = c ^ (l & 7);
                af[mi] = *(const short8*)(s_h + m * 128 + slot * 8);
            }
            #pragma unroll
            for (int ni = 0; ni < 4; ++ni)
                bfv[ni] = *(const short8*)(s_B + ((s * 8 + nt_base + ni) * 64 + l) * 8);
            #pragma unroll
            for (int mi = 0; mi < 2; ++mi)
                #pragma unroll
                for (int ni = 0; ni < 4; ++ni)
                    acc[mi][ni] = __builtin_amdgcn_mfma_f32_16x16x32_bf16(
                        af[mi], bfv[ni], acc[mi][ni], 0, 0, 0);
        }
    }
    // final h: write globals AND store into s_h (swizzled) for the fused cvec
    __syncthreads();   // protect s_h against pending W2-stage reads
    #pragma unroll
    for (int mi = 0; mi < 2; ++mi) {
        #pragma unroll
        for (int ni = 0; ni < 4; ++ni) {
            int f = (nt_base + ni) * 16 + (l & 15);
            float bv = b2[f];
            #pragma unroll
            for (int r = 0; r < 4; ++r) {
                int m = (mt_base + mi) * 16 + (l >> 4) * 4 + r;
                int gn = n0 + m;
                float v = acc[mi][ni][r] + bv;
                int slot = (f >> 3) ^ (m & 7);
                s_h[m * 128 + slot * 8 + (f & 7)] = f2bf(v);
                if (gn < NN) {
                    h[(size_t)gn * HID + f] = v;
                    h_bf[(size_t)gn * HID + f] = f2bf(v);
                }
            }
        }
    }

    // ---- fused cvec (layer 0): Csrc[n]=h@We_src, Cdst[n]=h@We_dst ----
    for (int sd = 0; sd < 2; ++sd) {
        #pragma unroll
        for (int mi = 0; mi < 2; ++mi)
            #pragma unroll
            for (int ni = 0; ni < 4; ++ni) acc[mi][ni] = (float4v){0.f,0.f,0.f,0.f};
        #pragma unroll
        for (int th = 0; th < 2; ++th) {
            int t = sd * 2 + th;
            __syncthreads();
            #pragma unroll
            for (int it = 0; it < 4; ++it) {
                int flat = it * 256 + tx;
                ((uint4*)s_B)[flat] = ((const uint4*)(WEp + (size_t)t * 8192))[flat];
            }
            __syncthreads();
            #pragma unroll
            for (int s = 0; s < 2; ++s) {
                short8 af[2], bfv[4];
                #pragma unroll
                for (int mi = 0; mi < 2; ++mi) {
                    int m = (mt_base + mi) * 16 + (l & 15);
                    int c = th * 8 + s * 4 + (l >> 4);
                    int slot = c ^ (l & 7);
                    af[mi] = *(const short8*)(s_h + m * 128 + slot * 8);
                }
                #pragma unroll
                for (int ni = 0; ni < 4; ++ni)
                    bfv[ni] = *(const short8*)(s_B + ((s * 8 + nt_base + ni) * 64 + l) * 8);
                #pragma unroll
                for (int mi = 0; mi < 2; ++mi)
                    #pragma unroll
                    for (int ni = 0; ni < 4; ++ni)
                        acc[mi][ni] = __builtin_amdgcn_mfma_f32_16x16x32_bf16(
                            af[mi], bfv[ni], acc[mi][ni], 0, 0, 0);
            }
        }
        u16* Cout = (sd == 0) ? Csrc : Cdst;
        #pragma unroll
        for (int mi = 0; mi < 2; ++mi) {
            #pragma unroll
            for (int ni = 0; ni < 4; ++ni) {
                int fq = (nt_base + ni) * 16 + (l & 15);
                #pragma unroll
                for (int r = 0; r < 4; ++r) {
                    int m = (mt_base + mi) * 16 + (l >> 4) * 4 + r;
                    int gn = n0 + m;
                    if (gn < NN)
                        Cout[(size_t)gn * 128 + fq] = f2bf(acc[mi][ni][r]);
                }
            }
        }
    }
}

// ================= cvec (layers 1,2): Csrc[n]=h@We_src, Cdst[n]=h@We_dst =================
__global__ __launch_bounds__(256) void cvec_kernel(
    const u16* __restrict__ h_bf, const u16* __restrict__ WEp,
    u16* __restrict__ Csrc, u16* __restrict__ Cdst)
{
    __shared__ u16 s_A[64 * 64];
    __shared__ u16 s_B[64 * 128];

    int tx = threadIdx.x;
    int n0 = blockIdx.x * 64;
    int l = tx & 63, w = tx >> 6;
    int mt_base = (w & 1) * 2, nt_base = (w >> 1) * 4;

    float4v acc[2][2][4];  // [side][mi][ni]
    #pragma unroll
    for (int sd = 0; sd < 2; ++sd)
        #pragma unroll
        for (int mi = 0; mi < 2; ++mi)
            #pragma unroll
            for (int ni = 0; ni < 4; ++ni)
                acc[sd][mi][ni] = (float4v){0.f,0.f,0.f,0.f};

    for (int t = 0; t < 4; ++t) {
        __syncthreads();
        #pragma unroll
        for (int it = 0; it < 2; ++it) {
            int flat = it * 256 + tx;
            int n = flat >> 3, sl = flat & 7;
            int c = sl ^ (n & 7);
            int gn = n0 + n;
            uint4 v = make_uint4(0,0,0,0);
            if (gn < NN) v = *(const uint4*)(h_bf + (size_t)gn * 128 + (t & 1) * 64 + c * 8);
            *(uint4*)&s_A[n * 64 + sl * 8] = v;
        }
        #pragma unroll
        for (int it = 0; it < 4; ++it) {
            int flat = it * 256 + tx;
            ((uint4*)s_B)[flat] = ((const uint4*)(WEp + (size_t)t * 8192))[flat];
        }
        __syncthreads();
        int sd = t >> 1;
        #pragma unroll
        for (int s = 0; s < 2; ++s) {
            short8 af[2], bfv[4];
            #pragma unroll
            for (int mi = 0; mi < 2; ++mi) {
                int m = (mt_base + mi) * 16 + (l & 15);
                int c = s * 4 + (l >> 4);
                int slot = c ^ (l & 7);
                af[mi] = *(const short8*)(s_A + m * 64 + slot * 8);
            }
            #pragma unroll
            for (int ni = 0; ni < 4; ++ni)
                bfv[ni] = *(const short8*)(s_B + ((s * 8 + nt_base + ni) * 64 + l) * 8);
            #pragma unroll
            for (int mi = 0; mi < 2; ++mi)
                #pragma unroll
                for (int ni = 0; ni < 4; ++ni)
                    acc[sd][mi][ni] = __builtin_amdgcn_mfma_f32_16x16x32_bf16(
                        af[mi], bfv[ni], acc[sd][mi][ni], 0, 0, 0);
        }
    }
    #pragma unroll
    for (int sd = 0; sd < 2; ++sd) {
        u16* Cout = (sd == 0) ? Csrc : Cdst;
        #pragma unroll
        for (int mi = 0; mi < 2; ++mi) {
            #pragma unroll
            for (int ni = 0; ni < 4; ++ni) {
                int fq = (nt_base + ni) * 16 + (l & 15);
                #pragma unroll
                for (int r = 0; r < 4; ++r) {
                    int m = (mt_base + mi) * 16 + (l >> 4) * 4 + r;
                    int gn = n0 + m;
                    if (gn < NN)
                        Cout[(size_t)gn * 128 + fq] = f2bf(acc[sd][mi][ni][r]);
                }
            }
        }
    }
}

// ================= fused node update v5 (R2 base; Csrc/Cdst split) =================
// NUB=8 nodes/block, 512 thr, wave w = node w. Wave-private edge staging:
//  - lane l holds edge l's src|et and geometry in REGISTERS (no LDS, no pre-loop barrier)
//  - consume-time broadcast via __shfl (ds_bpermute)
//  - 4-deep Csrc gather pipeline per parity (8 gathers in flight per wave)
//  - single block barrier (before Wh GEMM); Wh B-fragments straight from L2
__global__ __launch_bounds__(512, 4) void node_fused_kernel(
    float* __restrict__ h, u16* __restrict__ h_bf,
    const float* __restrict__ x_in, float* __restrict__ x_out,
    const u16* __restrict__ Csrc, const u16* __restrict__ Cdst,
    const int* __restrict__ src_s,
    const int* __restrict__ row_start,
    const float* __restrict__ tv_l, const float* __restrict__ wed2_l,
    const float* __restrict__ Wx_l, const float* __restrict__ bx_l,
    const u16* __restrict__ Whp_l, const float* __restrict__ bh_l)
{
    __shared__ u16 s_A[16 * 256];      // 8 KB: rows 0..7 = [h | agg] xor-swizzled, rows 8..15 zero

    int tx = threadIdx.x;
    int n0 = blockIdx.x * NUB;
    int l = tx & 63, w = tx >> 6;      // 8 waves; wave w owns node i = w
    int i = w;
    int gn = n0 + i;
    int p = l & 31, q = l >> 5;        // feat-chunk (4 feats), edge parity

    // ---- stage h rows (0..7) + zero pad rows (chunks 0..15) ----
    if (tx < 256) {
        int n = tx >> 4, c = tx & 15;
        int slot = c ^ (n & 7);
        uint4 v = make_uint4(0, 0, 0, 0);
        if (n < NUB) v = *(const uint4*)(h_bf + (size_t)(n0 + n) * 128 + c * 8);
        *(uint4*)&s_A[n * 256 + slot * 8] = v;
    } else if (tx < 384) {
        int n = 8 + ((tx - 256) >> 4), c = 16 + (tx & 15);
        int slot = c ^ (n & 7);
        *(uint4*)&s_A[n * 256 + slot * 8] = make_uint4(0, 0, 0, 0);
    }

    // ---- per-thread constants (4 feats) ----
    float c0[4], d01[4], wed[4], wx[4];
    {
        uint2 cd = *(const uint2*)(Cdst + (size_t)gn * 128 + p * 4);
        float cdv0 = bflo(cd.x), cdv1 = bfhi(cd.x), cdv2 = bflo(cd.y), cdv3 = bfhi(cd.y);
        float4 t0 = *(const float4*)(tv_l + p * 4);
        float4 t1 = *(const float4*)(tv_l + 128 + p * 4);
        float4 wd = *(const float4*)(wed2_l + p * 4);
        float4 wv = *(const float4*)(Wx_l + p * 4);
        c0[0] = t0.x + cdv0; c0[1] = t0.y + cdv1; c0[2] = t0.z + cdv2; c0[3] = t0.w + cdv3;
        d01[0] = t1.x - t0.x; d01[1] = t1.y - t0.y; d01[2] = t1.z - t0.z; d01[3] = t1.w - t0.w;
        wed[0] = wd.x; wed[1] = wd.y; wed[2] = wd.z; wed[3] = wd.w;
        wx[0] = wv.x; wx[1] = wv.y; wx[2] = wv.z; wx[3] = wv.w;
    }
    float bx32 = bx_l[0] * (1.f / 32.f);

    int rs = row_start[gn], re = row_start[gn + 1];
    int d = re - rs;

    // own-node coords (wave-uniform)
    float xd0 = x_in[gn * 3 + 0], xd1 = x_in[gn * 3 + 1], xd2 = x_in[gn * 3 + 2];

    float ag[4] = {0.f, 0.f, 0.f, 0.f};
    float sx = 0.f, sy = 0.f, sz = 0.f;

    for (int e0 = 0; e0 < d; e0 += 64) {
        int nchunk = d - e0; if (nchunk > 64) nchunk = 64;
        // stage: lane l holds edge (e0+l)
        int sp_l = (l < nchunk) ? src_s[rs + e0 + l] : 0;
        float gx_l = 0.f, gy_l = 0.f, gz_l = 0.f, d2_l = 0.f;
        if (l < nchunk) {
            int sm = sp_l & SRCMASK;
            gx_l = x_in[sm * 3 + 0] - xd0;
            gy_l = x_in[sm * 3 + 1] - xd1;
            gz_l = x_in[sm * 3 + 2] - xd2;
            d2_l = gx_l * gx_l + gy_l * gy_l + gz_l * gz_l;
        }

        auto FETCH = [&](int lj, uint2& cc, float& et) {
            int spE = __shfl(sp_l, lj);
            cc = make_uint2(0u, 0u); et = 0.f;
            if (lj < nchunk) {
                cc = *(const uint2*)(Csrc + (size_t)(spE & SRCMASK) * 128 + p * 4);
                et = (float)((u32)spE >> 30);
            }
        };
        auto PROC = [&](int lj, uint2 cc, float ee) {
            float dxe = __shfl(gx_l, lj);
            float dye = __shfl(gy_l, lj);
            float dze = __shfl(gz_l, lj);
            float d2e = __shfl(d2_l, lj);
            float av[4];
            av[0] = bflo(cc.x); av[1] = bfhi(cc.x);
            av[2] = bflo(cc.y); av[3] = bfhi(cc.y);
            float wpart = bx32;
            #pragma unroll
            for (int f = 0; f < 4; ++f) {
                float t = __fmaf_rn(d2e, wed[f], c0[f]);
                t = __fmaf_rn(ee, d01[f], t);
                float v = av[f] + t;
                float m = silu(v);
                ag[f] += m;
                wpart = __fmaf_rn(m, wx[f], wpart);
            }
            sx = __fmaf_rn(dxe, wpart, sx);
            sy = __fmaf_rn(dye, wpart, sy);
            sz = __fmaf_rn(dze, wpart, sz);
        };

        // 4-slot pipeline per parity (8 gathers in flight per wave)
        int ljA = q, ljB = q + 2, ljC = q + 4, ljD = q + 6, ljn = q + 8;
        uint2 ccA, ccB, ccC, ccD; float etA, etB, etC, etD;
        FETCH(ljA, ccA, etA); FETCH(ljB, ccB, etB);
        FETCH(ljC, ccC, etC); FETCH(ljD, ccD, etD);
        while (ljA < nchunk) {
            PROC(ljA, ccA, etA); ljA = ljn; ljn += 2; FETCH(ljA, ccA, etA);
            if (ljB >= nchunk) break;
            PROC(ljB, ccB, etB); ljB = ljn; ljn += 2; FETCH(ljB, ccB, etB);
            if (ljC >= nchunk) break;
            PROC(ljC, ccC, etC); ljC = ljn; ljn += 2; FETCH(ljC, ccC, etC);
            if (ljD >= nchunk) break;
            PROC(ljD, ccD, etD); ljD = ljn; ljn += 2; FETCH(ljD, ccD, etD);
        }
    }

    // ---- reductions (within this node's single wave) ----
    #pragma unroll
    for (int f = 0; f < 4; ++f) ag[f] += __shfl_xor(ag[f], 32);   // combine parities
    #pragma unroll
    for (int off = 1; off <= 32; off <<= 1) {
        sx += __shfl_xor(sx, off);
        sy += __shfl_xor(sy, off);
        sz += __shfl_xor(sz, off);
    }
    if (l < 32) {
        int c2 = 16 + (p >> 1);
        int slot = c2 ^ (i & 7);
        uint2 o;
        o.x = pack2(ag[0], ag[1]);
        o.y = pack2(ag[2], ag[3]);
        *(uint2*)&s_A[i * 256 + slot * 8 + (p & 1) * 4] = o;
    }
    if (l == 0) {
        float inv = 1.f / ((float)d + 1.f);
        x_out[gn * 3 + 0] = xd0 + sx * inv;
        x_out[gn * 3 + 1] = xd1 + sy * inv;
        x_out[gn * 3 + 2] = xd2 + sz * inv;
    }

    __syncthreads();

    // ---- Wh GEMM: wave w = N-tile w; B fragments straight from L2 ----
    float4v acc = (float4v){0.f, 0.f, 0.f, 0.f};
    #pragma unroll
    for (int t = 0; t < 4; ++t) {
        #pragma unroll
        for (int s = 0; s < 2; ++s) {
            int m = l & 15;
            int c = t * 8 + s * 4 + (l >> 4);
            int slot = c ^ (l & 7);
            short8 af = *(const short8*)(s_A + m * 256 + slot * 8);
            short8 bfv = *(const short8*)(Whp_l + (size_t)t * 8192 + ((s * 8 + w) * 64 + l) * 8);
            acc = __builtin_amdgcn_mfma_f32_16x16x32_bf16(af, bfv, acc, 0, 0, 0);
        }
    }
    // epilogue: h += silu(acc + bh)  (only rows 0..7 are real nodes)
    {
        int f = w * 16 + (l & 15);
        float bv = bh_l[f];
        #pragma unroll
        for (int r = 0; r < 4; ++r) {
            int m = (l >> 4) * 4 + r;
            if (m < NUB) {
                int gn2 = n0 + m;
                float v = acc[r] + bv;
                float hn = h[(size_t)gn2 * HID + f] + silu(v);
                h[(size_t)gn2 * HID + f] = hn;
                h_bf[(size_t)gn2 * HID + f] = f2bf(hn);
            }
        }
    }
}

// ================= final: MFMA h2i, 64 nodes/block =================
__global__ __launch_bounds__(256) void final_mfma_kernel(
    const u16* __restrict__ h_bf, const float* __restrict__ x,
    const int* __restrict__ gmask,
    const u16* __restrict__ h2ip, const float* __restrict__ b,
    float* __restrict__ out)
{
    __shared__ u16 s_A[64 * 128];
    __shared__ u16 s_B[4096];

    int tx = threadIdx.x;
    int n0 = blockIdx.x * 64;
    int l = tx & 63, w = tx >> 6;
    int mt_base = (w & 1) * 2, nt_base = (w >> 1) * 2;

    #pragma unroll
    for (int it = 0; it < 4; ++it) {
        int flat = it * 256 + tx;
        int n = flat >> 4, c = flat & 15;
        int slot = c ^ (n & 7);
        int gn = n0 + n;
        uint4 v = make_uint4(0,0,0,0);
        if (gn < NN) v = *(const uint4*)(h_bf + (size_t)gn * 128 + c * 8);
        *(uint4*)&s_A[n * 128 + slot * 8] = v;
    }

    float4v acc[2][2];
    #pragma unroll
    for (int mi = 0; mi < 2; ++mi)
        #pragma unroll
        for (int ni = 0; ni < 2; ++ni) acc[mi][ni] = (float4v){0.f,0.f,0.f,0.f};

    for (int t = 0; t < 2; ++t) {
        __syncthreads();
        #pragma unroll
        for (int it = 0; it < 2; ++it) {
            int flat = it * 256 + tx;
            ((uint4*)s_B)[flat] = ((const uint4*)(h2ip + (size_t)t * 4096))[flat];
        }
        __syncthreads();
        #pragma unroll
        for (int s = 0; s < 2; ++s) {
            short8 af[2], bfv[2];
            #pragma unroll
            for (int mi = 0; mi < 2; ++mi) {
                int m = (mt_base + mi) * 16 + (l & 15);
                int c = t * 8 + s * 4 + (l >> 4);
                int slot = c ^ (l & 7);
                af[mi] = *(const short8*)(s_A + m * 128 + slot * 8);
            }
            #pragma unroll
            for (int ni = 0; ni < 2; ++ni)
                bfv[ni] = *(const short8*)(s_B + ((s * 4 + nt_base + ni) * 64 + l) * 8);
            #pragma unroll
            for (int mi = 0; mi < 2; ++mi)
                #pragma unroll
                for (int ni = 0; ni < 2; ++ni)
                    acc[mi][ni] = __builtin_amdgcn_mfma_f32_16x16x32_bf16(
                        af[mi], bfv[ni], acc[mi][ni], 0, 0, 0);
        }
    }
    #pragma unroll
    for (int mi = 0; mi < 2; ++mi) {
        #pragma unroll
        for (int ni = 0; ni < 2; ++ni) {
            int f = (nt_base + ni) * 16 + (l & 15);
            float bv = b[f];
            #pragma unroll
            for (int r = 0; r < 4; ++r) {
                int m = (mt_base + mi) * 16 + (l >> 4) * 4 + r;
                int gn = n0 + m;
                if (gn < NN)
                    out[(size_t)gn * IN_DIM + f] = gmask[gn] ? (acc[mi][ni][r] + bv) : 0.f;
            }
        }
    }
    if (tx < 192) {
        int i = tx / 3, c = tx % 3;
        int gn = n0 + i;
        if (gn < NN)
            out[(size_t)NN * IN_DIM + gn * 3 + c] = gmask[gn] ? x[gn * 3 + c] : 0.f;
    }
}

// ================= fallback path (atomic, scalar; used only if ws too small) =================
__global__ __launch_bounds__(256) void init_fb_kernel(
    const float* __restrict__ X_t, const int* __restrict__ edges,
    float* __restrict__ x, float* __restrict__ cnt)
{
    int gid = blockIdx.x * blockDim.x + threadIdx.x;
    int stride = gridDim.x * blockDim.x;
    for (int i = gid; i < NN * 3; i += stride) x[i] = X_t[i];
    for (int e = gid; e < NE; e += stride)
        atomicAdd(&cnt[edges[NE + e]], 1.0f);
}

__global__ __launch_bounds__(128) void node_mlp_kernel(
    const float* __restrict__ H_t, const float* __restrict__ cond,
    const float* __restrict__ t_in,
    const float* __restrict__ W0, const float* __restrict__ b0,
    const float* __restrict__ W1, const float* __restrict__ b1,
    const float* __restrict__ W2, const float* __restrict__ b2,
    float* __restrict__ h)
{
    __shared__ float s_feat[D0][20];
    __shared__ float s_h0[HID][20];
    __shared__ float s_h1[HID][20];
    int n0 = blockIdx.x * 16;
    int tx = threadIdx.x;

    for (int idx = tx; idx < 16 * IN_DIM; idx += 128) {
        int i = idx >> 6, k = idx & 63;
        s_feat[k][i] = H_t[(n0 + i) * IN_DIM + k];
    }
    for (int idx = tx; idx < 16 * HID; idx += 128) {
        int i = idx >> 7, k = idx & 127;
        s_feat[IN_DIM + k][i] = cond[(n0 + i) * HID + k];
    }
    const float cfr = -logf(10000.f) / 63.f;
    for (int idx = tx; idx < 16 * HID; idx += 128) {
        int i = idx >> 7, k = idx & 127;
        float tv = t_in[n0 + i];
        int jj = k & 63;
        float ang = tv * __expf(cfr * (float)jj);
        s_feat[IN_DIM + HID + k][i] = (k < 64) ? __sinf(ang) : __cosf(ang);
    }
    __syncthreads();

    float acc[16];
    {
        float bv = b0[tx];
        #pragma unroll
        for (int i = 0; i < 16; ++i) acc[i] = bv;
        for (int k = 0; k < D0; ++k) {
            float w = W0[k * HID + tx];
            float4 f0 = *(const float4*)&s_feat[k][0];
            float4 f1 = *(const float4*)&s_feat[k][4];
            float4 f2 = *(const float4*)&s_feat[k][8];
            float4 f3 = *(const float4*)&s_feat[k][12];
            acc[0] += f0.x*w; acc[1] += f0.y*w; acc[2] += f0.z*w; acc[3] += f0.w*w;
            acc[4] += f1.x*w; acc[5] += f1.y*w; acc[6] += f1.z*w; acc[7] += f1.w*w;
            acc[8] += f2.x*w; acc[9] += f2.y*w; acc[10]+= f2.z*w; acc[11]+= f2.w*w;
            acc[12]+= f3.x*w; acc[13]+= f3.y*w; acc[14]+= f3.z*w; acc[15]+= f3.w*w;
        }
        #pragma unroll
        for (int i = 0; i < 16; ++i) s_h0[tx][i] = fmaxf(acc[i], 0.f);
    }
    __syncthreads();
    {
        float bv = b1[tx];
        #pragma unroll
        for (int i = 0; i < 16; ++i) acc[i] = bv;
        for (int k = 0; k < HID; ++k) {
            float w = W1[k * HID + tx];
            float4 f0 = *(const float4*)&s_h0[k][0];
            float4 f1 = *(const float4*)&s_h0[k][4];
            float4 f2 = *(const float4*)&s_h0[k][8];
            float4 f3 = *(const float4*)&s_h0[k][12];
            acc[0] += f0.x*w; acc[1] += f0.y*w; acc[2] += f0.z*w; acc[3] += f0.w*w;
            acc[4] += f1.x*w; acc[5] += f1.y*w; acc[6] += f1.z*w; acc[7] += f1.w*w;
            acc[8] += f2.x*w; acc[9] += f2.y*w; acc[10]+= f2.z*w; acc[11]+= f2.w*w;
            acc[12]+= f3.x*w; acc[13]+= f3.y*w; acc[14]+= f3.z*w; acc[15]+= f3.w*w;
        }
        #pragma unroll
        for (int i = 0; i < 16; ++i) s_h1[tx][i] = fmaxf(acc[i], 0.f);
    }
    __syncthreads();
    {
        float bv = b2[tx];
        #pragma unroll
        for (int i = 0; i < 16; ++i) acc[i] = bv;
        for (int k = 0; k < HID; ++k) {
            float w = W2[k * HID + tx];
            float4 f0 = *(const float4*)&s_h1[k][0];
            float4 f1 = *(const float4*)&s_h1[k][4];
            float4 f2 = *(const float4*)&s_h1[k][8];
            float4 f3 = *(const float4*)&s_h1[k][12];
            acc[0] += f0.x*w; acc[1] += f0.y*w; acc[2] += f0.z*w; acc[3] += f0.w*w;
            acc[4] += f1.x*w; acc[5] += f1.y*w; acc[6] += f1.z*w; acc[7] += f1.w*w;
            acc[8] += f2.x*w; acc[9] += f2.y*w; acc[10]+= f2.z*w; acc[11]+= f2.w*w;
            acc[12]+= f3.x*w; acc[13]+= f3.y*w; acc[14]+= f3.z*w; acc[15]+= f3.w*w;
        }
        #pragma unroll
        for (int i = 0; i < 16; ++i) h[(n0 + i) * HID + tx] = acc[i];
    }
}

__global__ __launch_bounds__(256) void edge_gemm_fb_kernel(
    const float* __restrict__ h, const float* __restrict__ x,
    const int* __restrict__ edges, const int* __restrict__ etype,
    const float* __restrict__ edge_table,
    const float* __restrict__ We_l, const float* __restrict__ be_l,
    const float* __restrict__ Wx_l, const float* __restrict__ bx_l,
    float* __restrict__ agg_m, float* __restrict__ agg_x)
{
    __shared__ int s_src[TILE_E], s_dst[TILE_E];
    __shared__ float s_diff[TILE_E][3];
    __shared__ float s_tail[TILE_E][36];
    __shared__ float s_Af[TILE_E][36];
    __shared__ float s_Bf[33][HID];
    __shared__ float s_wx[HID];

    int e0 = blockIdx.x * TILE_E;
    int tx = threadIdx.x;
    int tf = tx & 15;
    int te = tx >> 4;

    if (tx < TILE_E) {
        int s = edges[e0 + tx];
        int d = edges[NE + e0 + tx];
        s_src[tx] = s; s_dst[tx] = d;
        float dx = x[s * 3 + 0] - x[d * 3 + 0];
        float dy = x[s * 3 + 1] - x[d * 3 + 1];
        float dz = x[s * 3 + 2] - x[d * 3 + 2];
        s_diff[tx][0] = dx; s_diff[tx][1] = dy; s_diff[tx][2] = dz;
        s_tail[tx][0] = dx * dx + dy * dy + dz * dz;
        int et = etype[e0 + tx];
        #pragma unroll
        for (int j = 0; j < 32; ++j) s_tail[tx][1 + j] = edge_table[et * 32 + j];
    }
    if (tx < HID) s_wx[tx] = Wx_l[tx];
    __syncthreads();

    float acc[4][8];
    #pragma unroll
    for (int i = 0; i < 4; ++i)
        #pragma unroll
        for (int j = 0; j < 8; ++j) acc[i][j] = 0.f;

    for (int t = 0; t < 9; ++t) {
        int k0 = t * 32;
        int klen = (t == 8) ? 33 : 32;
        __syncthreads();
        if (t < 8) {
            const bool use_src = (t < 4);
            int kbase = (t & 3) * 32;
            for (int q4 = tx; q4 < TILE_E * 8; q4 += 256) {
                int e = q4 >> 3, q = q4 & 7;
                int row = use_src ? s_src[e] : s_dst[e];
                float4 v = *(const float4*)&h[row * HID + kbase + q * 4];
                *(float4*)&s_Af[e][q * 4] = v;
            }
        }
        for (int q4 = tx; q4 < klen * 32; q4 += 256) {
            int kk = q4 >> 5, c4 = q4 & 31;
            float4 v = *(const float4*)&We_l[(k0 + kk) * HID + c4 * 4];
            *(float4*)&s_Bf[kk][c4 * 4] = v;
        }
        __syncthreads();
        const float (*Asrc)[36] = (t == 8) ? (const float (*)[36])s_tail
                                           : (const float (*)[36])s_Af;
        for (int kk = 0; kk < klen; ++kk) {
            float a0 = Asrc[te * 4 + 0][kk];
            float a1 = Asrc[te * 4 + 1][kk];
            float a2 = Asrc[te * 4 + 2][kk];
            float a3 = Asrc[te * 4 + 3][kk];
            float4 bv0 = *(const float4*)&s_Bf[kk][tf * 8];
            float4 bv1 = *(const float4*)&s_Bf[kk][tf * 8 + 4];
            float b[8] = {bv0.x, bv0.y, bv0.z, bv0.w, bv1.x, bv1.y, bv1.z, bv1.w};
            #pragma unroll
            for (int j = 0; j < 8; ++j) {
                acc[0][j] += a0 * b[j];
                acc[1][j] += a1 * b[j];
                acc[2][j] += a2 * b[j];
                acc[3][j] += a3 * b[j];
            }
        }
    }

    float wsum[4];
    #pragma unroll
    for (int i = 0; i < 4; ++i) {
        float p = 0.f;
        #pragma unroll
        for (int j = 0; j < 8; ++j) {
            int f = tf * 8 + j;
            float v = acc[i][j] + be_l[f];
            float m = silu(v);
            acc[i][j] = m;
            p += m * s_wx[f];
        }
        wsum[i] = p;
    }
    #pragma unroll
    for (int off = 1; off < 16; off <<= 1) {
        #pragma unroll
        for (int i = 0; i < 4; ++i) wsum[i] += __shfl_xor(wsum[i], off);
    }
    float bxv = bx_l[0];
    if (tf < 3) {
        #pragma unroll
        for (int i = 0; i < 4; ++i) {
            int e = te * 4 + i;
            float w2 = wsum[i] + bxv;
            atomicAdd(&agg_x[s_dst[e] * 3 + tf], s_diff[e][tf] * w2);
        }
    }
    #pragma unroll
    for (int i = 0; i < 4; ++i) {
        int d = s_dst[te * 4 + i];
        #pragma unroll
        for (int j = 0; j < 8; ++j)
            atomicAdd(&agg_m[d * HID + tf * 8 + j], acc[i][j]);
    }
}

__global__ __launch_bounds__(128) void node_update_fb_kernel(
    float* __restrict__ h, float* __restrict__ x,
    const float* __restrict__ agg_m, const float* __restrict__ agg_x,
    const float* __restrict__ cnt,
    const float* __restrict__ Wh_l, const float* __restrict__ bh_l)
{
    __shared__ float s_in[256][20];
    int n0 = blockIdx.x * 16;
    int tx = threadIdx.x;
    for (int idx = tx; idx < 16 * HID; idx += 128) {
        int i = idx >> 7, k = idx & 127;
        s_in[k][i] = h[(n0 + i) * HID + k];
    }
    for (int idx = tx; idx < 16 * HID; idx += 128) {
        int i = idx >> 7, k = idx & 127;
        s_in[HID + k][i] = agg_m[(n0 + i) * HID + k];
    }
    __syncthreads();
    float acc[16];
    float bv = bh_l[tx];
    #pragma unroll
    for (int i = 0; i < 16; ++i) acc[i] = bv;
    for (int k = 0; k < 256; ++k) {
        float w = Wh_l[k * HID + tx];
        float4 f0 = *(const float4*)&s_in[k][0];
        float4 f1 = *(const float4*)&s_in[k][4];
        float4 f2 = *(const float4*)&s_in[k][8];
        float4 f3 = *(const float4*)&s_in[k][12];
        acc[0] += f0.x*w; acc[1] += f0.y*w; acc[2] += f0.z*w; acc[3] += f0.w*w;
        acc[4] += f1.x*w; acc[5] += f1.y*w; acc[6] += f1.z*w; acc[7] += f1.w*w;
        acc[8] += f2.x*w; acc[9] += f2.y*w; acc[10]+= f2.z*w; acc[11]+= f2.w*w;
        acc[12]+= f3.x*w; acc[13]+= f3.y*w; acc[14]+= f3.z*w; acc[15]+= f3.w*w;
    }
    #pragma unroll
    for (int i = 0; i < 16; ++i) {
        float v = acc[i];
        h[(n0 + i) * HID + tx] = s_in[tx][i] + silu(v);
    }
    if (tx < 48) {
        int i = tx / 3, c = tx % 3;
        int n = n0 + i;
        x[n * 3 + c] += agg_x[n * 3 + c] / (cnt[n] + 1.f);
    }
}

__global__ __launch_bounds__(64) void final_fb_kernel(
    const float* __restrict__ h, const float* __restrict__ x,
    const int* __restrict__ gmask,
    const float* __restrict__ W, const float* __restrict__ b,
    float* __restrict__ out)
{
    __shared__ float s_h[8][HID];
    int n0 = blockIdx.x * 8;
    int tx = threadIdx.x;
    for (int idx = tx; idx < 8 * HID; idx += 64) {
        int i = idx >> 7, k = idx & 127;
        s_h[i][k] = h[(n0 + i) * HID + k];
    }
    __syncthreads();
    float acc[8];
    float bv = b[tx];
    #pragma unroll
    for (int i = 0; i < 8; ++i) acc[i] = bv;
    for (int k = 0; k < HID; ++k) {
        float w = W[k * IN_DIM + tx];
        #pragma unroll
        for (int i = 0; i < 8; ++i) acc[i] += s_h[i][k] * w;
    }
    #pragma unroll
    for (int i = 0; i < 8; ++i) {
        int n = n0 + i;
        out[n * IN_DIM + tx] = gmask[n] ? acc[i] : 0.f;
    }
    if (tx < 24) {
        int i = tx / 3, c = tx % 3;
        int n = n0 + i;
        out[NN * IN_DIM + n * 3 + c] = gmask[n] ? x[n * 3 + c] : 0.f;
    }
}

extern "C" void kernel_launch(void* const* d_in, const int* in_sizes, int n_in,
                              void* d_out, int out_size, void* d_ws, size_t ws_size,
                              hipStream_t stream) {
    const float* H_t   = (const float*)d_in[0];
    const float* X_t   = (const float*)d_in[1];
    const float* cond  = (const float*)d_in[2];
    const float* t_in  = (const float*)d_in[3];
    const int*   edges = (const int*)d_in[4];
    const int*   etype = (const int*)d_in[5];
    const int*   gmask = (const int*)d_in[6];
    const float* W0 = (const float*)d_in[8];
    const float* b0 = (const float*)d_in[9];
    const float* W1 = (const float*)d_in[10];
    const float* b1 = (const float*)d_in[11];
    const float* W2 = (const float*)d_in[12];
    const float* b2 = (const float*)d_in[13];
    const float* edge_table = (const float*)d_in[14];
    const float* We = (const float*)d_in[15];
    const float* be = (const float*)d_in[16];
    const float* Wx = (const float*)d_in[17];
    const float* bx = (const float*)d_in[18];
    const float* Wh = (const float*)d_in[19];
    const float* bh = (const float*)d_in[20];
    const float* h2i_W = (const float*)d_in[21];
    const float* h2i_b = (const float*)d_in[22];

    char* p = (char*)d_ws;
    float* h = (float*)p;           p += (size_t)NN * HID * 4;
    u16* h_bf = (u16*)p;            p += (size_t)NN * HID * 2;
    float* xa = (float*)p;          p += (size_t)NN * 3 * 4;
    float* xb = (float*)p;          p += (size_t)NN * 3 * 4;
    u16* Csrc = (u16*)p;            p += (size_t)NN * 128 * 2;
    u16* Cdst = (u16*)p;            p += (size_t)NN * 128 * 2;
    u16* Bpack = (u16*)p;           p += (size_t)PACK_TOT * 2;
    float* tv = (float*)p;          p += (size_t)768 * 4;
    float* wed2 = (float*)p;        p += (size_t)384 * 4;
    int* row_start = (int*)p;       p += (size_t)(NN + 4) * 4;
    int* deg = (int*)p;             p += (size_t)NN * 4;
    int* head = (int*)p;            p += (size_t)NN * 4;
    int* src_s = (int*)p;           p += (size_t)NE * 4;
    size_t need = (size_t)(p - (char*)d_ws);

    if (ws_size >= need) {
        hipMemsetAsync(deg, 0, NN * sizeof(int), stream);
        hist_kernel<<<256, 256, 0, stream>>>(X_t, edges, xa, deg);
        scan_kernel<<<1, 1024, 0, stream>>>(deg, row_start, head);
        scatter_kernel<<<256, 256, 0, stream>>>(edges, etype, head, src_s);
        pack_all_kernel<<<(PACK_TOT + 255) / 256, 256, 0, stream>>>(
            We, W0, W1, W2, Wh, h2i_W, Bpack);
        precomp_tv_kernel<<<5, 256, 0, stream>>>(edge_table, We, be, tv, wed2);
        node_mlp_mfma_kernel<<<NB64, 256, 0, stream>>>(
            H_t, cond, t_in,
            Bpack + OFF_W0, b0, Bpack + OFF_W1, b1, Bpack + OFF_W2, b2,
            Bpack + OFF_WE, Csrc, Cdst,
            h, h_bf);
        for (int l = 0; l < 3; ++l) {
            if (l > 0)
                cvec_kernel<<<NB64, 256, 0, stream>>>(
                    h_bf, Bpack + OFF_WE + (size_t)l * 40960, Csrc, Cdst);
            const float* xin = (l & 1) ? xb : xa;
            float* xout = (l & 1) ? xa : xb;
            node_fused_kernel<<<NN / NUB, 512, 0, stream>>>(
                h, h_bf, xin, xout, Csrc, Cdst, src_s, row_start,
                tv + (size_t)l * 256, wed2 + (size_t)l * 128,
                Wx + l * HID, bx + l,
                Bpack + OFF_WH + (size_t)l * 32768, bh + l * HID);
        }
        // layers: l0 xa->xb, l1 xb->xa, l2 xa->xb  => final x lives in xb
        final_mfma_kernel<<<NB64, 256, 0, stream>>>(
            h_bf, xb, gmask, Bpack + OFF_H2I, h2i_b, (float*)d_out);
    } else {
        // fallback: scalar atomic path (~21 MB)
        float* ws    = (float*)d_ws;
        float* fh    = ws;
        float* fx    = fh + NN * HID;
        float* cnt   = fx + NN * 3;
        float* fagg_m = cnt + NN;
        float* fagg_x = fagg_m + NN * HID;

        hipMemsetAsync(cnt, 0, NN * sizeof(float), stream);
        init_fb_kernel<<<256, 256, 0, stream>>>(X_t, edges, fx, cnt);
        node_mlp_kernel<<<NN / 16, 128, 0, stream>>>(H_t, cond, t_in,
                                                     W0, b0, W1, b1, W2, b2, fh);
        for (int l = 0; l < 3; ++l) {
            hipMemsetAsync(fagg_m, 0, (size_t)NN * 131 * sizeof(float), stream);
            edge_gemm_fb_kernel<<<NE / TILE_E, 256, 0, stream>>>(
                fh, fx, edges, etype, edge_table,
                We + (size_t)l * DE * HID, be + l * HID,
                Wx + l * HID, bx + l, fagg_m, fagg_x);
            node_update_fb_kernel<<<NN / 16, 128, 0, stream>>>(
                fh, fx, fagg_m, fagg_x, cnt,
                Wh + (size_t)l * 256 * HID, bh + l * HID);
        }
        final_fb_kernel<<<NN / 8, 64, 0, stream>>>(fh, fx, gmask, h2i_W, h2i_b, (float*)d_out);
    }
}

// Round 6
// 371.153 us; speedup vs baseline: 1.0758x; 1.0149x over previous
//
#include <hip/hip_runtime.h>
#include <math.h>

#define NN 20000
#define NE 256000
#define IN_DIM 64
#define HID 128
#define DE 289     // 2*HID + 1 + 32
#define D0 320     // IN_DIM + 2*HID
#define TILE_E 64
#define NB64 313   // ceil(NN/64)
#define NUB 8      // nodes per block (fused node kernel)
#define SRCMASK 0x3FFFFFFF

typedef unsigned short u16;
typedef unsigned int u32;
typedef unsigned long long u64;
typedef __attribute__((ext_vector_type(8))) short short8;
typedef __attribute__((ext_vector_type(4))) float float4v;

// Bpack layout offsets (u16 elements)
#define OFF_WE   0          // 3 x 40960 (K=289 pad 320, N=128) — tiles 0..3 = We rows 0..255
#define OFF_W0   122880     // 40960 (K=320, N=128)
#define OFF_W1   163840     // 16384 (K=128, N=128)
#define OFF_W2   180224     // 16384
#define OFF_WH   196608     // 3 x 32768 (K=256, N=128)
#define OFF_H2I  294912     // 8192 (K=128, N=64)
#define PACK_TOT 303104
#define PREP_TOT (PACK_TOT + 1152 + NN)   // pack + tv/wed2 + deg-zero

static __device__ __forceinline__ u16 f2bf(float f) {
    unsigned int u = __float_as_uint(f);
    u += 0x7fffu + ((u >> 16) & 1u);
    return (u16)(u >> 16);
}
static __device__ __forceinline__ float bf2f(u16 s) {
    return __uint_as_float(((unsigned int)s) << 16);
}
static __device__ __forceinline__ float bflo(u32 u) { return bf2f((u16)(u & 0xffffu)); }
static __device__ __forceinline__ float bfhi(u32 u) { return bf2f((u16)(u >> 16)); }
static __device__ __forceinline__ u32 pack2(float a, float b) {
    return (u32)f2bf(a) | ((u32)f2bf(b) << 16);
}
static __device__ __forceinline__ uint4 pack8(const float* v) {
    uint4 r;
    r.x = (u32)f2bf(v[0]) | ((u32)f2bf(v[1]) << 16);
    r.y = (u32)f2bf(v[2]) | ((u32)f2bf(v[3]) << 16);
    r.z = (u32)f2bf(v[4]) | ((u32)f2bf(v[5]) << 16);
    r.w = (u32)f2bf(v[6]) | ((u32)f2bf(v[7]) << 16);
    return r;
}
static __device__ __forceinline__ float silu(float v) {
    return v * (1.f / (1.f + __expf(-v)));
}

// ================= CSR build =================
__global__ __launch_bounds__(256) void hist_kernel(
    const float* __restrict__ X_t, const int* __restrict__ edges,
    float* __restrict__ x, int* __restrict__ deg)
{
    int gid = blockIdx.x * blockDim.x + threadIdx.x;
    int stride = gridDim.x * blockDim.x;
    for (int i = gid; i < NN * 3; i += stride) x[i] = X_t[i];
    for (int e = gid; e < NE; e += stride)
        atomicAdd(&deg[edges[NE + e]], 1);
}

__global__ __launch_bounds__(1024) void scan_kernel(
    const int* __restrict__ deg, int* __restrict__ row_start, int* __restrict__ head)
{
    __shared__ int s[1024];
    int tx = threadIdx.x;
    const int per = (NN + 1023) / 1024;
    int st = tx * per, en = st + per;
    if (st > NN) st = NN;
    if (en > NN) en = NN;
    int sum = 0;
    for (int i = st; i < en; ++i) sum += deg[i];
    s[tx] = sum;
    __syncthreads();
    for (int off = 1; off < 1024; off <<= 1) {
        int t = (tx >= off) ? s[tx - off] : 0;
        __syncthreads();
        s[tx] += t;
        __syncthreads();
    }
    int run = (tx == 0) ? 0 : s[tx - 1];
    for (int i = st; i < en; ++i) {
        row_start[i] = run; head[i] = run; run += deg[i];
    }
    if (tx == 1023) row_start[NN] = run;
}

// permute edges into dst-sorted order; pack etype into src bit 30
__global__ __launch_bounds__(256) void scatter_kernel(
    const int* __restrict__ edges, const int* __restrict__ etype,
    int* __restrict__ head,
    int* __restrict__ src_s)
{
    int gid = blockIdx.x * blockDim.x + threadIdx.x;
    int stride = gridDim.x * blockDim.x;
    for (int e = gid; e < NE; e += stride) {
        int d = edges[NE + e];
        int p = atomicAdd(&head[d], 1);
        src_s[p] = edges[e] | (etype[e] << 30);
    }
}

// ================= combined prep: weight packing + edge tail precompute + deg zero =================
__global__ __launch_bounds__(256) void prep_kernel(
    const float* __restrict__ We, const float* __restrict__ W0,
    const float* __restrict__ W1, const float* __restrict__ W2,
    const float* __restrict__ Wh, const float* __restrict__ h2i,
    const float* __restrict__ edge_table, const float* __restrict__ be,
    u16* __restrict__ Bp, float* __restrict__ tv, float* __restrict__ wed2,
    int* __restrict__ deg)
{
    int idx = blockIdx.x * 256 + threadIdx.x;
    if (idx < PACK_TOT) {
        const float* src; int N = 128, Ksrc; int r;
        if (idx < OFF_W0) {
            int layer = idx / 40960; r = idx - layer * 40960;
            src = We + (size_t)layer * DE * HID; Ksrc = DE;
        } else if (idx < OFF_W1) { r = idx - OFF_W0; src = W0; Ksrc = 320; }
        else if (idx < OFF_W2)   { r = idx - OFF_W1; src = W1; Ksrc = 128; }
        else if (idx < OFF_WH)   { r = idx - OFF_W2; src = W2; Ksrc = 128; }
        else if (idx < OFF_H2I) {
            int t = idx - OFF_WH; int layer = t / 32768; r = t - layer * 32768;
            src = Wh + (size_t)layer * 256 * HID; Ksrc = 256;
        } else { r = idx - OFF_H2I; src = h2i; Ksrc = 128; N = 64; }
        int ntc = N / 16;
        int j = r & 7, lane = (r >> 3) & 63;
        int rem = r >> 9;
        int nt = rem % ntc, ks = rem / ntc;
        int k = ks * 32 + ((lane >> 4) << 3) + j;
        int c = nt * 16 + (lane & 15);
        Bp[idx] = f2bf((k < Ksrc) ? src[(size_t)k * N + c] : 0.f);
    } else if (idx < PACK_TOT + 768) {
        int q = idx - PACK_TOT;
        int f = q & 127, t = (q >> 7) & 1, l = q >> 8;
        float acc = be[l * 128 + f];
        const float* W = We + (size_t)l * DE * HID;
        #pragma unroll
        for (int k = 0; k < 32; ++k)
            acc += edge_table[t * 32 + k] * W[(size_t)(257 + k) * HID + f];
        tv[l * 256 + t * 128 + f] = acc;
    } else if (idx < PACK_TOT + 1152) {
        int r = idx - PACK_TOT - 768;
        int f = r & 127, l = r >> 7;
        wed2[l * 128 + f] = We[(size_t)l * DE * HID + (size_t)256 * HID + f];
    } else if (idx < PREP_TOT) {
        deg[idx - PACK_TOT - 1152] = 0;
    }
}

// ================= node MLP: MFMA, 64 nodes/block + fused cvec layer-0 =================
__global__ __launch_bounds__(256) void node_mlp_mfma_kernel(
    const float* __restrict__ H_t, const float* __restrict__ cond,
    const float* __restrict__ t_in,
    const u16* __restrict__ W0p, const float* __restrict__ b0,
    const u16* __restrict__ W1p, const float* __restrict__ b1,
    const u16* __restrict__ W2p, const float* __restrict__ b2,
    const u16* __restrict__ WEp,
    u16* __restrict__ Csrc, u16* __restrict__ Cdst,
    float* __restrict__ h, u16* __restrict__ h_bf)
{
    __shared__ u16 s_A[64 * 64];
    __shared__ u16 s_B[64 * 128];
    __shared__ u16 s_h[64 * 128];
    __shared__ float s_t[64];

    int tx = threadIdx.x;
    int n0 = blockIdx.x * 64;
    int l = tx & 63, w = tx >> 6;
    int mt_base = (w & 1) * 2, nt_base = (w >> 1) * 4;
    const float cfr = -logf(10000.f) / 63.f;

    if (tx < 64) s_t[tx] = (n0 + tx < NN) ? t_in[n0 + tx] : 0.f;

    float4v acc[2][4];
    #pragma unroll
    for (int mi = 0; mi < 2; ++mi)
        #pragma unroll
        for (int ni = 0; ni < 4; ++ni) acc[mi][ni] = (float4v){0.f,0.f,0.f,0.f};

    for (int t = 0; t < 5; ++t) {
        __syncthreads();
        #pragma unroll
        for (int it = 0; it < 2; ++it) {
            int flat = it * 256 + tx;
            int n = flat >> 3, sl = flat & 7;
            int c = sl ^ (n & 7);
            int k0 = t * 64 + c * 8;
            float tv8[8];
            int gn = n0 + n;
            if (gn < NN) {
                if (k0 < 192) {
                    const float* src = (k0 < 64) ? &H_t[(size_t)gn * IN_DIM + k0]
                                                 : &cond[(size_t)gn * HID + (k0 - 64)];
                    float4 a = *(const float4*)src;
                    float4 b = *(const float4*)(src + 4);
                    tv8[0]=a.x; tv8[1]=a.y; tv8[2]=a.z; tv8[3]=a.w;
                    tv8[4]=b.x; tv8[5]=b.y; tv8[6]=b.z; tv8[7]=b.w;
                } else {
                    float tvv = s_t[n];
                    int jj = (k0 - 192) & 63;
                    bool is_sin = (k0 < 256);
                    #pragma unroll
                    for (int jx = 0; jx < 8; ++jx) {
                        float ang = tvv * __expf(cfr * (float)(jj + jx));
                        tv8[jx] = is_sin ? __sinf(ang) : __cosf(ang);
                    }
                }
            } else {
                #pragma unroll
                for (int jx = 0; jx < 8; ++jx) tv8[jx] = 0.f;
            }
            *(uint4*)&s_A[n * 64 + sl * 8] = pack8(tv8);
        }
        #pragma unroll
        for (int it = 0; it < 4; ++it) {
            int flat = it * 256 + tx;
            ((uint4*)s_B)[flat] = ((const uint4*)(W0p + (size_t)t * 8192))[flat];
        }
        __syncthreads();
        #pragma unroll
        for (int s = 0; s < 2; ++s) {
            short8 af[2], bfv[4];
            #pragma unroll
            for (int mi = 0; mi < 2; ++mi) {
                int m = (mt_base + mi) * 16 + (l & 15);
                int c = s * 4 + (l >> 4);
                int slot = c ^ (l & 7);
                af[mi] = *(const short8*)(s_A + m * 64 + slot * 8);
            }
            #pragma unroll
            for (int ni = 0; ni < 4; ++ni)
                bfv[ni] = *(const short8*)(s_B + ((s * 8 + nt_base + ni) * 64 + l) * 8);
            #pragma unroll
            for (int mi = 0; mi < 2; ++mi)
                #pragma unroll
                for (int ni = 0; ni < 4; ++ni)
                    acc[mi][ni] = __builtin_amdgcn_mfma_f32_16x16x32_bf16(
                        af[mi], bfv[ni], acc[mi][ni], 0, 0, 0);
        }
    }
    #pragma unroll
    for (int mi = 0; mi < 2; ++mi) {
        #pragma unroll
        for (int ni = 0; ni < 4; ++ni) {
            int f = (nt_base + ni) * 16 + (l & 15);
            float bv = b0[f];
            #pragma unroll
            for (int r = 0; r < 4; ++r) {
                int m = (mt_base + mi) * 16 + (l >> 4) * 4 + r;
                float v = fmaxf(acc[mi][ni][r] + bv, 0.f);
                int slot = (f >> 3) ^ (m & 7);
                s_h[m * 128 + slot * 8 + (f & 7)] = f2bf(v);
            }
            acc[mi][ni] = (float4v){0.f,0.f,0.f,0.f};
        }
    }
    for (int t = 0; t < 2; ++t) {
        __syncthreads();
        #pragma unroll
        for (int it = 0; it < 4; ++it) {
            int flat = it * 256 + tx;
            ((uint4*)s_B)[flat] = ((const uint4*)(W1p + (size_t)t * 8192))[flat];
        }
        __syncthreads();
        #pragma unroll
        for (int s = 0; s < 2; ++s) {
            short8 af[2], bfv[4];
            #pragma unroll
            for (int mi = 0; mi < 2; ++mi) {
                int m = (mt_base + mi) * 16 + (l & 15);
                int c = t * 8 + s * 4 + (l >> 4);
                int slot = c ^ (l & 7);
                af[mi] = *(const short8*)(s_h + m * 128 + slot * 8);
            }
            #pragma unroll
            for (int ni = 0; ni < 4; ++ni)
                bfv[ni] = *(const short8*)(s_B + ((s * 8 + nt_base + ni) * 64 + l) * 8);
            #pragma unroll
            for (int mi = 0; mi < 2; ++mi)
                #pragma unroll
                for (int ni = 0; ni < 4; ++ni)
                    acc[mi][ni] = __builtin_amdgcn_mfma_f32_16x16x32_bf16(
                        af[mi], bfv[ni], acc[mi][ni], 0, 0, 0);
        }
    }
    __syncthreads();
    #pragma unroll
    for (int mi = 0; mi < 2; ++mi) {
        #pragma unroll
        for (int ni = 0; ni < 4; ++ni) {
            int f = (nt_base + ni) * 16 + (l & 15);
            float bv = b1[f];
            #pragma unroll
            for (int r = 0; r < 4; ++r) {
                int m = (mt_base + mi) * 16 + (l >> 4) * 4 + r;
                float v = fmaxf(acc[mi][ni][r] + bv, 0.f);
                int slot = (f >> 3) ^ (m & 7);
                s_h[m * 128 + slot * 8 + (f & 7)] = f2bf(v);
            }
            acc[mi][ni] = (float4v){0.f,0.f,0.f,0.f};
        }
    }
    for (int t = 0; t < 2; ++t) {
        __syncthreads();
        #pragma unroll
        for (int it = 0; it < 4; ++it) {
            int flat = it * 256 + tx;
            ((uint4*)s_B)[flat] = ((const uint4*)(W2p + (size_t)t * 8192))[flat];
        }
        __syncthreads();
        #pragma unroll
        for (int s = 0; s < 2; ++s) {
            short8 af[2], bfv[4];
            #pragma unroll
            for (int mi = 0; mi < 2; ++mi) {
                int m = (mt_base + mi) * 16 + (l & 15);
                int c = t * 8 + s * 4 + (l >> 4);
                int slot = c ^ (l & 7);
                af[mi] = *(const short8*)(s_h + m * 128 + slot * 8);
            }
            #pragma unroll
            for (int ni = 0; ni < 4; ++ni)
                bfv[ni] = *(const short8*)(s_B + ((s * 8 + nt_base + ni) * 64 + l) * 8);
            #pragma unroll
            for (int mi = 0; mi < 2; ++mi)
                #pragma unroll
                for (int ni = 0; ni < 4; ++ni)
                    acc[mi][ni] = __builtin_amdgcn_mfma_f32_16x16x32_bf16(
                        af[mi], bfv[ni], acc[mi][ni], 0, 0, 0);
        }
    }
    // final h: write globals AND store into s_h (swizzled) for the fused cvec
    __syncthreads();   // protect s_h against pending W2-stage reads
    #pragma unroll
    for (int mi = 0; mi < 2; ++mi) {
        #pragma unroll
        for (int ni = 0; ni < 4; ++ni) {
            int f = (nt_base + ni) * 16 + (l & 15);
            float bv = b2[f];
            #pragma unroll
            for (int r = 0; r < 4; ++r) {
                int m = (mt_base + mi) * 16 + (l >> 4) * 4 + r;
                int gn = n0 + m;
                float v = acc[mi][ni][r] + bv;
                int slot = (f >> 3) ^ (m & 7);
                s_h[m * 128 + slot * 8 + (f & 7)] = f2bf(v);
                if (gn < NN) {
                    h[(size_t)gn * HID + f] = v;
                    h_bf[(size_t)gn * HID + f] = f2bf(v);
                }
            }
        }
    }

    // ---- fused cvec (layer 0): Csrc[n]=h@We_src, Cdst[n]=h@We_dst ----
    for (int sd = 0; sd < 2; ++sd) {
        #pragma unroll
        for (int mi = 0; mi < 2; ++mi)
            #pragma unroll
            for (int ni = 0; ni < 4; ++ni) acc[mi][ni] = (float4v){0.f,0.f,0.f,0.f};
        #pragma unroll
        for (int th = 0; th < 2; ++th) {
            int t = sd * 2 + th;
            __syncthreads();
            #pragma unroll
            for (int it = 0; it < 4; ++it) {
                int flat = it * 256 + tx;
                ((uint4*)s_B)[flat] = ((const uint4*)(WEp + (size_t)t * 8192))[flat];
            }
            __syncthreads();
            #pragma unroll
            for (int s = 0; s < 2; ++s) {
                short8 af[2], bfv[4];
                #pragma unroll
                for (int mi = 0; mi < 2; ++mi) {
                    int m = (mt_base + mi) * 16 + (l & 15);
                    int c = th * 8 + s * 4 + (l >> 4);
                    int slot = c ^ (l & 7);
                    af[mi] = *(const short8*)(s_h + m * 128 + slot * 8);
                }
                #pragma unroll
                for (int ni = 0; ni < 4; ++ni)
                    bfv[ni] = *(const short8*)(s_B + ((s * 8 + nt_base + ni) * 64 + l) * 8);
                #pragma unroll
                for (int mi = 0; mi < 2; ++mi)
                    #pragma unroll
                    for (int ni = 0; ni < 4; ++ni)
                        acc[mi][ni] = __builtin_amdgcn_mfma_f32_16x16x32_bf16(
                            af[mi], bfv[ni], acc[mi][ni], 0, 0, 0);
            }
        }
        u16* Cout = (sd == 0) ? Csrc : Cdst;
        #pragma unroll
        for (int mi = 0; mi < 2; ++mi) {
            #pragma unroll
            for (int ni = 0; ni < 4; ++ni) {
                int fq = (nt_base + ni) * 16 + (l & 15);
                #pragma unroll
                for (int r = 0; r < 4; ++r) {
                    int m = (mt_base + mi) * 16 + (l >> 4) * 4 + r;
                    int gn = n0 + m;
                    if (gn < NN)
                        Cout[(size_t)gn * 128 + fq] = f2bf(acc[mi][ni][r]);
                }
            }
        }
    }
}

// ================= cvec (layers 1,2): Csrc[n]=h@We_src, Cdst[n]=h@We_dst =================
__global__ __launch_bounds__(256) void cvec_kernel(
    const u16* __restrict__ h_bf, const u16* __restrict__ WEp,
    u16* __restrict__ Csrc, u16* __restrict__ Cdst)
{
    __shared__ u16 s_A[64 * 64];
    __shared__ u16 s_B[64 * 128];

    int tx = threadIdx.x;
    int n0 = blockIdx.x * 64;
    int l = tx & 63, w = tx >> 6;
    int mt_base = (w & 1) * 2, nt_base = (w >> 1) * 4;

    float4v acc[2][2][4];  // [side][mi][ni]
    #pragma unroll
    for (int sd = 0; sd < 2; ++sd)
        #pragma unroll
        for (int mi = 0; mi < 2; ++mi)
            #pragma unroll
            for (int ni = 0; ni < 4; ++ni)
                acc[sd][mi][ni] = (float4v){0.f,0.f,0.f,0.f};

    for (int t = 0; t < 4; ++t) {
        __syncthreads();
        #pragma unroll
        for (int it = 0; it < 2; ++it) {
            int flat = it * 256 + tx;
            int n = flat >> 3, sl = flat & 7;
            int c = sl ^ (n & 7);
            int gn = n0 + n;
            uint4 v = make_uint4(0,0,0,0);
            if (gn < NN) v = *(const uint4*)(h_bf + (size_t)gn * 128 + (t & 1) * 64 + c * 8);
            *(uint4*)&s_A[n * 64 + sl * 8] = v;
        }
        #pragma unroll
        for (int it = 0; it < 4; ++it) {
            int flat = it * 256 + tx;
            ((uint4*)s_B)[flat] = ((const uint4*)(WEp + (size_t)t * 8192))[flat];
        }
        __syncthreads();
        int sd = t >> 1;
        #pragma unroll
        for (int s = 0; s < 2; ++s) {
            short8 af[2], bfv[4];
            #pragma unroll
            for (int mi = 0; mi < 2; ++mi) {
                int m = (mt_base + mi) * 16 + (l & 15);
                int c = s * 4 + (l >> 4);
                int slot = c ^ (l & 7);
                af[mi] = *(const short8*)(s_A + m * 64 + slot * 8);
            }
            #pragma unroll
            for (int ni = 0; ni < 4; ++ni)
                bfv[ni] = *(const short8*)(s_B + ((s * 8 + nt_base + ni) * 64 + l) * 8);
            #pragma unroll
            for (int mi = 0; mi < 2; ++mi)
                #pragma unroll
                for (int ni = 0; ni < 4; ++ni)
                    acc[sd][mi][ni] = __builtin_amdgcn_mfma_f32_16x16x32_bf16(
                        af[mi], bfv[ni], acc[sd][mi][ni], 0, 0, 0);
        }
    }
    #pragma unroll
    for (int sd = 0; sd < 2; ++sd) {
        u16* Cout = (sd == 0) ? Csrc : Cdst;
        #pragma unroll
        for (int mi = 0; mi < 2; ++mi) {
            #pragma unroll
            for (int ni = 0; ni < 4; ++ni) {
                int fq = (nt_base + ni) * 16 + (l & 15);
                #pragma unroll
                for (int r = 0; r < 4; ++r) {
                    int m = (mt_base + mi) * 16 + (l >> 4) * 4 + r;
                    int gn = n0 + m;
                    if (gn < NN)
                        Cout[(size_t)gn * 128 + fq] = f2bf(acc[sd][mi][ni][r]);
                }
            }
        }
    }
}

// ================= fused node update v6: 8-deep gather pipeline per parity =================
// NUB=8 nodes/block, 512 thr, wave w = node w. Wave-private edge staging:
//  - lane l holds edge l's src|et and geometry in REGISTERS (no LDS, no pre-loop barrier)
//  - consume-time broadcast via __shfl (ds_bpermute)
//  - 8-deep Csrc gather pipeline per parity (16 gathers in flight per wave)
//  - single block barrier (before Wh GEMM); Wh B-fragments straight from L2
__global__ __launch_bounds__(512, 4) void node_fused_kernel(
    float* __restrict__ h, u16* __restrict__ h_bf,
    const float* __restrict__ x_in, float* __restrict__ x_out,
    const u16* __restrict__ Csrc, const u16* __restrict__ Cdst,
    const int* __restrict__ src_s,
    const int* __restrict__ row_start,
    const float* __restrict__ tv_l, const float* __restrict__ wed2_l,
    const float* __restrict__ Wx_l, const float* __restrict__ bx_l,
    const u16* __restrict__ Whp_l, const float* __restrict__ bh_l)
{
    __shared__ u16 s_A[16 * 256];      // 8 KB: rows 0..7 = [h | agg] xor-swizzled, rows 8..15 zero

    int tx = threadIdx.x;
    int n0 = blockIdx.x * NUB;
    int l = tx & 63, w = tx >> 6;      // 8 waves; wave w owns node i = w
    int i = w;
    int gn = n0 + i;
    int p = l & 31, q = l >> 5;        // feat-chunk (4 feats), edge parity

    // ---- stage h rows (0..7) + zero pad rows (chunks 0..15) ----
    if (tx < 256) {
        int n = tx >> 4, c = tx & 15;
        int slot = c ^ (n & 7);
        uint4 v = make_uint4(0, 0, 0, 0);
        if (n < NUB) v = *(const uint4*)(h_bf + (size_t)(n0 + n) * 128 + c * 8);
        *(uint4*)&s_A[n * 256 + slot * 8] = v;
    } else if (tx < 384) {
        int n = 8 + ((tx - 256) >> 4), c = 16 + (tx & 15);
        int slot = c ^ (n & 7);
        *(uint4*)&s_A[n * 256 + slot * 8] = make_uint4(0, 0, 0, 0);
    }

    // ---- per-thread constants (4 feats) ----
    float c0[4], d01[4], wed[4], wx[4];
    {
        uint2 cd = *(const uint2*)(Cdst + (size_t)gn * 128 + p * 4);
        float cdv0 = bflo(cd.x), cdv1 = bfhi(cd.x), cdv2 = bflo(cd.y), cdv3 = bfhi(cd.y);
        float4 t0 = *(const float4*)(tv_l + p * 4);
        float4 t1 = *(const float4*)(tv_l + 128 + p * 4);
        float4 wd = *(const float4*)(wed2_l + p * 4);
        float4 wv = *(const float4*)(Wx_l + p * 4);
        c0[0] = t0.x + cdv0; c0[1] = t0.y + cdv1; c0[2] = t0.z + cdv2; c0[3] = t0.w + cdv3;
        d01[0] = t1.x - t0.x; d01[1] = t1.y - t0.y; d01[2] = t1.z - t0.z; d01[3] = t1.w - t0.w;
        wed[0] = wd.x; wed[1] = wd.y; wed[2] = wd.z; wed[3] = wd.w;
        wx[0] = wv.x; wx[1] = wv.y; wx[2] = wv.z; wx[3] = wv.w;
    }
    float bx32 = bx_l[0] * (1.f / 32.f);

    int rs = row_start[gn], re = row_start[gn + 1];
    int d = re - rs;

    // own-node coords (wave-uniform)
    float xd0 = x_in[gn * 3 + 0], xd1 = x_in[gn * 3 + 1], xd2 = x_in[gn * 3 + 2];

    float ag[4] = {0.f, 0.f, 0.f, 0.f};
    float sx = 0.f, sy = 0.f, sz = 0.f;

    for (int e0 = 0; e0 < d; e0 += 64) {
        int nchunk = d - e0; if (nchunk > 64) nchunk = 64;
        // stage: lane l holds edge (e0+l)
        int sp_l = (l < nchunk) ? src_s[rs + e0 + l] : 0;
        float gx_l = 0.f, gy_l = 0.f, gz_l = 0.f, d2_l = 0.f;
        if (l < nchunk) {
            int sm = sp_l & SRCMASK;
            gx_l = x_in[sm * 3 + 0] - xd0;
            gy_l = x_in[sm * 3 + 1] - xd1;
            gz_l = x_in[sm * 3 + 2] - xd2;
            d2_l = gx_l * gx_l + gy_l * gy_l + gz_l * gz_l;
        }

        auto FETCH = [&](int lj, uint2& cc, float& et) {
            int spE = __shfl(sp_l, lj);
            cc = make_uint2(0u, 0u); et = 0.f;
            if (lj < nchunk) {
                cc = *(const uint2*)(Csrc + (size_t)(spE & SRCMASK) * 128 + p * 4);
                et = (float)((u32)spE >> 30);
            }
        };
        auto PROC = [&](int lj, uint2 cc, float ee) {
            float dxe = __shfl(gx_l, lj);
            float dye = __shfl(gy_l, lj);
            float dze = __shfl(gz_l, lj);
            float d2e = __shfl(d2_l, lj);
            float av[4];
            av[0] = bflo(cc.x); av[1] = bfhi(cc.x);
            av[2] = bflo(cc.y); av[3] = bfhi(cc.y);
            float wpart = bx32;
            #pragma unroll
            for (int f = 0; f < 4; ++f) {
                float t = __fmaf_rn(d2e, wed[f], c0[f]);
                t = __fmaf_rn(ee, d01[f], t);
                float v = av[f] + t;
                float m = silu(v);
                ag[f] += m;
                wpart = __fmaf_rn(m, wx[f], wpart);
            }
            sx = __fmaf_rn(dxe, wpart, sx);
            sy = __fmaf_rn(dye, wpart, sy);
            sz = __fmaf_rn(dze, wpart, sz);
        };

        // 8-slot pipeline per parity (16 gathers in flight per wave)
        int ljA = q,      ljB = q + 2,  ljC = q + 4,  ljD = q + 6;
        int ljE = q + 8,  ljF = q + 10, ljG = q + 12, ljH = q + 14;
        int ljn = q + 16;
        uint2 ccA, ccB, ccC, ccD, ccE, ccF, ccG, ccH;
        float etA, etB, etC, etD, etE, etF, etG, etH;
        FETCH(ljA, ccA, etA); FETCH(ljB, ccB, etB);
        FETCH(ljC, ccC, etC); FETCH(ljD, ccD, etD);
        FETCH(ljE, ccE, etE); FETCH(ljF, ccF, etF);
        FETCH(ljG, ccG, etG); FETCH(ljH, ccH, etH);
        while (ljA < nchunk) {
            PROC(ljA, ccA, etA); ljA = ljn; ljn += 2; FETCH(ljA, ccA, etA);
            if (ljB >= nchunk) break;
            PROC(ljB, ccB, etB); ljB = ljn; ljn += 2; FETCH(ljB, ccB, etB);
            if (ljC >= nchunk) break;
            PROC(ljC, ccC, etC); ljC = ljn; ljn += 2; FETCH(ljC, ccC, etC);
            if (ljD >= nchunk) break;
            PROC(ljD, ccD, etD); ljD = ljn; ljn += 2; FETCH(ljD, ccD, etD);
            if (ljE >= nchunk) break;
            PROC(ljE, ccE, etE); ljE = ljn; ljn += 2; FETCH(ljE, ccE, etE);
            if (ljF >= nchunk) break;
            PROC(ljF, ccF, etF); ljF = ljn; ljn += 2; FETCH(ljF, ccF, etF);
            if (ljG >= nchunk) break;
            PROC(ljG, ccG, etG); ljG = ljn; ljn += 2; FETCH(ljG, ccG, etG);
            if (ljH >= nchunk) break;
            PROC(ljH, ccH, etH); ljH = ljn; ljn += 2; FETCH(ljH, ccH, etH);
        }
    }

    // ---- reductions (within this node's single wave) ----
    #pragma unroll
    for (int f = 0; f < 4; ++f) ag[f] += __shfl_xor(ag[f], 32);   // combine parities
    #pragma unroll
    for (int off = 1; off <= 32; off <<= 1) {
        sx += __shfl_xor(sx, off);
        sy += __shfl_xor(sy, off);
        sz += __shfl_xor(sz, off);
    }
    if (l < 32) {
        int c2 = 16 + (p >> 1);
        int slot = c2 ^ (i & 7);
        uint2 o;
        o.x = pack2(ag[0], ag[1]);
        o.y = pack2(ag[2], ag[3]);
        *(uint2*)&s_A[i * 256 + slot * 8 + (p & 1) * 4] = o;
    }
    if (l == 0) {
        float inv = 1.f / ((float)d + 1.f);
        x_out[gn * 3 + 0] = xd0 + sx * inv;
        x_out[gn * 3 + 1] = xd1 + sy * inv;
        x_out[gn * 3 + 2] = xd2 + sz * inv;
    }

    __syncthreads();

    // ---- Wh GEMM: wave w = N-tile w; B fragments straight from L2 ----
    float4v acc = (float4v){0.f, 0.f, 0.f, 0.f};
    #pragma unroll
    for (int t = 0; t < 4; ++t) {
        #pragma unroll
        for (int s = 0; s < 2; ++s) {
            int m = l & 15;
            int c = t * 8 + s * 4 + (l >> 4);
            int slot = c ^ (l & 7);
            short8 af = *(const short8*)(s_A + m * 256 + slot * 8);
            short8 bfv = *(const short8*)(Whp_l + (size_t)t * 8192 + ((s * 8 + w) * 64 + l) * 8);
            acc = __builtin_amdgcn_mfma_f32_16x16x32_bf16(af, bfv, acc, 0, 0, 0);
        }
    }
    // epilogue: h += silu(acc + bh)  (only rows 0..7 are real nodes)
    {
        int f = w * 16 + (l & 15);
        float bv = bh_l[f];
        #pragma unroll
        for (int r = 0; r < 4; ++r) {
            int m = (l >> 4) * 4 + r;
            if (m < NUB) {
                int gn2 = n0 + m;
                float v = acc[r] + bv;
                float hn = h[(size_t)gn2 * HID + f] + silu(v);
                h[(size_t)gn2 * HID + f] = hn;
                h_bf[(size_t)gn2 * HID + f] = f2bf(hn);
            }
        }
    }
}

// ================= final: MFMA h2i, 64 nodes/block =================
__global__ __launch_bounds__(256) void final_mfma_kernel(
    const u16* __restrict__ h_bf, const float* __restrict__ x,
    const int* __restrict__ gmask,
    const u16* __restrict__ h2ip, const float* __restrict__ b,
    float* __restrict__ out)
{
    __shared__ u16 s_A[64 * 128];
    __shared__ u16 s_B[4096];

    int tx = threadIdx.x;
    int n0 = blockIdx.x * 64;
    int l = tx & 63, w = tx >> 6;
    int mt_base = (w & 1) * 2, nt_base = (w >> 1) * 2;

    #pragma unroll
    for (int it = 0; it < 4; ++it) {
        int flat = it * 256 + tx;
        int n = flat >> 4, c = flat & 15;
        int slot = c ^ (n & 7);
        int gn = n0 + n;
        uint4 v = make_uint4(0,0,0,0);
        if (gn < NN) v = *(const uint4*)(h_bf + (size_t)gn * 128 + c * 8);
        *(uint4*)&s_A[n * 128 + slot * 8] = v;
    }

    float4v acc[2][2];
    #pragma unroll
    for (int mi = 0; mi < 2; ++mi)
        #pragma unroll
        for (int ni = 0; ni < 2; ++ni) acc[mi][ni] = (float4v){0.f,0.f,0.f,0.f};

    for (int t = 0; t < 2; ++t) {
        __syncthreads();
        #pragma unroll
        for (int it = 0; it < 2; ++it) {
            int flat = it * 256 + tx;
            ((uint4*)s_B)[flat] = ((const uint4*)(h2ip + (size_t)t * 4096))[flat];
        }
        __syncthreads();
        #pragma unroll
        for (int s = 0; s < 2; ++s) {
            short8 af[2], bfv[2];
            #pragma unroll
            for (int mi = 0; mi < 2; ++mi) {
                int m = (mt_base + mi) * 16 + (l & 15);
                int c = t * 8 + s * 4 + (l >> 4);
                int slot = c ^ (l & 7);
                af[mi] = *(const short8*)(s_A + m * 128 + slot * 8);
            }
            #pragma unroll
            for (int ni = 0; ni < 2; ++ni)
                bfv[ni] = *(const short8*)(s_B + ((s * 4 + nt_base + ni) * 64 + l) * 8);
            #pragma unroll
            for (int mi = 0; mi < 2; ++mi)
                #pragma unroll
                for (int ni = 0; ni < 2; ++ni)
                    acc[mi][ni] = __builtin_amdgcn_mfma_f32_16x16x32_bf16(
                        af[mi], bfv[ni], acc[mi][ni], 0, 0, 0);
        }
    }
    #pragma unroll
    for (int mi = 0; mi < 2; ++mi) {
        #pragma unroll
        for (int ni = 0; ni < 2; ++ni) {
            int f = (nt_base + ni) * 16 + (l & 15);
            float bv = b[f];
            #pragma unroll
            for (int r = 0; r < 4; ++r) {
                int m = (mt_base + mi) * 16 + (l >> 4) * 4 + r;
                int gn = n0 + m;
                if (gn < NN)
                    out[(size_t)gn * IN_DIM + f] = gmask[gn] ? (acc[mi][ni][r] + bv) : 0.f;
            }
        }
    }
    if (tx < 192) {
        int i = tx / 3, c = tx % 3;
        int gn = n0 + i;
        if (gn < NN)
            out[(size_t)NN * IN_DIM + gn * 3 + c] = gmask[gn] ? x[gn * 3 + c] : 0.f;
    }
}

// ================= fallback path (atomic, scalar; used only if ws too small) =================
__global__ __launch_bounds__(256) void init_fb_kernel(
    const float* __restrict__ X_t, const int* __restrict__ edges,
    float* __restrict__ x, float* __restrict__ cnt)
{
    int gid = blockIdx.x * blockDim.x + threadIdx.x;
    int stride = gridDim.x * blockDim.x;
    for (int i = gid; i < NN * 3; i += stride) x[i] = X_t[i];
    for (int e = gid; e < NE; e += stride)
        atomicAdd(&cnt[edges[NE + e]], 1.0f);
}

__global__ __launch_bounds__(128) void node_mlp_kernel(
    const float* __restrict__ H_t, const float* __restrict__ cond,
    const float* __restrict__ t_in,
    const float* __restrict__ W0, const float* __restrict__ b0,
    const float* __restrict__ W1, const float* __restrict__ b1,
    const float* __restrict__ W2, const float* __restrict__ b2,
    float* __restrict__ h)
{
    __shared__ float s_feat[D0][20];
    __shared__ float s_h0[HID][20];
    __shared__ float s_h1[HID][20];
    int n0 = blockIdx.x * 16;
    int tx = threadIdx.x;

    for (int idx = tx; idx < 16 * IN_DIM; idx += 128) {
        int i = idx >> 6, k = idx & 63;
        s_feat[k][i] = H_t[(n0 + i) * IN_DIM + k];
    }
    for (int idx = tx; idx < 16 * HID; idx += 128) {
        int i = idx >> 7, k = idx & 127;
        s_feat[IN_DIM + k][i] = cond[(n0 + i) * HID + k];
    }
    const float cfr = -logf(10000.f) / 63.f;
    for (int idx = tx; idx < 16 * HID; idx += 128) {
        int i = idx >> 7, k = idx & 127;
        float tv = t_in[n0 + i];
        int jj = k & 63;
        float ang = tv * __expf(cfr * (float)jj);
        s_feat[IN_DIM + HID + k][i] = (k < 64) ? __sinf(ang) : __cosf(ang);
    }
    __syncthreads();

    float acc[16];
    {
        float bv = b0[tx];
        #pragma unroll
        for (int i = 0; i < 16; ++i) acc[i] = bv;
        for (int k = 0; k < D0; ++k) {
            float w = W0[k * HID + tx];
            float4 f0 = *(const float4*)&s_feat[k][0];
            float4 f1 = *(const float4*)&s_feat[k][4];
            float4 f2 = *(const float4*)&s_feat[k][8];
            float4 f3 = *(const float4*)&s_feat[k][12];
            acc[0] += f0.x*w; acc[1] += f0.y*w; acc[2] += f0.z*w; acc[3] += f0.w*w;
            acc[4] += f1.x*w; acc[5] += f1.y*w; acc[6] += f1.z*w; acc[7] += f1.w*w;
            acc[8] += f2.x*w; acc[9] += f2.y*w; acc[10]+= f2.z*w; acc[11]+= f2.w*w;
            acc[12]+= f3.x*w; acc[13]+= f3.y*w; acc[14]+= f3.z*w; acc[15]+= f3.w*w;
        }
        #pragma unroll
        for (int i = 0; i < 16; ++i) s_h0[tx][i] = fmaxf(acc[i], 0.f);
    }
    __syncthreads();
    {
        float bv = b1[tx];
        #pragma unroll
        for (int i = 0; i < 16; ++i) acc[i] = bv;
        for (int k = 0; k < HID; ++k) {
            float w = W1[k * HID + tx];
            float4 f0 = *(const float4*)&s_h0[k][0];
            float4 f1 = *(const float4*)&s_h0[k][4];
            float4 f2 = *(const float4*)&s_h0[k][8];
            float4 f3 = *(const float4*)&s_h0[k][12];
            acc[0] += f0.x*w; acc[1] += f0.y*w; acc[2] += f0.z*w; acc[3] += f0.w*w;
            acc[4] += f1.x*w; acc[5] += f1.y*w; acc[6] += f1.z*w; acc[7] += f1.w*w;
            acc[8] += f2.x*w; acc[9] += f2.y*w; acc[10]+= f2.z*w; acc[11]+= f2.w*w;
            acc[12]+= f3.x*w; acc[13]+= f3.y*w; acc[14]+= f3.z*w; acc[15]+= f3.w*w;
        }
        #pragma unroll
        for (int i = 0; i < 16; ++i) s_h1[tx][i] = fmaxf(acc[i], 0.f);
    }
    __syncthreads();
    {
        float bv = b2[tx];
        #pragma unroll
        for (int i = 0; i < 16; ++i) acc[i] = bv;
        for (int k = 0; k < HID; ++k) {
            float w = W2[k * HID + tx];
            float4 f0 = *(const float4*)&s_h1[k][0];
            float4 f1 = *(const float4*)&s_h1[k][4];
            float4 f2 = *(const float4*)&s_h1[k][8];
            float4 f3 = *(const float4*)&s_h1[k][12];
            acc[0] += f0.x*w; acc[1] += f0.y*w; acc[2] += f0.z*w; acc[3] += f0.w*w;
            acc[4] += f1.x*w; acc[5] += f1.y*w; acc[6] += f1.z*w; acc[7] += f1.w*w;
            acc[8] += f2.x*w; acc[9] += f2.y*w; acc[10]+= f2.z*w; acc[11]+= f2.w*w;
            acc[12]+= f3.x*w; acc[13]+= f3.y*w; acc[14]+= f3.z*w; acc[15]+= f3.w*w;
        }
        #pragma unroll
        for (int i = 0; i < 16; ++i) h[(n0 + i) * HID + tx] = acc[i];
    }
}

__global__ __launch_bounds__(256) void edge_gemm_fb_kernel(
    const float* __restrict__ h, const float* __restrict__ x,
    const int* __restrict__ edges, const int* __restrict__ etype,
    const float* __restrict__ edge_table,
    const float* __restrict__ We_l, const float* __restrict__ be_l,
    const float* __restrict__ Wx_l, const float* __restrict__ bx_l,
    float* __restrict__ agg_m, float* __restrict__ agg_x)
{
    __shared__ int s_src[TILE_E], s_dst[TILE_E];
    __shared__ float s_diff[TILE_E][3];
    __shared__ float s_tail[TILE_E][36];
    __shared__ float s_Af[TILE_E][36];
    __shared__ float s_Bf[33][HID];
    __shared__ float s_wx[HID];

    int e0 = blockIdx.x * TILE_E;
    int tx = threadIdx.x;
    int tf = tx & 15;
    int te = tx >> 4;

    if (tx < TILE_E) {
        int s = edges[e0 + tx];
        int d = edges[NE + e0 + tx];
        s_src[tx] = s; s_dst[tx] = d;
        float dx = x[s * 3 + 0] - x[d * 3 + 0];
        float dy = x[s * 3 + 1] - x[d * 3 + 1];
        float dz = x[s * 3 + 2] - x[d * 3 + 2];
        s_diff[tx][0] = dx; s_diff[tx][1] = dy; s_diff[tx][2] = dz;
        s_tail[tx][0] = dx * dx + dy * dy + dz * dz;
        int et = etype[e0 + tx];
        #pragma unroll
        for (int j = 0; j < 32; ++j) s_tail[tx][1 + j] = edge_table[et * 32 + j];
    }
    if (tx < HID) s_wx[tx] = Wx_l[tx];
    __syncthreads();

    float acc[4][8];
    #pragma unroll
    for (int i = 0; i < 4; ++i)
        #pragma unroll
        for (int j = 0; j < 8; ++j) acc[i][j] = 0.f;

    for (int t = 0; t < 9; ++t) {
        int k0 = t * 32;
        int klen = (t == 8) ? 33 : 32;
        __syncthreads();
        if (t < 8) {
            const bool use_src = (t < 4);
            int kbase = (t & 3) * 32;
            for (int q4 = tx; q4 < TILE_E * 8; q4 += 256) {
                int e = q4 >> 3, q = q4 & 7;
                int row = use_src ? s_src[e] : s_dst[e];
                float4 v = *(const float4*)&h[row * HID + kbase + q * 4];
                *(float4*)&s_Af[e][q * 4] = v;
            }
        }
        for (int q4 = tx; q4 < klen * 32; q4 += 256) {
            int kk = q4 >> 5, c4 = q4 & 31;
            float4 v = *(const float4*)&We_l[(k0 + kk) * HID + c4 * 4];
            *(float4*)&s_Bf[kk][c4 * 4] = v;
        }
        __syncthreads();
        const float (*Asrc)[36] = (t == 8) ? (const float (*)[36])s_tail
                                           : (const float (*)[36])s_Af;
        for (int kk = 0; kk < klen; ++kk) {
            float a0 = Asrc[te * 4 + 0][kk];
            float a1 = Asrc[te * 4 + 1][kk];
            float a2 = Asrc[te * 4 + 2][kk];
            float a3 = Asrc[te * 4 + 3][kk];
            float4 bv0 = *(const float4*)&s_Bf[kk][tf * 8];
            float4 bv1 = *(const float4*)&s_Bf[kk][tf * 8 + 4];
            float b[8] = {bv0.x, bv0.y, bv0.z, bv0.w, bv1.x, bv1.y, bv1.z, bv1.w};
            #pragma unroll
            for (int j = 0; j < 8; ++j) {
                acc[0][j] += a0 * b[j];
                acc[1][j] += a1 * b[j];
                acc[2][j] += a2 * b[j];
                acc[3][j] += a3 * b[j];
            }
        }
    }

    float wsum[4];
    #pragma unroll
    for (int i = 0; i < 4; ++i) {
        float p = 0.f;
        #pragma unroll
        for (int j = 0; j < 8; ++j) {
            int f = tf * 8 + j;
            float v = acc[i][j] + be_l[f];
            float m = silu(v);
            acc[i][j] = m;
            p += m * s_wx[f];
        }
        wsum[i] = p;
    }
    #pragma unroll
    for (int off = 1; off < 16; off <<= 1) {
        #pragma unroll
        for (int i = 0; i < 4; ++i) wsum[i] += __shfl_xor(wsum[i], off);
    }
    float bxv = bx_l[0];
    if (tf < 3) {
        #pragma unroll
        for (int i = 0; i < 4; ++i) {
            int e = te * 4 + i;
            float w2 = wsum[i] + bxv;
            atomicAdd(&agg_x[s_dst[e] * 3 + tf], s_diff[e][tf] * w2);
        }
    }
    #pragma unroll
    for (int i = 0; i < 4; ++i) {
        int d = s_dst[te * 4 + i];
        #pragma unroll
        for (int j = 0; j < 8; ++j)
            atomicAdd(&agg_m[d * HID + tf * 8 + j], acc[i][j]);
    }
}

__global__ __launch_bounds__(128) void node_update_fb_kernel(
    float* __restrict__ h, float* __restrict__ x,
    const float* __restrict__ agg_m, const float* __restrict__ agg_x,
    const float* __restrict__ cnt,
    const float* __restrict__ Wh_l, const float* __restrict__ bh_l)
{
    __shared__ float s_in[256][20];
    int n0 = blockIdx.x * 16;
    int tx = threadIdx.x;
    for (int idx = tx; idx < 16 * HID; idx += 128) {
        int i = idx >> 7, k = idx & 127;
        s_in[k][i] = h[(n0 + i) * HID + k];
    }
    for (int idx = tx; idx < 16 * HID; idx += 128) {
        int i = idx >> 7, k = idx & 127;
        s_in[HID + k][i] = agg_m[(n0 + i) * HID + k];
    }
    __syncthreads();
    float acc[16];
    float bv = bh_l[tx];
    #pragma unroll
    for (int i = 0; i < 16; ++i) acc[i] = bv;
    for (int k = 0; k < 256; ++k) {
        float w = Wh_l[k * HID + tx];
        float4 f0 = *(const float4*)&s_in[k][0];
        float4 f1 = *(const float4*)&s_in[k][4];
        float4 f2 = *(const float4*)&s_in[k][8];
        float4 f3 = *(const float4*)&s_in[k][12];
        acc[0] += f0.x*w; acc[1] += f0.y*w; acc[2] += f0.z*w; acc[3] += f0.w*w;
        acc[4] += f1.x*w; acc[5] += f1.y*w; acc[6] += f1.z*w; acc[7] += f1.w*w;
        acc[8] += f2.x*w; acc[9] += f2.y*w; acc[10]+= f2.z*w; acc[11]+= f2.w*w;
        acc[12]+= f3.x*w; acc[13]+= f3.y*w; acc[14]+= f3.z*w; acc[15]+= f3.w*w;
    }
    #pragma unroll
    for (int i = 0; i < 16; ++i) {
        float v = acc[i];
        h[(n0 + i) * HID + tx] = s_in[tx][i] + silu(v);
    }
    if (tx < 48) {
        int i = tx / 3, c = tx % 3;
        int n = n0 + i;
        x[n * 3 + c] += agg_x[n * 3 + c] / (cnt[n] + 1.f);
    }
}

__global__ __launch_bounds__(64) void final_fb_kernel(
    const float* __restrict__ h, const float* __restrict__ x,
    const int* __restrict__ gmask,
    const float* __restrict__ W, const float* __restrict__ b,
    float* __restrict__ out)
{
    __shared__ float s_h[8][HID];
    int n0 = blockIdx.x * 8;
    int tx = threadIdx.x;
    for (int idx = tx; idx < 8 * HID; idx += 64) {
        int i = idx >> 7, k = idx & 127;
        s_h[i][k] = h[(n0 + i) * HID + k];
    }
    __syncthreads();
    float acc[8];
    float bv = b[tx];
    #pragma unroll
    for (int i = 0; i < 8; ++i) acc[i] = bv;
    for (int k = 0; k < HID; ++k) {
        float w = W[k * IN_DIM + tx];
        #pragma unroll
        for (int i = 0; i < 8; ++i) acc[i] += s_h[i][k] * w;
    }
    #pragma unroll
    for (int i = 0; i < 8; ++i) {
        int n = n0 + i;
        out[n * IN_DIM + tx] = gmask[n] ? acc[i] : 0.f;
    }
    if (tx < 24) {
        int i = tx / 3, c = tx % 3;
        int n = n0 + i;
        out[NN * IN_DIM + n * 3 + c] = gmask[n] ? x[n * 3 + c] : 0.f;
    }
}

extern "C" void kernel_launch(void* const* d_in, const int* in_sizes, int n_in,
                              void* d_out, int out_size, void* d_ws, size_t ws_size,
                              hipStream_t stream) {
    const float* H_t   = (const float*)d_in[0];
    const float* X_t   = (const float*)d_in[1];
    const float* cond  = (const float*)d_in[2];
    const float* t_in  = (const float*)d_in[3];
    const int*   edges = (const int*)d_in[4];
    const int*   etype = (const int*)d_in[5];
    const int*   gmask = (const int*)d_in[6];
    const float* W0 = (const float*)d_in[8];
    const float* b0 = (const float*)d_in[9];
    const float* W1 = (const float*)d_in[10];
    const float* b1 = (const float*)d_in[11];
    const float* W2 = (const float*)d_in[12];
    const float* b2 = (const float*)d_in[13];
    const float* edge_table = (const float*)d_in[14];
    const float* We = (const float*)d_in[15];
    const float* be = (const float*)d_in[16];
    const float* Wx = (const float*)d_in[17];
    const float* bx = (const float*)d_in[18];
    const float* Wh = (const float*)d_in[19];
    const float* bh = (const float*)d_in[20];
    const float* h2i_W = (const float*)d_in[21];
    const float* h2i_b = (const float*)d_in[22];

    char* p = (char*)d_ws;
    float* h = (float*)p;           p += (size_t)NN * HID * 4;
    u16* h_bf = (u16*)p;            p += (size_t)NN * HID * 2;
    float* xa = (float*)p;          p += (size_t)NN * 3 * 4;
    float* xb = (float*)p;          p += (size_t)NN * 3 * 4;
    u16* Csrc = (u16*)p;            p += (size_t)NN * 128 * 2;
    u16* Cdst = (u16*)p;            p += (size_t)NN * 128 * 2;
    u16* Bpack = (u16*)p;           p += (size_t)PACK_TOT * 2;
    float* tv = (float*)p;          p += (size_t)768 * 4;
    float* wed2 = (float*)p;        p += (size_t)384 * 4;
    int* row_start = (int*)p;       p += (size_t)(NN + 4) * 4;
    int* deg = (int*)p;             p += (size_t)NN * 4;
    int* head = (int*)p;            p += (size_t)NN * 4;
    int* src_s = (int*)p;           p += (size_t)NE * 4;
    size_t need = (size_t)(p - (char*)d_ws);

    if (ws_size >= need) {
        prep_kernel<<<(PREP_TOT + 255) / 256, 256, 0, stream>>>(
            We, W0, W1, W2, Wh, h2i_W, edge_table, be, Bpack, tv, wed2, deg);
        hist_kernel<<<256, 256, 0, stream>>>(X_t, edges, xa, deg);
        scan_kernel<<<1, 1024, 0, stream>>>(deg, row_start, head);
        scatter_kernel<<<256, 256, 0, stream>>>(edges, etype, head, src_s);
        node_mlp_mfma_kernel<<<NB64, 256, 0, stream>>>(
            H_t, cond, t_in,
            Bpack + OFF_W0, b0, Bpack + OFF_W1, b1, Bpack + OFF_W2, b2,
            Bpack + OFF_WE, Csrc, Cdst,
            h, h_bf);
        for (int l = 0; l < 3; ++l) {
            if (l > 0)
                cvec_kernel<<<NB64, 256, 0, stream>>>(
                    h_bf, Bpack + OFF_WE + (size_t)l * 40960, Csrc, Cdst);
            const float* xin = (l & 1) ? xb : xa;
            float* xout = (l & 1) ? xa : xb;
            node_fused_kernel<<<NN / NUB, 512, 0, stream>>>(
                h, h_bf, xin, xout, Csrc, Cdst, src_s, row_start,
                tv + (size_t)l * 256, wed2 + (size_t)l * 128,
                Wx + l * HID, bx + l,
                Bpack + OFF_WH + (size_t)l * 32768, bh + l * HID);
        }
        // layers: l0 xa->xb, l1 xb->xa, l2 xa->xb  => final x lives in xb
        final_mfma_kernel<<<NB64, 256, 0, stream>>>(
            h_bf, xb, gmask, Bpack + OFF_H2I, h2i_b, (float*)d_out);
    } else {
        // fallback: scalar atomic path (~21 MB)
        float* ws    = (float*)d_ws;
        float* fh    = ws;
        float* fx    = fh + NN * HID;
        float* cnt   = fx + NN * 3;
        float* fagg_m = cnt + NN;
        float* fagg_x = fagg_m + NN * HID;

        hipMemsetAsync(cnt, 0, NN * sizeof(float), stream);
        init_fb_kernel<<<256, 256, 0, stream>>>(X_t, edges, fx, cnt);
        node_mlp_kernel<<<NN / 16, 128, 0, stream>>>(H_t, cond, t_in,
                                                     W0, b0, W1, b1, W2, b2, fh);
        for (int l = 0; l < 3; ++l) {
            hipMemsetAsync(fagg_m, 0, (size_t)NN * 131 * sizeof(float), stream);
            edge_gemm_fb_kernel<<<NE / TILE_E, 256, 0, stream>>>(
                fh, fx, edges, etype, edge_table,
                We + (size_t)l * DE * HID, be + l * HID,
                Wx + l * HID, bx + l, fagg_m, fagg_x);
            node_update_fb_kernel<<<NN / 16, 128, 0, stream>>>(
                fh, fx, fagg_m, fagg_x, cnt,
                Wh + (size_t)l * 256 * HID, bh + l * HID);
        }
        final_fb_kernel<<<NN / 8, 64, 0, stream>>>(fh, fx, gmask, h2i_W, h2i_b, (float*)d_out);
    }
}

// Round 7
// 353.590 us; speedup vs baseline: 1.1293x; 1.0497x over previous
//
#include <hip/hip_runtime.h>
#include <math.h>

#define NN 20000
#define NE 256000
#define IN_DIM 64
#define HID 128
#define DE 289     // 2*HID + 1 + 32
#define D0 320     // IN_DIM + 2*HID
#define TILE_E 64
#define NB64 313   // ceil(NN/64)
#define NUB 8      // nodes per block (fused node kernel)
#define SRCMASK 0x3FFFFFFF

typedef unsigned short u16;
typedef unsigned int u32;
typedef unsigned long long u64;
typedef __attribute__((ext_vector_type(8))) short short8;
typedef __attribute__((ext_vector_type(4))) float float4v;

// Bpack layout offsets (u16 elements)
#define OFF_WE   0          // 3 x 40960 (K=289 pad 320, N=128) — tiles 0..3 = We rows 0..255
#define OFF_W0   122880     // 40960 (K=320, N=128)
#define OFF_W1   163840     // 16384 (K=128, N=128)
#define OFF_W2   180224     // 16384
#define OFF_WH   196608     // 3 x 32768 (K=256, N=128)
#define OFF_H2I  294912     // 8192 (K=128, N=64)
#define PACK_TOT 303104
#define PREP_TOT (PACK_TOT + 1152 + NN)   // pack + tv/wed2 + deg-zero

static __device__ __forceinline__ u16 f2bf(float f) {
    unsigned int u = __float_as_uint(f);
    u += 0x7fffu + ((u >> 16) & 1u);
    return (u16)(u >> 16);
}
static __device__ __forceinline__ float bf2f(u16 s) {
    return __uint_as_float(((unsigned int)s) << 16);
}
static __device__ __forceinline__ float bflo(u32 u) { return bf2f((u16)(u & 0xffffu)); }
static __device__ __forceinline__ float bfhi(u32 u) { return bf2f((u16)(u >> 16)); }
static __device__ __forceinline__ u32 pack2(float a, float b) {
    return (u32)f2bf(a) | ((u32)f2bf(b) << 16);
}
static __device__ __forceinline__ uint4 pack8(const float* v) {
    uint4 r;
    r.x = (u32)f2bf(v[0]) | ((u32)f2bf(v[1]) << 16);
    r.y = (u32)f2bf(v[2]) | ((u32)f2bf(v[3]) << 16);
    r.z = (u32)f2bf(v[4]) | ((u32)f2bf(v[5]) << 16);
    r.w = (u32)f2bf(v[6]) | ((u32)f2bf(v[7]) << 16);
    return r;
}
static __device__ __forceinline__ float silu(float v) {
    return v * (1.f / (1.f + __expf(-v)));
}

// ================= CSR build =================
__global__ __launch_bounds__(256) void hist_kernel(
    const float* __restrict__ X_t, const int* __restrict__ edges,
    float* __restrict__ x, int* __restrict__ deg)
{
    int gid = blockIdx.x * blockDim.x + threadIdx.x;
    int stride = gridDim.x * blockDim.x;
    for (int i = gid; i < NN * 3; i += stride) x[i] = X_t[i];
    for (int e = gid; e < NE; e += stride)
        atomicAdd(&deg[edges[NE + e]], 1);
}

__global__ __launch_bounds__(1024) void scan_kernel(
    const int* __restrict__ deg, int* __restrict__ row_start, int* __restrict__ head)
{
    __shared__ int s[1024];
    int tx = threadIdx.x;
    const int per = (NN + 1023) / 1024;
    int st = tx * per, en = st + per;
    if (st > NN) st = NN;
    if (en > NN) en = NN;
    int sum = 0;
    for (int i = st; i < en; ++i) sum += deg[i];
    s[tx] = sum;
    __syncthreads();
    for (int off = 1; off < 1024; off <<= 1) {
        int t = (tx >= off) ? s[tx - off] : 0;
        __syncthreads();
        s[tx] += t;
        __syncthreads();
    }
    int run = (tx == 0) ? 0 : s[tx - 1];
    for (int i = st; i < en; ++i) {
        row_start[i] = run; head[i] = run; run += deg[i];
    }
    if (tx == 1023) row_start[NN] = run;
}

// permute edges into dst-sorted order; pack etype into src bit 30
__global__ __launch_bounds__(256) void scatter_kernel(
    const int* __restrict__ edges, const int* __restrict__ etype,
    int* __restrict__ head,
    int* __restrict__ src_s)
{
    int gid = blockIdx.x * blockDim.x + threadIdx.x;
    int stride = gridDim.x * blockDim.x;
    for (int e = gid; e < NE; e += stride) {
        int d = edges[NE + e];
        int p = atomicAdd(&head[d], 1);
        src_s[p] = edges[e] | (etype[e] << 30);
    }
}

// ================= combined prep: weight packing + edge tail precompute + deg zero =================
__global__ __launch_bounds__(256) void prep_kernel(
    const float* __restrict__ We, const float* __restrict__ W0,
    const float* __restrict__ W1, const float* __restrict__ W2,
    const float* __restrict__ Wh, const float* __restrict__ h2i,
    const float* __restrict__ edge_table, const float* __restrict__ be,
    u16* __restrict__ Bp, float* __restrict__ tv, float* __restrict__ wed2,
    int* __restrict__ deg)
{
    int idx = blockIdx.x * 256 + threadIdx.x;
    if (idx < PACK_TOT) {
        const float* src; int N = 128, Ksrc; int r;
        if (idx < OFF_W0) {
            int layer = idx / 40960; r = idx - layer * 40960;
            src = We + (size_t)layer * DE * HID; Ksrc = DE;
        } else if (idx < OFF_W1) { r = idx - OFF_W0; src = W0; Ksrc = 320; }
        else if (idx < OFF_W2)   { r = idx - OFF_W1; src = W1; Ksrc = 128; }
        else if (idx < OFF_WH)   { r = idx - OFF_W2; src = W2; Ksrc = 128; }
        else if (idx < OFF_H2I) {
            int t = idx - OFF_WH; int layer = t / 32768; r = t - layer * 32768;
            src = Wh + (size_t)layer * 256 * HID; Ksrc = 256;
        } else { r = idx - OFF_H2I; src = h2i; Ksrc = 128; N = 64; }
        int ntc = N / 16;
        int j = r & 7, lane = (r >> 3) & 63;
        int rem = r >> 9;
        int nt = rem % ntc, ks = rem / ntc;
        int k = ks * 32 + ((lane >> 4) << 3) + j;
        int c = nt * 16 + (lane & 15);
        Bp[idx] = f2bf((k < Ksrc) ? src[(size_t)k * N + c] : 0.f);
    } else if (idx < PACK_TOT + 768) {
        int q = idx - PACK_TOT;
        int f = q & 127, t = (q >> 7) & 1, l = q >> 8;
        float acc = be[l * 128 + f];
        const float* W = We + (size_t)l * DE * HID;
        #pragma unroll
        for (int k = 0; k < 32; ++k)
            acc += edge_table[t * 32 + k] * W[(size_t)(257 + k) * HID + f];
        tv[l * 256 + t * 128 + f] = acc;
    } else if (idx < PACK_TOT + 1152) {
        int r = idx - PACK_TOT - 768;
        int f = r & 127, l = r >> 7;
        wed2[l * 128 + f] = We[(size_t)l * DE * HID + (size_t)256 * HID + f];
    } else if (idx < PREP_TOT) {
        deg[idx - PACK_TOT - 1152] = 0;
    }
}

// ================= node MLP: MFMA, 64 nodes/block + fused cvec layer-0 =================
__global__ __launch_bounds__(256) void node_mlp_mfma_kernel(
    const float* __restrict__ H_t, const float* __restrict__ cond,
    const float* __restrict__ t_in,
    const u16* __restrict__ W0p, const float* __restrict__ b0,
    const u16* __restrict__ W1p, const float* __restrict__ b1,
    const u16* __restrict__ W2p, const float* __restrict__ b2,
    const u16* __restrict__ WEp,
    u16* __restrict__ Csrc, u16* __restrict__ Cdst,
    float* __restrict__ h, u16* __restrict__ h_bf)
{
    __shared__ u16 s_A[64 * 64];
    __shared__ u16 s_B[64 * 128];
    __shared__ u16 s_h[64 * 128];
    __shared__ float s_t[64];

    int tx = threadIdx.x;
    int n0 = blockIdx.x * 64;
    int l = tx & 63, w = tx >> 6;
    int mt_base = (w & 1) * 2, nt_base = (w >> 1) * 4;
    const float cfr = -logf(10000.f) / 63.f;

    if (tx < 64) s_t[tx] = (n0 + tx < NN) ? t_in[n0 + tx] : 0.f;

    float4v acc[2][4];
    #pragma unroll
    for (int mi = 0; mi < 2; ++mi)
        #pragma unroll
        for (int ni = 0; ni < 4; ++ni) acc[mi][ni] = (float4v){0.f,0.f,0.f,0.f};

    for (int t = 0; t < 5; ++t) {
        __syncthreads();
        #pragma unroll
        for (int it = 0; it < 2; ++it) {
            int flat = it * 256 + tx;
            int n = flat >> 3, sl = flat & 7;
            int c = sl ^ (n & 7);
            int k0 = t * 64 + c * 8;
            float tv8[8];
            int gn = n0 + n;
            if (gn < NN) {
                if (k0 < 192) {
                    const float* src = (k0 < 64) ? &H_t[(size_t)gn * IN_DIM + k0]
                                                 : &cond[(size_t)gn * HID + (k0 - 64)];
                    float4 a = *(const float4*)src;
                    float4 b = *(const float4*)(src + 4);
                    tv8[0]=a.x; tv8[1]=a.y; tv8[2]=a.z; tv8[3]=a.w;
                    tv8[4]=b.x; tv8[5]=b.y; tv8[6]=b.z; tv8[7]=b.w;
                } else {
                    float tvv = s_t[n];
                    int jj = (k0 - 192) & 63;
                    bool is_sin = (k0 < 256);
                    #pragma unroll
                    for (int jx = 0; jx < 8; ++jx) {
                        float ang = tvv * __expf(cfr * (float)(jj + jx));
                        tv8[jx] = is_sin ? __sinf(ang) : __cosf(ang);
                    }
                }
            } else {
                #pragma unroll
                for (int jx = 0; jx < 8; ++jx) tv8[jx] = 0.f;
            }
            *(uint4*)&s_A[n * 64 + sl * 8] = pack8(tv8);
        }
        #pragma unroll
        for (int it = 0; it < 4; ++it) {
            int flat = it * 256 + tx;
            ((uint4*)s_B)[flat] = ((const uint4*)(W0p + (size_t)t * 8192))[flat];
        }
        __syncthreads();
        #pragma unroll
        for (int s = 0; s < 2; ++s) {
            short8 af[2], bfv[4];
            #pragma unroll
            for (int mi = 0; mi < 2; ++mi) {
                int m = (mt_base + mi) * 16 + (l & 15);
                int c = s * 4 + (l >> 4);
                int slot = c ^ (l & 7);
                af[mi] = *(const short8*)(s_A + m * 64 + slot * 8);
            }
            #pragma unroll
            for (int ni = 0; ni < 4; ++ni)
                bfv[ni] = *(const short8*)(s_B + ((s * 8 + nt_base + ni) * 64 + l) * 8);
            #pragma unroll
            for (int mi = 0; mi < 2; ++mi)
                #pragma unroll
                for (int ni = 0; ni < 4; ++ni)
                    acc[mi][ni] = __builtin_amdgcn_mfma_f32_16x16x32_bf16(
                        af[mi], bfv[ni], acc[mi][ni], 0, 0, 0);
        }
    }
    #pragma unroll
    for (int mi = 0; mi < 2; ++mi) {
        #pragma unroll
        for (int ni = 0; ni < 4; ++ni) {
            int f = (nt_base + ni) * 16 + (l & 15);
            float bv = b0[f];
            #pragma unroll
            for (int r = 0; r < 4; ++r) {
                int m = (mt_base + mi) * 16 + (l >> 4) * 4 + r;
                float v = fmaxf(acc[mi][ni][r] + bv, 0.f);
                int slot = (f >> 3) ^ (m & 7);
                s_h[m * 128 + slot * 8 + (f & 7)] = f2bf(v);
            }
            acc[mi][ni] = (float4v){0.f,0.f,0.f,0.f};
        }
    }
    for (int t = 0; t < 2; ++t) {
        __syncthreads();
        #pragma unroll
        for (int it = 0; it < 4; ++it) {
            int flat = it * 256 + tx;
            ((uint4*)s_B)[flat] = ((const uint4*)(W1p + (size_t)t * 8192))[flat];
        }
        __syncthreads();
        #pragma unroll
        for (int s = 0; s < 2; ++s) {
            short8 af[2], bfv[4];
            #pragma unroll
            for (int mi = 0; mi < 2; ++mi) {
                int m = (mt_base + mi) * 16 + (l & 15);
                int c = t * 8 + s * 4 + (l >> 4);
                int slot = c ^ (l & 7);
                af[mi] = *(const short8*)(s_h + m * 128 + slot * 8);
            }
            #pragma unroll
            for (int ni = 0; ni < 4; ++ni)
                bfv[ni] = *(const short8*)(s_B + ((s * 8 + nt_base + ni) * 64 + l) * 8);
            #pragma unroll
            for (int mi = 0; mi < 2; ++mi)
                #pragma unroll
                for (int ni = 0; ni < 4; ++ni)
                    acc[mi][ni] = __builtin_amdgcn_mfma_f32_16x16x32_bf16(
                        af[mi], bfv[ni], acc[mi][ni], 0, 0, 0);
        }
    }
    __syncthreads();
    #pragma unroll
    for (int mi = 0; mi < 2; ++mi) {
        #pragma unroll
        for (int ni = 0; ni < 4; ++ni) {
            int f = (nt_base + ni) * 16 + (l & 15);
            float bv = b1[f];
            #pragma unroll
            for (int r = 0; r < 4; ++r) {
                int m = (mt_base + mi) * 16 + (l >> 4) * 4 + r;
                float v = fmaxf(acc[mi][ni][r] + bv, 0.f);
                int slot = (f >> 3) ^ (m & 7);
                s_h[m * 128 + slot * 8 + (f & 7)] = f2bf(v);
            }
            acc[mi][ni] = (float4v){0.f,0.f,0.f,0.f};
        }
    }
    for (int t = 0; t < 2; ++t) {
        __syncthreads();
        #pragma unroll
        for (int it = 0; it < 4; ++it) {
            int flat = it * 256 + tx;
            ((uint4*)s_B)[flat] = ((const uint4*)(W2p + (size_t)t * 8192))[flat];
        }
        __syncthreads();
        #pragma unroll
        for (int s = 0; s < 2; ++s) {
            short8 af[2], bfv[4];
            #pragma unroll
            for (int mi = 0; mi < 2; ++mi) {
                int m = (mt_base + mi) * 16 + (l & 15);
                int c = t * 8 + s * 4 + (l >> 4);
                int slot = c ^ (l & 7);
                af[mi] = *(const short8*)(s_h + m * 128 + slot * 8);
            }
            #pragma unroll
            for (int ni = 0; ni < 4; ++ni)
                bfv[ni] = *(const short8*)(s_B + ((s * 8 + nt_base + ni) * 64 + l) * 8);
            #pragma unroll
            for (int mi = 0; mi < 2; ++mi)
                #pragma unroll
                for (int ni = 0; ni < 4; ++ni)
                    acc[mi][ni] = __builtin_amdgcn_mfma_f32_16x16x32_bf16(
                        af[mi], bfv[ni], acc[mi][ni], 0, 0, 0);
        }
    }
    // final h: write globals AND store into s_h (swizzled) for the fused cvec
    __syncthreads();   // protect s_h against pending W2-stage reads
    #pragma unroll
    for (int mi = 0; mi < 2; ++mi) {
        #pragma unroll
        for (int ni = 0; ni < 4; ++ni) {
            int f = (nt_base + ni) * 16 + (l & 15);
            float bv = b2[f];
            #pragma unroll
            for (int r = 0; r < 4; ++r) {
                int m = (mt_base + mi) * 16 + (l >> 4) * 4 + r;
                int gn = n0 + m;
                float v = acc[mi][ni][r] + bv;
                int slot = (f >> 3) ^ (m & 7);
                s_h[m * 128 + slot * 8 + (f & 7)] = f2bf(v);
                if (gn < NN) {
                    h[(size_t)gn * HID + f] = v;
                    h_bf[(size_t)gn * HID + f] = f2bf(v);
                }
            }
        }
    }

    // ---- fused cvec (layer 0): Csrc[n]=h@We_src, Cdst[n]=h@We_dst ----
    for (int sd = 0; sd < 2; ++sd) {
        #pragma unroll
        for (int mi = 0; mi < 2; ++mi)
            #pragma unroll
            for (int ni = 0; ni < 4; ++ni) acc[mi][ni] = (float4v){0.f,0.f,0.f,0.f};
        #pragma unroll
        for (int th = 0; th < 2; ++th) {
            int t = sd * 2 + th;
            __syncthreads();
            #pragma unroll
            for (int it = 0; it < 4; ++it) {
                int flat = it * 256 + tx;
                ((uint4*)s_B)[flat] = ((const uint4*)(WEp + (size_t)t * 8192))[flat];
            }
            __syncthreads();
            #pragma unroll
            for (int s = 0; s < 2; ++s) {
                short8 af[2], bfv[4];
                #pragma unroll
                for (int mi = 0; mi < 2; ++mi) {
                    int m = (mt_base + mi) * 16 + (l & 15);
                    int c = th * 8 + s * 4 + (l >> 4);
                    int slot = c ^ (l & 7);
                    af[mi] = *(const short8*)(s_h + m * 128 + slot * 8);
                }
                #pragma unroll
                for (int ni = 0; ni < 4; ++ni)
                    bfv[ni] = *(const short8*)(s_B + ((s * 8 + nt_base + ni) * 64 + l) * 8);
                #pragma unroll
                for (int mi = 0; mi < 2; ++mi)
                    #pragma unroll
                    for (int ni = 0; ni < 4; ++ni)
                        acc[mi][ni] = __builtin_amdgcn_mfma_f32_16x16x32_bf16(
                            af[mi], bfv[ni], acc[mi][ni], 0, 0, 0);
            }
        }
        u16* Cout = (sd == 0) ? Csrc : Cdst;
        #pragma unroll
        for (int mi = 0; mi < 2; ++mi) {
            #pragma unroll
            for (int ni = 0; ni < 4; ++ni) {
                int fq = (nt_base + ni) * 16 + (l & 15);
                #pragma unroll
                for (int r = 0; r < 4; ++r) {
                    int m = (mt_base + mi) * 16 + (l >> 4) * 4 + r;
                    int gn = n0 + m;
                    if (gn < NN)
                        Cout[(size_t)gn * 128 + fq] = f2bf(acc[mi][ni][r]);
                }
            }
        }
    }
}

// ================= fused node update v7: edge agg + Wh GEMM + fused next-cvec / final =================
// mode 0: epilogue computes next layer's Csrc/Cdst from hn (in-block GEMM vs Wnext=WE[l+1] pack).
// mode 1 (last layer): epilogue computes out = gmask ? hn@h2i + b : 0, plus x outputs; skips h/h_bf writes.
__global__ __launch_bounds__(512, 4) void node_fused_kernel(
    float* __restrict__ h, u16* __restrict__ h_bf,
    const float* __restrict__ x_in, float* __restrict__ x_out,
    const u16* __restrict__ Csrc, const u16* __restrict__ Cdst,
    u16* __restrict__ Csrc_n, u16* __restrict__ Cdst_n,
    const u16* __restrict__ Wnext, const float* __restrict__ bfin,
    const int* __restrict__ gmask, float* __restrict__ out,
    const int* __restrict__ src_s,
    const int* __restrict__ row_start,
    const float* __restrict__ tv_l, const float* __restrict__ wed2_l,
    const float* __restrict__ Wx_l, const float* __restrict__ bx_l,
    const u16* __restrict__ Whp_l, const float* __restrict__ bh_l,
    int mode)
{
    __shared__ u16 s_A[16 * 256];      // 8 KB: rows 0..7 = [h | agg] xor-swizzled, rows 8..15 zero
    __shared__ u16 s_h2[16 * 128];     // 4 KB: hn tile (rows 8..15 zero) for epilogue GEMM

    int tx = threadIdx.x;
    int n0 = blockIdx.x * NUB;
    int l = tx & 63, w = tx >> 6;      // 8 waves; wave w owns node i = w
    int i = w;
    int gn = n0 + i;
    int p = l & 31, q = l >> 5;        // feat-chunk (4 feats), edge parity

    // ---- stage h rows (0..7) + zero pad rows (chunks 0..15) ----
    if (tx < 256) {
        int n = tx >> 4, c = tx & 15;
        int slot = c ^ (n & 7);
        uint4 v = make_uint4(0, 0, 0, 0);
        if (n < NUB) v = *(const uint4*)(h_bf + (size_t)(n0 + n) * 128 + c * 8);
        *(uint4*)&s_A[n * 256 + slot * 8] = v;
    } else if (tx < 384) {
        int n = 8 + ((tx - 256) >> 4), c = 16 + (tx & 15);
        int slot = c ^ (n & 7);
        *(uint4*)&s_A[n * 256 + slot * 8] = make_uint4(0, 0, 0, 0);
    }

    // ---- per-thread constants (4 feats) ----
    float c0[4], d01[4], wed[4], wx[4];
    {
        uint2 cd = *(const uint2*)(Cdst + (size_t)gn * 128 + p * 4);
        float cdv0 = bflo(cd.x), cdv1 = bfhi(cd.x), cdv2 = bflo(cd.y), cdv3 = bfhi(cd.y);
        float4 t0 = *(const float4*)(tv_l + p * 4);
        float4 t1 = *(const float4*)(tv_l + 128 + p * 4);
        float4 wd = *(const float4*)(wed2_l + p * 4);
        float4 wv = *(const float4*)(Wx_l + p * 4);
        c0[0] = t0.x + cdv0; c0[1] = t0.y + cdv1; c0[2] = t0.z + cdv2; c0[3] = t0.w + cdv3;
        d01[0] = t1.x - t0.x; d01[1] = t1.y - t0.y; d01[2] = t1.z - t0.z; d01[3] = t1.w - t0.w;
        wed[0] = wd.x; wed[1] = wd.y; wed[2] = wd.z; wed[3] = wd.w;
        wx[0] = wv.x; wx[1] = wv.y; wx[2] = wv.z; wx[3] = wv.w;
    }
    float bx32 = bx_l[0] * (1.f / 32.f);

    int rs = row_start[gn], re = row_start[gn + 1];
    int d = re - rs;

    // own-node coords (wave-uniform)
    float xd0 = x_in[gn * 3 + 0], xd1 = x_in[gn * 3 + 1], xd2 = x_in[gn * 3 + 2];

    float ag[4] = {0.f, 0.f, 0.f, 0.f};
    float sx = 0.f, sy = 0.f, sz = 0.f;

    for (int e0 = 0; e0 < d; e0 += 64) {
        int nchunk = d - e0; if (nchunk > 64) nchunk = 64;
        // stage: lane l holds edge (e0+l)
        int sp_l = (l < nchunk) ? src_s[rs + e0 + l] : 0;
        float gx_l = 0.f, gy_l = 0.f, gz_l = 0.f, d2_l = 0.f;
        if (l < nchunk) {
            int sm = sp_l & SRCMASK;
            gx_l = x_in[sm * 3 + 0] - xd0;
            gy_l = x_in[sm * 3 + 1] - xd1;
            gz_l = x_in[sm * 3 + 2] - xd2;
            d2_l = gx_l * gx_l + gy_l * gy_l + gz_l * gz_l;
        }

        auto FETCH = [&](int lj, uint2& cc, float& et) {
            int spE = __shfl(sp_l, lj);
            cc = make_uint2(0u, 0u); et = 0.f;
            if (lj < nchunk) {
                cc = *(const uint2*)(Csrc + (size_t)(spE & SRCMASK) * 128 + p * 4);
                et = (float)((u32)spE >> 30);
            }
        };
        auto PROC = [&](int lj, uint2 cc, float ee) {
            float dxe = __shfl(gx_l, lj);
            float dye = __shfl(gy_l, lj);
            float dze = __shfl(gz_l, lj);
            float d2e = __shfl(d2_l, lj);
            float av[4];
            av[0] = bflo(cc.x); av[1] = bfhi(cc.x);
            av[2] = bflo(cc.y); av[3] = bfhi(cc.y);
            float wpart = bx32;
            #pragma unroll
            for (int f = 0; f < 4; ++f) {
                float t = __fmaf_rn(d2e, wed[f], c0[f]);
                t = __fmaf_rn(ee, d01[f], t);
                float v = av[f] + t;
                float m = silu(v);
                ag[f] += m;
                wpart = __fmaf_rn(m, wx[f], wpart);
            }
            sx = __fmaf_rn(dxe, wpart, sx);
            sy = __fmaf_rn(dye, wpart, sy);
            sz = __fmaf_rn(dze, wpart, sz);
        };

        // 4-slot pipeline per parity (8 gathers in flight per wave)
        int ljA = q, ljB = q + 2, ljC = q + 4, ljD = q + 6, ljn = q + 8;
        uint2 ccA, ccB, ccC, ccD; float etA, etB, etC, etD;
        FETCH(ljA, ccA, etA); FETCH(ljB, ccB, etB);
        FETCH(ljC, ccC, etC); FETCH(ljD, ccD, etD);
        while (ljA < nchunk) {
            PROC(ljA, ccA, etA); ljA = ljn; ljn += 2; FETCH(ljA, ccA, etA);
            if (ljB >= nchunk) break;
            PROC(ljB, ccB, etB); ljB = ljn; ljn += 2; FETCH(ljB, ccB, etB);
            if (ljC >= nchunk) break;
            PROC(ljC, ccC, etC); ljC = ljn; ljn += 2; FETCH(ljC, ccC, etC);
            if (ljD >= nchunk) break;
            PROC(ljD, ccD, etD); ljD = ljn; ljn += 2; FETCH(ljD, ccD, etD);
        }
    }

    // ---- reductions (within this node's single wave) ----
    #pragma unroll
    for (int f = 0; f < 4; ++f) ag[f] += __shfl_xor(ag[f], 32);   // combine parities
    #pragma unroll
    for (int off = 1; off <= 32; off <<= 1) {
        sx += __shfl_xor(sx, off);
        sy += __shfl_xor(sy, off);
        sz += __shfl_xor(sz, off);
    }
    if (l < 32) {
        int c2 = 16 + (p >> 1);
        int slot = c2 ^ (i & 7);
        uint2 o;
        o.x = pack2(ag[0], ag[1]);
        o.y = pack2(ag[2], ag[3]);
        *(uint2*)&s_A[i * 256 + slot * 8 + (p & 1) * 4] = o;
    }
    float inv = 1.f / ((float)d + 1.f);
    if (l == 0) {
        x_out[gn * 3 + 0] = xd0 + sx * inv;
        x_out[gn * 3 + 1] = xd1 + sy * inv;
        x_out[gn * 3 + 2] = xd2 + sz * inv;
    }
    if (mode == 1 && l < 3) {
        float xv = (l == 0) ? (xd0 + sx * inv)
                 : (l == 1) ? (xd1 + sy * inv)
                            : (xd2 + sz * inv);
        out[(size_t)NN * IN_DIM + gn * 3 + l] = gmask[gn] ? xv : 0.f;
    }

    __syncthreads();

    // ---- Wh GEMM: wave w = N-tile w; B fragments straight from L2 ----
    float4v acc = (float4v){0.f, 0.f, 0.f, 0.f};
    #pragma unroll
    for (int t = 0; t < 4; ++t) {
        #pragma unroll
        for (int s = 0; s < 2; ++s) {
            int m = l & 15;
            int c = t * 8 + s * 4 + (l >> 4);
            int slot = c ^ (l & 7);
            short8 af = *(const short8*)(s_A + m * 256 + slot * 8);
            short8 bfv = *(const short8*)(Whp_l + (size_t)t * 8192 + ((s * 8 + w) * 64 + l) * 8);
            acc = __builtin_amdgcn_mfma_f32_16x16x32_bf16(af, bfv, acc, 0, 0, 0);
        }
    }
    // epilogue: hn = h + silu(acc + bh); write globals (mode 0) and s_h2 tile
    {
        int f = w * 16 + (l & 15);
        float bv = bh_l[f];
        #pragma unroll
        for (int r = 0; r < 4; ++r) {
            int m = (l >> 4) * 4 + r;
            u16 hb = 0;
            if (m < NUB) {
                int gn2 = n0 + m;
                float v = acc[r] + bv;
                float hn = h[(size_t)gn2 * HID + f] + silu(v);
                hb = f2bf(hn);
                if (mode == 0) {
                    h[(size_t)gn2 * HID + f] = hn;
                    h_bf[(size_t)gn2 * HID + f] = hb;
                }
            }
            int slot2 = (f >> 3) ^ (m & 7);
            s_h2[m * 128 + slot2 * 8 + (f & 7)] = hb;
        }
    }
    __syncthreads();

    if (mode == 0) {
        // ---- fused next-layer cvec: Csrc_n/Cdst_n = hn @ We_next (M=16,N=256,K=128) ----
        #pragma unroll
        for (int j = 0; j < 2; ++j) {
            int g = w * 2 + j;           // 0..15
            int sd = g >> 3, nt = g & 7;
            float4v a2 = (float4v){0.f, 0.f, 0.f, 0.f};
            #pragma unroll
            for (int kt = 0; kt < 2; ++kt) {
                #pragma unroll
                for (int s = 0; s < 2; ++s) {
                    int c = kt * 8 + s * 4 + (l >> 4);
                    int slot = c ^ (l & 7);
                    short8 af = *(const short8*)(s_h2 + (l & 15) * 128 + slot * 8);
                    short8 bfv = *(const short8*)(Wnext + (size_t)(sd * 2 + kt) * 8192
                                                  + ((s * 8 + nt) * 64 + l) * 8);
                    a2 = __builtin_amdgcn_mfma_f32_16x16x32_bf16(af, bfv, a2, 0, 0, 0);
                }
            }
            u16* Cout = sd ? Cdst_n : Csrc_n;
            int f = nt * 16 + (l & 15);
            #pragma unroll
            for (int r = 0; r < 4; ++r) {
                int m = (l >> 4) * 4 + r;
                if (m < NUB)
                    Cout[(size_t)(n0 + m) * 128 + f] = f2bf(a2[r]);
            }
        }
    } else {
        // ---- fused final: out = gmask ? hn @ h2i + b : 0 (M=16,N=64,K=128) ----
        if (w < 4) {
            int nt = w;
            float4v a2 = (float4v){0.f, 0.f, 0.f, 0.f};
            #pragma unroll
            for (int t = 0; t < 2; ++t) {
                #pragma unroll
                for (int s = 0; s < 2; ++s) {
                    int c = t * 8 + s * 4 + (l >> 4);
                    int slot = c ^ (l & 7);
                    short8 af = *(const short8*)(s_h2 + (l & 15) * 128 + slot * 8);
                    short8 bfv = *(const short8*)(Wnext + (size_t)t * 4096
                                                  + ((s * 4 + nt) * 64 + l) * 8);
                    a2 = __builtin_amdgcn_mfma_f32_16x16x32_bf16(af, bfv, a2, 0, 0, 0);
                }
            }
            int f = nt * 16 + (l & 15);
            float bv = bfin[f];
            #pragma unroll
            for (int r = 0; r < 4; ++r) {
                int m = (l >> 4) * 4 + r;
                if (m < NUB) {
                    int gn2 = n0 + m;
                    out[(size_t)gn2 * IN_DIM + f] = gmask[gn2] ? (a2[r] + bv) : 0.f;
                }
            }
        }
    }
}

// ================= fallback path (atomic, scalar; used only if ws too small) =================
__global__ __launch_bounds__(256) void init_fb_kernel(
    const float* __restrict__ X_t, const int* __restrict__ edges,
    float* __restrict__ x, float* __restrict__ cnt)
{
    int gid = blockIdx.x * blockDim.x + threadIdx.x;
    int stride = gridDim.x * blockDim.x;
    for (int i = gid; i < NN * 3; i += stride) x[i] = X_t[i];
    for (int e = gid; e < NE; e += stride)
        atomicAdd(&cnt[edges[NE + e]], 1.0f);
}

__global__ __launch_bounds__(128) void node_mlp_kernel(
    const float* __restrict__ H_t, const float* __restrict__ cond,
    const float* __restrict__ t_in,
    const float* __restrict__ W0, const float* __restrict__ b0,
    const float* __restrict__ W1, const float* __restrict__ b1,
    const float* __restrict__ W2, const float* __restrict__ b2,
    float* __restrict__ h)
{
    __shared__ float s_feat[D0][20];
    __shared__ float s_h0[HID][20];
    __shared__ float s_h1[HID][20];
    int n0 = blockIdx.x * 16;
    int tx = threadIdx.x;

    for (int idx = tx; idx < 16 * IN_DIM; idx += 128) {
        int i = idx >> 6, k = idx & 63;
        s_feat[k][i] = H_t[(n0 + i) * IN_DIM + k];
    }
    for (int idx = tx; idx < 16 * HID; idx += 128) {
        int i = idx >> 7, k = idx & 127;
        s_feat[IN_DIM + k][i] = cond[(n0 + i) * HID + k];
    }
    const float cfr = -logf(10000.f) / 63.f;
    for (int idx = tx; idx < 16 * HID; idx += 128) {
        int i = idx >> 7, k = idx & 127;
        float tv = t_in[n0 + i];
        int jj = k & 63;
        float ang = tv * __expf(cfr * (float)jj);
        s_feat[IN_DIM + HID + k][i] = (k < 64) ? __sinf(ang) : __cosf(ang);
    }
    __syncthreads();

    float acc[16];
    {
        float bv = b0[tx];
        #pragma unroll
        for (int i = 0; i < 16; ++i) acc[i] = bv;
        for (int k = 0; k < D0; ++k) {
            float w = W0[k * HID + tx];
            float4 f0 = *(const float4*)&s_feat[k][0];
            float4 f1 = *(const float4*)&s_feat[k][4];
            float4 f2 = *(const float4*)&s_feat[k][8];
            float4 f3 = *(const float4*)&s_feat[k][12];
            acc[0] += f0.x*w; acc[1] += f0.y*w; acc[2] += f0.z*w; acc[3] += f0.w*w;
            acc[4] += f1.x*w; acc[5] += f1.y*w; acc[6] += f1.z*w; acc[7] += f1.w*w;
            acc[8] += f2.x*w; acc[9] += f2.y*w; acc[10]+= f2.z*w; acc[11]+= f2.w*w;
            acc[12]+= f3.x*w; acc[13]+= f3.y*w; acc[14]+= f3.z*w; acc[15]+= f3.w*w;
        }
        #pragma unroll
        for (int i = 0; i < 16; ++i) s_h0[tx][i] = fmaxf(acc[i], 0.f);
    }
    __syncthreads();
    {
        float bv = b1[tx];
        #pragma unroll
        for (int i = 0; i < 16; ++i) acc[i] = bv;
        for (int k = 0; k < HID; ++k) {
            float w = W1[k * HID + tx];
            float4 f0 = *(const float4*)&s_h0[k][0];
            float4 f1 = *(const float4*)&s_h0[k][4];
            float4 f2 = *(const float4*)&s_h0[k][8];
            float4 f3 = *(const float4*)&s_h0[k][12];
            acc[0] += f0.x*w; acc[1] += f0.y*w; acc[2] += f0.z*w; acc[3] += f0.w*w;
            acc[4] += f1.x*w; acc[5] += f1.y*w; acc[6] += f1.z*w; acc[7] += f1.w*w;
            acc[8] += f2.x*w; acc[9] += f2.y*w; acc[10]+= f2.z*w; acc[11]+= f2.w*w;
            acc[12]+= f3.x*w; acc[13]+= f3.y*w; acc[14]+= f3.z*w; acc[15]+= f3.w*w;
        }
        #pragma unroll
        for (int i = 0; i < 16; ++i) s_h1[tx][i] = fmaxf(acc[i], 0.f);
    }
    __syncthreads();
    {
        float bv = b2[tx];
        #pragma unroll
        for (int i = 0; i < 16; ++i) acc[i] = bv;
        for (int k = 0; k < HID; ++k) {
            float w = W2[k * HID + tx];
            float4 f0 = *(const float4*)&s_h1[k][0];
            float4 f1 = *(const float4*)&s_h1[k][4];
            float4 f2 = *(const float4*)&s_h1[k][8];
            float4 f3 = *(const float4*)&s_h1[k][12];
            acc[0] += f0.x*w; acc[1] += f0.y*w; acc[2] += f0.z*w; acc[3] += f0.w*w;
            acc[4] += f1.x*w; acc[5] += f1.y*w; acc[6] += f1.z*w; acc[7] += f1.w*w;
            acc[8] += f2.x*w; acc[9] += f2.y*w; acc[10]+= f2.z*w; acc[11]+= f2.w*w;
            acc[12]+= f3.x*w; acc[13]+= f3.y*w; acc[14]+= f3.z*w; acc[15]+= f3.w*w;
        }
        #pragma unroll
        for (int i = 0; i < 16; ++i) h[(n0 + i) * HID + tx] = acc[i];
    }
}

__global__ __launch_bounds__(256) void edge_gemm_fb_kernel(
    const float* __restrict__ h, const float* __restrict__ x,
    const int* __restrict__ edges, const int* __restrict__ etype,
    const float* __restrict__ edge_table,
    const float* __restrict__ We_l, const float* __restrict__ be_l,
    const float* __restrict__ Wx_l, const float* __restrict__ bx_l,
    float* __restrict__ agg_m, float* __restrict__ agg_x)
{
    __shared__ int s_src[TILE_E], s_dst[TILE_E];
    __shared__ float s_diff[TILE_E][3];
    __shared__ float s_tail[TILE_E][36];
    __shared__ float s_Af[TILE_E][36];
    __shared__ float s_Bf[33][HID];
    __shared__ float s_wx[HID];

    int e0 = blockIdx.x * TILE_E;
    int tx = threadIdx.x;
    int tf = tx & 15;
    int te = tx >> 4;

    if (tx < TILE_E) {
        int s = edges[e0 + tx];
        int d = edges[NE + e0 + tx];
        s_src[tx] = s; s_dst[tx] = d;
        float dx = x[s * 3 + 0] - x[d * 3 + 0];
        float dy = x[s * 3 + 1] - x[d * 3 + 1];
        float dz = x[s * 3 + 2] - x[d * 3 + 2];
        s_diff[tx][0] = dx; s_diff[tx][1] = dy; s_diff[tx][2] = dz;
        s_tail[tx][0] = dx * dx + dy * dy + dz * dz;
        int et = etype[e0 + tx];
        #pragma unroll
        for (int j = 0; j < 32; ++j) s_tail[tx][1 + j] = edge_table[et * 32 + j];
    }
    if (tx < HID) s_wx[tx] = Wx_l[tx];
    __syncthreads();

    float acc[4][8];
    #pragma unroll
    for (int i = 0; i < 4; ++i)
        #pragma unroll
        for (int j = 0; j < 8; ++j) acc[i][j] = 0.f;

    for (int t = 0; t < 9; ++t) {
        int k0 = t * 32;
        int klen = (t == 8) ? 33 : 32;
        __syncthreads();
        if (t < 8) {
            const bool use_src = (t < 4);
            int kbase = (t & 3) * 32;
            for (int q4 = tx; q4 < TILE_E * 8; q4 += 256) {
                int e = q4 >> 3, q = q4 & 7;
                int row = use_src ? s_src[e] : s_dst[e];
                float4 v = *(const float4*)&h[row * HID + kbase + q * 4];
                *(float4*)&s_Af[e][q * 4] = v;
            }
        }
        for (int q4 = tx; q4 < klen * 32; q4 += 256) {
            int kk = q4 >> 5, c4 = q4 & 31;
            float4 v = *(const float4*)&We_l[(k0 + kk) * HID + c4 * 4];
            *(float4*)&s_Bf[kk][c4 * 4] = v;
        }
        __syncthreads();
        const float (*Asrc)[36] = (t == 8) ? (const float (*)[36])s_tail
                                           : (const float (*)[36])s_Af;
        for (int kk = 0; kk < klen; ++kk) {
            float a0 = Asrc[te * 4 + 0][kk];
            float a1 = Asrc[te * 4 + 1][kk];
            float a2 = Asrc[te * 4 + 2][kk];
            float a3 = Asrc[te * 4 + 3][kk];
            float4 bv0 = *(const float4*)&s_Bf[kk][tf * 8];
            float4 bv1 = *(const float4*)&s_Bf[kk][tf * 8 + 4];
            float b[8] = {bv0.x, bv0.y, bv0.z, bv0.w, bv1.x, bv1.y, bv1.z, bv1.w};
            #pragma unroll
            for (int j = 0; j < 8; ++j) {
                acc[0][j] += a0 * b[j];
                acc[1][j] += a1 * b[j];
                acc[2][j] += a2 * b[j];
                acc[3][j] += a3 * b[j];
            }
        }
    }

    float wsum[4];
    #pragma unroll
    for (int i = 0; i < 4; ++i) {
        float p = 0.f;
        #pragma unroll
        for (int j = 0; j < 8; ++j) {
            int f = tf * 8 + j;
            float v = acc[i][j] + be_l[f];
            float m = silu(v);
            acc[i][j] = m;
            p += m * s_wx[f];
        }
        wsum[i] = p;
    }
    #pragma unroll
    for (int off = 1; off < 16; off <<= 1) {
        #pragma unroll
        for (int i = 0; i < 4; ++i) wsum[i] += __shfl_xor(wsum[i], off);
    }
    float bxv = bx_l[0];
    if (tf < 3) {
        #pragma unroll
        for (int i = 0; i < 4; ++i) {
            int e = te * 4 + i;
            float w2 = wsum[i] + bxv;
            atomicAdd(&agg_x[s_dst[e] * 3 + tf], s_diff[e][tf] * w2);
        }
    }
    #pragma unroll
    for (int i = 0; i < 4; ++i) {
        int d = s_dst[te * 4 + i];
        #pragma unroll
        for (int j = 0; j < 8; ++j)
            atomicAdd(&agg_m[d * HID + tf * 8 + j], acc[i][j]);
    }
}

__global__ __launch_bounds__(128) void node_update_fb_kernel(
    float* __restrict__ h, float* __restrict__ x,
    const float* __restrict__ agg_m, const float* __restrict__ agg_x,
    const float* __restrict__ cnt,
    const float* __restrict__ Wh_l, const float* __restrict__ bh_l)
{
    __shared__ float s_in[256][20];
    int n0 = blockIdx.x * 16;
    int tx = threadIdx.x;
    for (int idx = tx; idx < 16 * HID; idx += 128) {
        int i = idx >> 7, k = idx & 127;
        s_in[k][i] = h[(n0 + i) * HID + k];
    }
    for (int idx = tx; idx < 16 * HID; idx += 128) {
        int i = idx >> 7, k = idx & 127;
        s_in[HID + k][i] = agg_m[(n0 + i) * HID + k];
    }
    __syncthreads();
    float acc[16];
    float bv = bh_l[tx];
    #pragma unroll
    for (int i = 0; i < 16; ++i) acc[i] = bv;
    for (int k = 0; k < 256; ++k) {
        float w = Wh_l[k * HID + tx];
        float4 f0 = *(const float4*)&s_in[k][0];
        float4 f1 = *(const float4*)&s_in[k][4];
        float4 f2 = *(const float4*)&s_in[k][8];
        float4 f3 = *(const float4*)&s_in[k][12];
        acc[0] += f0.x*w; acc[1] += f0.y*w; acc[2] += f0.z*w; acc[3] += f0.w*w;
        acc[4] += f1.x*w; acc[5] += f1.y*w; acc[6] += f1.z*w; acc[7] += f1.w*w;
        acc[8] += f2.x*w; acc[9] += f2.y*w; acc[10]+= f2.z*w; acc[11]+= f2.w*w;
        acc[12]+= f3.x*w; acc[13]+= f3.y*w; acc[14]+= f3.z*w; acc[15]+= f3.w*w;
    }
    #pragma unroll
    for (int i = 0; i < 16; ++i) {
        float v = acc[i];
        h[(n0 + i) * HID + tx] = s_in[tx][i] + silu(v);
    }
    if (tx < 48) {
        int i = tx / 3, c = tx % 3;
        int n = n0 + i;
        x[n * 3 + c] += agg_x[n * 3 + c] / (cnt[n] + 1.f);
    }
}

__global__ __launch_bounds__(64) void final_fb_kernel(
    const float* __restrict__ h, const float* __restrict__ x,
    const int* __restrict__ gmask,
    const float* __restrict__ W, const float* __restrict__ b,
    float* __restrict__ out)
{
    __shared__ float s_h[8][HID];
    int n0 = blockIdx.x * 8;
    int tx = threadIdx.x;
    for (int idx = tx; idx < 8 * HID; idx += 64) {
        int i = idx >> 7, k = idx & 127;
        s_h[i][k] = h[(n0 + i) * HID + k];
    }
    __syncthreads();
    float acc[8];
    float bv = b[tx];
    #pragma unroll
    for (int i = 0; i < 8; ++i) acc[i] = bv;
    for (int k = 0; k < HID; ++k) {
        float w = W[k * IN_DIM + tx];
        #pragma unroll
        for (int i = 0; i < 8; ++i) acc[i] += s_h[i][k] * w;
    }
    #pragma unroll
    for (int i = 0; i < 8; ++i) {
        int n = n0 + i;
        out[n * IN_DIM + tx] = gmask[n] ? acc[i] : 0.f;
    }
    if (tx < 24) {
        int i = tx / 3, c = tx % 3;
        int n = n0 + i;
        out[NN * IN_DIM + n * 3 + c] = gmask[n] ? x[n * 3 + c] : 0.f;
    }
}

extern "C" void kernel_launch(void* const* d_in, const int* in_sizes, int n_in,
                              void* d_out, int out_size, void* d_ws, size_t ws_size,
                              hipStream_t stream) {
    const float* H_t   = (const float*)d_in[0];
    const float* X_t   = (const float*)d_in[1];
    const float* cond  = (const float*)d_in[2];
    const float* t_in  = (const float*)d_in[3];
    const int*   edges = (const int*)d_in[4];
    const int*   etype = (const int*)d_in[5];
    const int*   gmask = (const int*)d_in[6];
    const float* W0 = (const float*)d_in[8];
    const float* b0 = (const float*)d_in[9];
    const float* W1 = (const float*)d_in[10];
    const float* b1 = (const float*)d_in[11];
    const float* W2 = (const float*)d_in[12];
    const float* b2 = (const float*)d_in[13];
    const float* edge_table = (const float*)d_in[14];
    const float* We = (const float*)d_in[15];
    const float* be = (const float*)d_in[16];
    const float* Wx = (const float*)d_in[17];
    const float* bx = (const float*)d_in[18];
    const float* Wh = (const float*)d_in[19];
    const float* bh = (const float*)d_in[20];
    const float* h2i_W = (const float*)d_in[21];
    const float* h2i_b = (const float*)d_in[22];

    char* p = (char*)d_ws;
    float* h = (float*)p;           p += (size_t)NN * HID * 4;
    u16* h_bf = (u16*)p;            p += (size_t)NN * HID * 2;
    float* xa = (float*)p;          p += (size_t)NN * 3 * 4;
    float* xb = (float*)p;          p += (size_t)NN * 3 * 4;
    u16* Ca_s = (u16*)p;            p += (size_t)NN * 128 * 2;
    u16* Ca_d = (u16*)p;            p += (size_t)NN * 128 * 2;
    u16* Cb_s = (u16*)p;            p += (size_t)NN * 128 * 2;
    u16* Cb_d = (u16*)p;            p += (size_t)NN * 128 * 2;
    u16* Bpack = (u16*)p;           p += (size_t)PACK_TOT * 2;
    float* tv = (float*)p;          p += (size_t)768 * 4;
    float* wed2 = (float*)p;        p += (size_t)384 * 4;
    int* row_start = (int*)p;       p += (size_t)(NN + 4) * 4;
    int* deg = (int*)p;             p += (size_t)NN * 4;
    int* head = (int*)p;            p += (size_t)NN * 4;
    int* src_s = (int*)p;           p += (size_t)NE * 4;
    size_t need = (size_t)(p - (char*)d_ws);

    if (ws_size >= need) {
        prep_kernel<<<(PREP_TOT + 255) / 256, 256, 0, stream>>>(
            We, W0, W1, W2, Wh, h2i_W, edge_table, be, Bpack, tv, wed2, deg);
        hist_kernel<<<256, 256, 0, stream>>>(X_t, edges, xa, deg);
        scan_kernel<<<1, 1024, 0, stream>>>(deg, row_start, head);
        scatter_kernel<<<256, 256, 0, stream>>>(edges, etype, head, src_s);
        node_mlp_mfma_kernel<<<NB64, 256, 0, stream>>>(
            H_t, cond, t_in,
            Bpack + OFF_W0, b0, Bpack + OFF_W1, b1, Bpack + OFF_W2, b2,
            Bpack + OFF_WE, Ca_s, Ca_d,
            h, h_bf);
        for (int l = 0; l < 3; ++l) {
            const float* xin = (l & 1) ? xb : xa;
            float* xout = (l & 1) ? xa : xb;
            const u16* cs_in = (l & 1) ? Cb_s : Ca_s;
            const u16* cd_in = (l & 1) ? Cb_d : Ca_d;
            u16* cs_out = (l & 1) ? Ca_s : Cb_s;
            u16* cd_out = (l & 1) ? Ca_d : Cb_d;
            int mode = (l == 2) ? 1 : 0;
            const u16* Wnext = mode ? (Bpack + OFF_H2I)
                                    : (Bpack + OFF_WE + (size_t)(l + 1) * 40960);
            node_fused_kernel<<<NN / NUB, 512, 0, stream>>>(
                h, h_bf, xin, xout, cs_in, cd_in, cs_out, cd_out,
                Wnext, h2i_b, gmask, (float*)d_out,
                src_s, row_start,
                tv + (size_t)l * 256, wed2 + (size_t)l * 128,
                Wx + l * HID, bx + l,
                Bpack + OFF_WH + (size_t)l * 32768, bh + l * HID,
                mode);
        }
    } else {
        // fallback: scalar atomic path (~21 MB)
        float* ws    = (float*)d_ws;
        float* fh    = ws;
        float* fx    = fh + NN * HID;
        float* cnt   = fx + NN * 3;
        float* fagg_m = cnt + NN;
        float* fagg_x = fagg_m + NN * HID;

        hipMemsetAsync(cnt, 0, NN * sizeof(float), stream);
        init_fb_kernel<<<256, 256, 0, stream>>>(X_t, edges, fx, cnt);
        node_mlp_kernel<<<NN / 16, 128, 0, stream>>>(H_t, cond, t_in,
                                                     W0, b0, W1, b1, W2, b2, fh);
        for (int l = 0; l < 3; ++l) {
            hipMemsetAsync(fagg_m, 0, (size_t)NN * 131 * sizeof(float), stream);
            edge_gemm_fb_kernel<<<NE / TILE_E, 256, 0, stream>>>(
                fh, fx, edges, etype, edge_table,
                We + (size_t)l * DE * HID, be + l * HID,
                Wx + l * HID, bx + l, fagg_m, fagg_x);
            node_update_fb_kernel<<<NN / 16, 128, 0, stream>>>(
                fh, fx, fagg_m, fagg_x, cnt,
                Wh + (size_t)l * 256 * HID, bh + l * HID);
        }
        final_fb_kernel<<<NN / 8, 64, 0, stream>>>(fh, fx, gmask, h2i_W, h2i_b, (float*)d_out);
    }
}

// Round 8
// 297.415 us; speedup vs baseline: 1.3425x; 1.1889x over previous
//
#include <hip/hip_runtime.h>
#include <math.h>

#define NN 20000
#define NE 256000
#define IN_DIM 64
#define HID 128
#define DE 289     // 2*HID + 1 + 32
#define D0 320     // IN_DIM + 2*HID
#define TILE_E 64
#define NB64 313   // ceil(NN/64)
#define NUB 16     // nodes per block (fused node kernel); NN % NUB == 0
#define SCB 79     // ceil(NN/256) scan blocks
#define SRCMASK 0x3FFFFFFF

typedef unsigned short u16;
typedef unsigned int u32;
typedef unsigned long long u64;
typedef __attribute__((ext_vector_type(8))) short short8;
typedef __attribute__((ext_vector_type(4))) float float4v;

// Bpack layout offsets (u16 elements)
#define OFF_WE   0          // 3 x 40960 (K=289 pad 320, N=128) — tiles 0..3 = We rows 0..255
#define OFF_W0   122880     // 40960 (K=320, N=128)
#define OFF_W1   163840     // 16384 (K=128, N=128)
#define OFF_W2   180224     // 16384
#define OFF_WH   196608     // 3 x 32768 (K=256, N=128)
#define OFF_H2I  294912     // 8192 (K=128, N=64)
#define PACK_TOT 303104
#define PREP_TOT (PACK_TOT + 1152 + NN)   // pack + tv/wed2 + deg-zero

static __device__ __forceinline__ u16 f2bf(float f) {
    unsigned int u = __float_as_uint(f);
    u += 0x7fffu + ((u >> 16) & 1u);
    return (u16)(u >> 16);
}
static __device__ __forceinline__ float bf2f(u16 s) {
    return __uint_as_float(((unsigned int)s) << 16);
}
static __device__ __forceinline__ float bflo(u32 u) { return bf2f((u16)(u & 0xffffu)); }
static __device__ __forceinline__ float bfhi(u32 u) { return bf2f((u16)(u >> 16)); }
static __device__ __forceinline__ u32 pack2(float a, float b) {
    return (u32)f2bf(a) | ((u32)f2bf(b) << 16);
}
static __device__ __forceinline__ uint4 pack8(const float* v) {
    uint4 r;
    r.x = (u32)f2bf(v[0]) | ((u32)f2bf(v[1]) << 16);
    r.y = (u32)f2bf(v[2]) | ((u32)f2bf(v[3]) << 16);
    r.z = (u32)f2bf(v[4]) | ((u32)f2bf(v[5]) << 16);
    r.w = (u32)f2bf(v[6]) | ((u32)f2bf(v[7]) << 16);
    return r;
}
static __device__ __forceinline__ float silu(float v) {
    return v * (1.f / (1.f + __expf(-v)));
}

// ================= CSR build =================
__global__ __launch_bounds__(256) void hist_kernel(
    const float* __restrict__ X_t, const int* __restrict__ edges,
    float* __restrict__ x, int* __restrict__ deg)
{
    int gid = blockIdx.x * blockDim.x + threadIdx.x;
    int stride = gridDim.x * blockDim.x;
    for (int i = gid; i < NN * 3; i += stride) x[i] = X_t[i];
    for (int e = gid; e < NE; e += stride)
        atomicAdd(&deg[edges[NE + e]], 1);
}

// 3-phase scan: block-local exclusive scan -> partial scan -> offset add
__global__ __launch_bounds__(256) void scan1_kernel(
    const int* __restrict__ deg, int* __restrict__ row_start, int* __restrict__ bsum)
{
    __shared__ int s[256];
    int t = threadIdx.x;
    int n = blockIdx.x * 256 + t;
    int v = (n < NN) ? deg[n] : 0;
    s[t] = v;
    __syncthreads();
    for (int off = 1; off < 256; off <<= 1) {
        int u = (t >= off) ? s[t - off] : 0;
        __syncthreads();
        s[t] += u;
        __syncthreads();
    }
    if (n < NN) row_start[n] = s[t] - v;   // exclusive within block
    if (t == 255) bsum[blockIdx.x] = s[255];
}

__global__ __launch_bounds__(128) void scan2_kernel(
    int* __restrict__ bsum, int* __restrict__ row_start)
{
    __shared__ int s[128];
    int t = threadIdx.x;
    int v = (t < SCB) ? bsum[t] : 0;
    s[t] = v;
    __syncthreads();
    for (int off = 1; off < 128; off <<= 1) {
        int u = (t >= off) ? s[t - off] : 0;
        __syncthreads();
        s[t] += u;
        __syncthreads();
    }
    if (t < SCB) bsum[t] = s[t] - v;       // exclusive block offsets
    if (t == SCB - 1) row_start[NN] = s[t];
}

__global__ __launch_bounds__(256) void scan3_kernel(
    int* __restrict__ row_start, const int* __restrict__ bsum, int* __restrict__ head)
{
    int n = blockIdx.x * 256 + threadIdx.x;
    if (n < NN) {
        int v = row_start[n] + bsum[blockIdx.x];
        row_start[n] = v;
        head[n] = v;
    }
}

// permute edges into dst-sorted order; pack etype into src bit 30
__global__ __launch_bounds__(256) void scatter_kernel(
    const int* __restrict__ edges, const int* __restrict__ etype,
    int* __restrict__ head,
    int* __restrict__ src_s)
{
    int gid = blockIdx.x * blockDim.x + threadIdx.x;
    int stride = gridDim.x * blockDim.x;
    for (int e = gid; e < NE; e += stride) {
        int d = edges[NE + e];
        int p = atomicAdd(&head[d], 1);
        src_s[p] = edges[e] | (etype[e] << 30);
    }
}

// ================= combined prep: weight packing + edge tail precompute + deg zero =================
__global__ __launch_bounds__(256) void prep_kernel(
    const float* __restrict__ We, const float* __restrict__ W0,
    const float* __restrict__ W1, const float* __restrict__ W2,
    const float* __restrict__ Wh, const float* __restrict__ h2i,
    const float* __restrict__ edge_table, const float* __restrict__ be,
    u16* __restrict__ Bp, float* __restrict__ tv, float* __restrict__ wed2,
    int* __restrict__ deg)
{
    int idx = blockIdx.x * 256 + threadIdx.x;
    if (idx < PACK_TOT) {
        const float* src; int N = 128, Ksrc; int r;
        if (idx < OFF_W0) {
            int layer = idx / 40960; r = idx - layer * 40960;
            src = We + (size_t)layer * DE * HID; Ksrc = DE;
        } else if (idx < OFF_W1) { r = idx - OFF_W0; src = W0; Ksrc = 320; }
        else if (idx < OFF_W2)   { r = idx - OFF_W1; src = W1; Ksrc = 128; }
        else if (idx < OFF_WH)   { r = idx - OFF_W2; src = W2; Ksrc = 128; }
        else if (idx < OFF_H2I) {
            int t = idx - OFF_WH; int layer = t / 32768; r = t - layer * 32768;
            src = Wh + (size_t)layer * 256 * HID; Ksrc = 256;
        } else { r = idx - OFF_H2I; src = h2i; Ksrc = 128; N = 64; }
        int ntc = N / 16;
        int j = r & 7, lane = (r >> 3) & 63;
        int rem = r >> 9;
        int nt = rem % ntc, ks = rem / ntc;
        int k = ks * 32 + ((lane >> 4) << 3) + j;
        int c = nt * 16 + (lane & 15);
        Bp[idx] = f2bf((k < Ksrc) ? src[(size_t)k * N + c] : 0.f);
    } else if (idx < PACK_TOT + 768) {
        int q = idx - PACK_TOT;
        int f = q & 127, t = (q >> 7) & 1, l = q >> 8;
        float acc = be[l * 128 + f];
        const float* W = We + (size_t)l * DE * HID;
        #pragma unroll
        for (int k = 0; k < 32; ++k)
            acc += edge_table[t * 32 + k] * W[(size_t)(257 + k) * HID + f];
        tv[l * 256 + t * 128 + f] = acc;
    } else if (idx < PACK_TOT + 1152) {
        int r = idx - PACK_TOT - 768;
        int f = r & 127, l = r >> 7;
        wed2[l * 128 + f] = We[(size_t)l * DE * HID + (size_t)256 * HID + f];
    } else if (idx < PREP_TOT) {
        deg[idx - PACK_TOT - 1152] = 0;
    }
}

// ================= node MLP: MFMA, 64 nodes/block + fused cvec layer-0 =================
__global__ __launch_bounds__(256) void node_mlp_mfma_kernel(
    const float* __restrict__ H_t, const float* __restrict__ cond,
    const float* __restrict__ t_in,
    const u16* __restrict__ W0p, const float* __restrict__ b0,
    const u16* __restrict__ W1p, const float* __restrict__ b1,
    const u16* __restrict__ W2p, const float* __restrict__ b2,
    const u16* __restrict__ WEp,
    u16* __restrict__ Csrc, u16* __restrict__ Cdst,
    float* __restrict__ h, u16* __restrict__ h_bf)
{
    __shared__ u16 s_A[64 * 64];
    __shared__ u16 s_B[64 * 128];
    __shared__ u16 s_h[64 * 128];
    __shared__ float s_t[64];

    int tx = threadIdx.x;
    int n0 = blockIdx.x * 64;
    int l = tx & 63, w = tx >> 6;
    int mt_base = (w & 1) * 2, nt_base = (w >> 1) * 4;
    const float cfr = -logf(10000.f) / 63.f;

    if (tx < 64) s_t[tx] = (n0 + tx < NN) ? t_in[n0 + tx] : 0.f;

    float4v acc[2][4];
    #pragma unroll
    for (int mi = 0; mi < 2; ++mi)
        #pragma unroll
        for (int ni = 0; ni < 4; ++ni) acc[mi][ni] = (float4v){0.f,0.f,0.f,0.f};

    for (int t = 0; t < 5; ++t) {
        __syncthreads();
        #pragma unroll
        for (int it = 0; it < 2; ++it) {
            int flat = it * 256 + tx;
            int n = flat >> 3, sl = flat & 7;
            int c = sl ^ (n & 7);
            int k0 = t * 64 + c * 8;
            float tv8[8];
            int gn = n0 + n;
            if (gn < NN) {
                if (k0 < 192) {
                    const float* src = (k0 < 64) ? &H_t[(size_t)gn * IN_DIM + k0]
                                                 : &cond[(size_t)gn * HID + (k0 - 64)];
                    float4 a = *(const float4*)src;
                    float4 b = *(const float4*)(src + 4);
                    tv8[0]=a.x; tv8[1]=a.y; tv8[2]=a.z; tv8[3]=a.w;
                    tv8[4]=b.x; tv8[5]=b.y; tv8[6]=b.z; tv8[7]=b.w;
                } else {
                    float tvv = s_t[n];
                    int jj = (k0 - 192) & 63;
                    bool is_sin = (k0 < 256);
                    #pragma unroll
                    for (int jx = 0; jx < 8; ++jx) {
                        float ang = tvv * __expf(cfr * (float)(jj + jx));
                        tv8[jx] = is_sin ? __sinf(ang) : __cosf(ang);
                    }
                }
            } else {
                #pragma unroll
                for (int jx = 0; jx < 8; ++jx) tv8[jx] = 0.f;
            }
            *(uint4*)&s_A[n * 64 + sl * 8] = pack8(tv8);
        }
        #pragma unroll
        for (int it = 0; it < 4; ++it) {
            int flat = it * 256 + tx;
            ((uint4*)s_B)[flat] = ((const uint4*)(W0p + (size_t)t * 8192))[flat];
        }
        __syncthreads();
        #pragma unroll
        for (int s = 0; s < 2; ++s) {
            short8 af[2], bfv[4];
            #pragma unroll
            for (int mi = 0; mi < 2; ++mi) {
                int m = (mt_base + mi) * 16 + (l & 15);
                int c = s * 4 + (l >> 4);
                int slot = c ^ (l & 7);
                af[mi] = *(const short8*)(s_A + m * 64 + slot * 8);
            }
            #pragma unroll
            for (int ni = 0; ni < 4; ++ni)
                bfv[ni] = *(const short8*)(s_B + ((s * 8 + nt_base + ni) * 64 + l) * 8);
            #pragma unroll
            for (int mi = 0; mi < 2; ++mi)
                #pragma unroll
                for (int ni = 0; ni < 4; ++ni)
                    acc[mi][ni] = __builtin_amdgcn_mfma_f32_16x16x32_bf16(
                        af[mi], bfv[ni], acc[mi][ni], 0, 0, 0);
        }
    }
    #pragma unroll
    for (int mi = 0; mi < 2; ++mi) {
        #pragma unroll
        for (int ni = 0; ni < 4; ++ni) {
            int f = (nt_base + ni) * 16 + (l & 15);
            float bv = b0[f];
            #pragma unroll
            for (int r = 0; r < 4; ++r) {
                int m = (mt_base + mi) * 16 + (l >> 4) * 4 + r;
                float v = fmaxf(acc[mi][ni][r] + bv, 0.f);
                int slot = (f >> 3) ^ (m & 7);
                s_h[m * 128 + slot * 8 + (f & 7)] = f2bf(v);
            }
            acc[mi][ni] = (float4v){0.f,0.f,0.f,0.f};
        }
    }
    for (int t = 0; t < 2; ++t) {
        __syncthreads();
        #pragma unroll
        for (int it = 0; it < 4; ++it) {
            int flat = it * 256 + tx;
            ((uint4*)s_B)[flat] = ((const uint4*)(W1p + (size_t)t * 8192))[flat];
        }
        __syncthreads();
        #pragma unroll
        for (int s = 0; s < 2; ++s) {
            short8 af[2], bfv[4];
            #pragma unroll
            for (int mi = 0; mi < 2; ++mi) {
                int m = (mt_base + mi) * 16 + (l & 15);
                int c = t * 8 + s * 4 + (l >> 4);
                int slot = c ^ (l & 7);
                af[mi] = *(const short8*)(s_h + m * 128 + slot * 8);
            }
            #pragma unroll
            for (int ni = 0; ni < 4; ++ni)
                bfv[ni] = *(const short8*)(s_B + ((s * 8 + nt_base + ni) * 64 + l) * 8);
            #pragma unroll
            for (int mi = 0; mi < 2; ++mi)
                #pragma unroll
                for (int ni = 0; ni < 4; ++ni)
                    acc[mi][ni] = __builtin_amdgcn_mfma_f32_16x16x32_bf16(
                        af[mi], bfv[ni], acc[mi][ni], 0, 0, 0);
        }
    }
    __syncthreads();
    #pragma unroll
    for (int mi = 0; mi < 2; ++mi) {
        #pragma unroll
        for (int ni = 0; ni < 4; ++ni) {
            int f = (nt_base + ni) * 16 + (l & 15);
            float bv = b1[f];
            #pragma unroll
            for (int r = 0; r < 4; ++r) {
                int m = (mt_base + mi) * 16 + (l >> 4) * 4 + r;
                float v = fmaxf(acc[mi][ni][r] + bv, 0.f);
                int slot = (f >> 3) ^ (m & 7);
                s_h[m * 128 + slot * 8 + (f & 7)] = f2bf(v);
            }
            acc[mi][ni] = (float4v){0.f,0.f,0.f,0.f};
        }
    }
    for (int t = 0; t < 2; ++t) {
        __syncthreads();
        #pragma unroll
        for (int it = 0; it < 4; ++it) {
            int flat = it * 256 + tx;
            ((uint4*)s_B)[flat] = ((const uint4*)(W2p + (size_t)t * 8192))[flat];
        }
        __syncthreads();
        #pragma unroll
        for (int s = 0; s < 2; ++s) {
            short8 af[2], bfv[4];
            #pragma unroll
            for (int mi = 0; mi < 2; ++mi) {
                int m = (mt_base + mi) * 16 + (l & 15);
                int c = t * 8 + s * 4 + (l >> 4);
                int slot = c ^ (l & 7);
                af[mi] = *(const short8*)(s_h + m * 128 + slot * 8);
            }
            #pragma unroll
            for (int ni = 0; ni < 4; ++ni)
                bfv[ni] = *(const short8*)(s_B + ((s * 8 + nt_base + ni) * 64 + l) * 8);
            #pragma unroll
            for (int mi = 0; mi < 2; ++mi)
                #pragma unroll
                for (int ni = 0; ni < 4; ++ni)
                    acc[mi][ni] = __builtin_amdgcn_mfma_f32_16x16x32_bf16(
                        af[mi], bfv[ni], acc[mi][ni], 0, 0, 0);
        }
    }
    // final h: write globals AND store into s_h (swizzled) for the fused cvec
    __syncthreads();   // protect s_h against pending W2-stage reads
    #pragma unroll
    for (int mi = 0; mi < 2; ++mi) {
        #pragma unroll
        for (int ni = 0; ni < 4; ++ni) {
            int f = (nt_base + ni) * 16 + (l & 15);
            float bv = b2[f];
            #pragma unroll
            for (int r = 0; r < 4; ++r) {
                int m = (mt_base + mi) * 16 + (l >> 4) * 4 + r;
                int gn = n0 + m;
                float v = acc[mi][ni][r] + bv;
                int slot = (f >> 3) ^ (m & 7);
                s_h[m * 128 + slot * 8 + (f & 7)] = f2bf(v);
                if (gn < NN) {
                    h[(size_t)gn * HID + f] = v;
                    h_bf[(size_t)gn * HID + f] = f2bf(v);
                }
            }
        }
    }

    // ---- fused cvec (layer 0): Csrc[n]=h@We_src, Cdst[n]=h@We_dst ----
    for (int sd = 0; sd < 2; ++sd) {
        #pragma unroll
        for (int mi = 0; mi < 2; ++mi)
            #pragma unroll
            for (int ni = 0; ni < 4; ++ni) acc[mi][ni] = (float4v){0.f,0.f,0.f,0.f};
        #pragma unroll
        for (int th = 0; th < 2; ++th) {
            int t = sd * 2 + th;
            __syncthreads();
            #pragma unroll
            for (int it = 0; it < 4; ++it) {
                int flat = it * 256 + tx;
                ((uint4*)s_B)[flat] = ((const uint4*)(WEp + (size_t)t * 8192))[flat];
            }
            __syncthreads();
            #pragma unroll
            for (int s = 0; s < 2; ++s) {
                short8 af[2], bfv[4];
                #pragma unroll
                for (int mi = 0; mi < 2; ++mi) {
                    int m = (mt_base + mi) * 16 + (l & 15);
                    int c = th * 8 + s * 4 + (l >> 4);
                    int slot = c ^ (l & 7);
                    af[mi] = *(const short8*)(s_h + m * 128 + slot * 8);
                }
                #pragma unroll
                for (int ni = 0; ni < 4; ++ni)
                    bfv[ni] = *(const short8*)(s_B + ((s * 8 + nt_base + ni) * 64 + l) * 8);
                #pragma unroll
                for (int mi = 0; mi < 2; ++mi)
                    #pragma unroll
                    for (int ni = 0; ni < 4; ++ni)
                        acc[mi][ni] = __builtin_amdgcn_mfma_f32_16x16x32_bf16(
                            af[mi], bfv[ni], acc[mi][ni], 0, 0, 0);
            }
        }
        u16* Cout = (sd == 0) ? Csrc : Cdst;
        #pragma unroll
        for (int mi = 0; mi < 2; ++mi) {
            #pragma unroll
            for (int ni = 0; ni < 4; ++ni) {
                int fq = (nt_base + ni) * 16 + (l & 15);
                #pragma unroll
                for (int r = 0; r < 4; ++r) {
                    int m = (mt_base + mi) * 16 + (l >> 4) * 4 + r;
                    int gn = n0 + m;
                    if (gn < NN)
                        Cout[(size_t)gn * 128 + fq] = f2bf(acc[mi][ni][r]);
                }
            }
        }
    }
}

// ================= fused node update v8: NUB=16 (wave = 2 nodes), fused next-cvec / final =================
// mode 0: epilogue computes next layer's Csrc/Cdst from hn (in-block GEMM vs Wnext=WE[l+1] pack).
// mode 1 (last layer): epilogue computes out = gmask ? hn@h2i + b : 0, plus x outputs; skips h/h_bf writes.
__global__ __launch_bounds__(512, 4) void node_fused_kernel(
    float* __restrict__ h, u16* __restrict__ h_bf,
    const float* __restrict__ x_in, float* __restrict__ x_out,
    const u16* __restrict__ Csrc, const u16* __restrict__ Cdst,
    u16* __restrict__ Csrc_n, u16* __restrict__ Cdst_n,
    const u16* __restrict__ Wnext, const float* __restrict__ bfin,
    const int* __restrict__ gmask, float* __restrict__ out,
    const int* __restrict__ src_s,
    const int* __restrict__ row_start,
    const float* __restrict__ tv_l, const float* __restrict__ wed2_l,
    const float* __restrict__ Wx_l, const float* __restrict__ bx_l,
    const u16* __restrict__ Whp_l, const float* __restrict__ bh_l,
    int mode)
{
    __shared__ u16 s_A[16 * 256];      // 8 KB: 16 real rows [h | agg] xor-swizzled
    __shared__ u16 s_h2[16 * 128];     // 4 KB: hn tile for epilogue GEMM

    int tx = threadIdx.x;
    int n0 = blockIdx.x * NUB;
    int l = tx & 63, w = tx >> 6;      // 8 waves; wave w owns nodes 2w, 2w+1
    int p = l & 31, q = l >> 5;        // feat-chunk (4 feats), edge parity

    // ---- stage h rows 0..15 (chunks 0..15) — all real, no padding ----
    if (tx < 256) {
        int n = tx >> 4, c = tx & 15;
        int slot = c ^ (n & 7);
        uint4 v = *(const uint4*)(h_bf + (size_t)(n0 + n) * 128 + c * 8);
        *(uint4*)&s_A[n * 256 + slot * 8] = v;
    }

    // ---- layer constants (4 feats) ----
    float tva[4], d01[4], wed[4], wx[4];
    {
        float4 t0 = *(const float4*)(tv_l + p * 4);
        float4 t1 = *(const float4*)(tv_l + 128 + p * 4);
        float4 wd = *(const float4*)(wed2_l + p * 4);
        float4 wv = *(const float4*)(Wx_l + p * 4);
        tva[0] = t0.x; tva[1] = t0.y; tva[2] = t0.z; tva[3] = t0.w;
        d01[0] = t1.x - t0.x; d01[1] = t1.y - t0.y; d01[2] = t1.z - t0.z; d01[3] = t1.w - t0.w;
        wed[0] = wd.x; wed[1] = wd.y; wed[2] = wd.z; wed[3] = wd.w;
        wx[0] = wv.x; wx[1] = wv.y; wx[2] = wv.z; wx[3] = wv.w;
    }
    float bx32 = bx_l[0] * (1.f / 32.f);

    #pragma unroll
    for (int nn = 0; nn < 2; ++nn) {
        int i2 = 2 * w + nn;
        int gn = n0 + i2;

        float c0[4];
        {
            uint2 cd = *(const uint2*)(Cdst + (size_t)gn * 128 + p * 4);
            c0[0] = tva[0] + bflo(cd.x); c0[1] = tva[1] + bfhi(cd.x);
            c0[2] = tva[2] + bflo(cd.y); c0[3] = tva[3] + bfhi(cd.y);
        }
        int rs = row_start[gn], re = row_start[gn + 1];
        int d = re - rs;
        float xd0 = x_in[gn * 3 + 0], xd1 = x_in[gn * 3 + 1], xd2 = x_in[gn * 3 + 2];

        float ag[4] = {0.f, 0.f, 0.f, 0.f};
        float sx = 0.f, sy = 0.f, sz = 0.f;

        for (int e0 = 0; e0 < d; e0 += 64) {
            int nchunk = d - e0; if (nchunk > 64) nchunk = 64;
            int sp_l = (l < nchunk) ? src_s[rs + e0 + l] : 0;
            float gx_l = 0.f, gy_l = 0.f, gz_l = 0.f, d2_l = 0.f;
            if (l < nchunk) {
                int sm = sp_l & SRCMASK;
                gx_l = x_in[sm * 3 + 0] - xd0;
                gy_l = x_in[sm * 3 + 1] - xd1;
                gz_l = x_in[sm * 3 + 2] - xd2;
                d2_l = gx_l * gx_l + gy_l * gy_l + gz_l * gz_l;
            }

            auto FETCH = [&](int lj, uint2& cc, float& et) {
                int spE = __shfl(sp_l, lj);
                cc = make_uint2(0u, 0u); et = 0.f;
                if (lj < nchunk) {
                    cc = *(const uint2*)(Csrc + (size_t)(spE & SRCMASK) * 128 + p * 4);
                    et = (float)((u32)spE >> 30);
                }
            };
            auto PROC = [&](int lj, uint2 cc, float ee) {
                float dxe = __shfl(gx_l, lj);
                float dye = __shfl(gy_l, lj);
                float dze = __shfl(gz_l, lj);
                float d2e = __shfl(d2_l, lj);
                float av[4];
                av[0] = bflo(cc.x); av[1] = bfhi(cc.x);
                av[2] = bflo(cc.y); av[3] = bfhi(cc.y);
                float wpart = bx32;
                #pragma unroll
                for (int f = 0; f < 4; ++f) {
                    float t = __fmaf_rn(d2e, wed[f], c0[f]);
                    t = __fmaf_rn(ee, d01[f], t);
                    float v = av[f] + t;
                    float m = silu(v);
                    ag[f] += m;
                    wpart = __fmaf_rn(m, wx[f], wpart);
                }
                sx = __fmaf_rn(dxe, wpart, sx);
                sy = __fmaf_rn(dye, wpart, sy);
                sz = __fmaf_rn(dze, wpart, sz);
            };

            // 4-slot pipeline per parity (8 gathers in flight per wave)
            int ljA = q, ljB = q + 2, ljC = q + 4, ljD = q + 6, ljn = q + 8;
            uint2 ccA, ccB, ccC, ccD; float etA, etB, etC, etD;
            FETCH(ljA, ccA, etA); FETCH(ljB, ccB, etB);
            FETCH(ljC, ccC, etC); FETCH(ljD, ccD, etD);
            while (ljA < nchunk) {
                PROC(ljA, ccA, etA); ljA = ljn; ljn += 2; FETCH(ljA, ccA, etA);
                if (ljB >= nchunk) break;
                PROC(ljB, ccB, etB); ljB = ljn; ljn += 2; FETCH(ljB, ccB, etB);
                if (ljC >= nchunk) break;
                PROC(ljC, ccC, etC); ljC = ljn; ljn += 2; FETCH(ljC, ccC, etC);
                if (ljD >= nchunk) break;
                PROC(ljD, ccD, etD); ljD = ljn; ljn += 2; FETCH(ljD, ccD, etD);
            }
        }

        // ---- per-node reductions (within this wave) ----
        #pragma unroll
        for (int f = 0; f < 4; ++f) ag[f] += __shfl_xor(ag[f], 32);   // combine parities
        #pragma unroll
        for (int off = 1; off <= 32; off <<= 1) {
            sx += __shfl_xor(sx, off);
            sy += __shfl_xor(sy, off);
            sz += __shfl_xor(sz, off);
        }
        if (l < 32) {
            int c2 = 16 + (p >> 1);
            int slot = c2 ^ (i2 & 7);
            uint2 o;
            o.x = pack2(ag[0], ag[1]);
            o.y = pack2(ag[2], ag[3]);
            *(uint2*)&s_A[i2 * 256 + slot * 8 + (p & 1) * 4] = o;
        }
        float inv = 1.f / ((float)d + 1.f);
        if (l == 0) {
            x_out[gn * 3 + 0] = xd0 + sx * inv;
            x_out[gn * 3 + 1] = xd1 + sy * inv;
            x_out[gn * 3 + 2] = xd2 + sz * inv;
        }
        if (mode == 1 && l < 3) {
            float xv = (l == 0) ? (xd0 + sx * inv)
                     : (l == 1) ? (xd1 + sy * inv)
                                : (xd2 + sz * inv);
            out[(size_t)NN * IN_DIM + gn * 3 + l] = gmask[gn] ? xv : 0.f;
        }
    }

    __syncthreads();

    // ---- Wh GEMM: wave w = N-tile w; M=16 all real; B fragments straight from L2 ----
    float4v acc = (float4v){0.f, 0.f, 0.f, 0.f};
    #pragma unroll
    for (int t = 0; t < 4; ++t) {
        #pragma unroll
        for (int s = 0; s < 2; ++s) {
            int m = l & 15;
            int c = t * 8 + s * 4 + (l >> 4);
            int slot = c ^ (l & 7);
            short8 af = *(const short8*)(s_A + m * 256 + slot * 8);
            short8 bfv = *(const short8*)(Whp_l + (size_t)t * 8192 + ((s * 8 + w) * 64 + l) * 8);
            acc = __builtin_amdgcn_mfma_f32_16x16x32_bf16(af, bfv, acc, 0, 0, 0);
        }
    }
    // epilogue: hn = h + silu(acc + bh); write globals (mode 0) and s_h2 tile
    {
        int f = w * 16 + (l & 15);
        float bv = bh_l[f];
        #pragma unroll
        for (int r = 0; r < 4; ++r) {
            int m = (l >> 4) * 4 + r;
            int gn2 = n0 + m;
            float v = acc[r] + bv;
            float hn = h[(size_t)gn2 * HID + f] + silu(v);
            u16 hb = f2bf(hn);
            if (mode == 0) {
                h[(size_t)gn2 * HID + f] = hn;
                h_bf[(size_t)gn2 * HID + f] = hb;
            }
            int slot2 = (f >> 3) ^ (m & 7);
            s_h2[m * 128 + slot2 * 8 + (f & 7)] = hb;
        }
    }
    __syncthreads();

    if (mode == 0) {
        // ---- fused next-layer cvec: Csrc_n/Cdst_n = hn @ We_next (M=16,N=256,K=128) ----
        #pragma unroll
        for (int j = 0; j < 2; ++j) {
            int g = w * 2 + j;           // 0..15
            int sd = g >> 3, nt = g & 7;
            float4v a2 = (float4v){0.f, 0.f, 0.f, 0.f};
            #pragma unroll
            for (int kt = 0; kt < 2; ++kt) {
                #pragma unroll
                for (int s = 0; s < 2; ++s) {
                    int c = kt * 8 + s * 4 + (l >> 4);
                    int slot = c ^ (l & 7);
                    short8 af = *(const short8*)(s_h2 + (l & 15) * 128 + slot * 8);
                    short8 bfv = *(const short8*)(Wnext + (size_t)(sd * 2 + kt) * 8192
                                                  + ((s * 8 + nt) * 64 + l) * 8);
                    a2 = __builtin_amdgcn_mfma_f32_16x16x32_bf16(af, bfv, a2, 0, 0, 0);
                }
            }
            u16* Cout = sd ? Cdst_n : Csrc_n;
            int f = nt * 16 + (l & 15);
            #pragma unroll
            for (int r = 0; r < 4; ++r) {
                int m = (l >> 4) * 4 + r;
                Cout[(size_t)(n0 + m) * 128 + f] = f2bf(a2[r]);
            }
        }
    } else {
        // ---- fused final: out = gmask ? hn @ h2i + b : 0 (M=16,N=64,K=128) ----
        if (w < 4) {
            int nt = w;
            float4v a2 = (float4v){0.f, 0.f, 0.f, 0.f};
            #pragma unroll
            for (int t = 0; t < 2; ++t) {
                #pragma unroll
                for (int s = 0; s < 2; ++s) {
                    int c = t * 8 + s * 4 + (l >> 4);
                    int slot = c ^ (l & 7);
                    short8 af = *(const short8*)(s_h2 + (l & 15) * 128 + slot * 8);
                    short8 bfv = *(const short8*)(Wnext + (size_t)t * 4096
                                                  + ((s * 4 + nt) * 64 + l) * 8);
                    a2 = __builtin_amdgcn_mfma_f32_16x16x32_bf16(af, bfv, a2, 0, 0, 0);
                }
            }
            int f = nt * 16 + (l & 15);
            float bv = bfin[f];
            #pragma unroll
            for (int r = 0; r < 4; ++r) {
                int m = (l >> 4) * 4 + r;
                int gn2 = n0 + m;
                out[(size_t)gn2 * IN_DIM + f] = gmask[gn2] ? (a2[r] + bv) : 0.f;
            }
        }
    }
}

// ================= fallback path (atomic, scalar; used only if ws too small) =================
__global__ __launch_bounds__(256) void init_fb_kernel(
    const float* __restrict__ X_t, const int* __restrict__ edges,
    float* __restrict__ x, float* __restrict__ cnt)
{
    int gid = blockIdx.x * blockDim.x + threadIdx.x;
    int stride = gridDim.x * blockDim.x;
    for (int i = gid; i < NN * 3; i += stride) x[i] = X_t[i];
    for (int e = gid; e < NE; e += stride)
        atomicAdd(&cnt[edges[NE + e]], 1.0f);
}

__global__ __launch_bounds__(128) void node_mlp_kernel(
    const float* __restrict__ H_t, const float* __restrict__ cond,
    const float* __restrict__ t_in,
    const float* __restrict__ W0, const float* __restrict__ b0,
    const float* __restrict__ W1, const float* __restrict__ b1,
    const float* __restrict__ W2, const float* __restrict__ b2,
    float* __restrict__ h)
{
    __shared__ float s_feat[D0][20];
    __shared__ float s_h0[HID][20];
    __shared__ float s_h1[HID][20];
    int n0 = blockIdx.x * 16;
    int tx = threadIdx.x;

    for (int idx = tx; idx < 16 * IN_DIM; idx += 128) {
        int i = idx >> 6, k = idx & 63;
        s_feat[k][i] = H_t[(n0 + i) * IN_DIM + k];
    }
    for (int idx = tx; idx < 16 * HID; idx += 128) {
        int i = idx >> 7, k = idx & 127;
        s_feat[IN_DIM + k][i] = cond[(n0 + i) * HID + k];
    }
    const float cfr = -logf(10000.f) / 63.f;
    for (int idx = tx; idx < 16 * HID; idx += 128) {
        int i = idx >> 7, k = idx & 127;
        float tv = t_in[n0 + i];
        int jj = k & 63;
        float ang = tv * __expf(cfr * (float)jj);
        s_feat[IN_DIM + HID + k][i] = (k < 64) ? __sinf(ang) : __cosf(ang);
    }
    __syncthreads();

    float acc[16];
    {
        float bv = b0[tx];
        #pragma unroll
        for (int i = 0; i < 16; ++i) acc[i] = bv;
        for (int k = 0; k < D0; ++k) {
            float w = W0[k * HID + tx];
            float4 f0 = *(const float4*)&s_feat[k][0];
            float4 f1 = *(const float4*)&s_feat[k][4];
            float4 f2 = *(const float4*)&s_feat[k][8];
            float4 f3 = *(const float4*)&s_feat[k][12];
            acc[0] += f0.x*w; acc[1] += f0.y*w; acc[2] += f0.z*w; acc[3] += f0.w*w;
            acc[4] += f1.x*w; acc[5] += f1.y*w; acc[6] += f1.z*w; acc[7] += f1.w*w;
            acc[8] += f2.x*w; acc[9] += f2.y*w; acc[10]+= f2.z*w; acc[11]+= f2.w*w;
            acc[12]+= f3.x*w; acc[13]+= f3.y*w; acc[14]+= f3.z*w; acc[15]+= f3.w*w;
        }
        #pragma unroll
        for (int i = 0; i < 16; ++i) s_h0[tx][i] = fmaxf(acc[i], 0.f);
    }
    __syncthreads();
    {
        float bv = b1[tx];
        #pragma unroll
        for (int i = 0; i < 16; ++i) acc[i] = bv;
        for (int k = 0; k < HID; ++k) {
            float w = W1[k * HID + tx];
            float4 f0 = *(const float4*)&s_h0[k][0];
            float4 f1 = *(const float4*)&s_h0[k][4];
            float4 f2 = *(const float4*)&s_h0[k][8];
            float4 f3 = *(const float4*)&s_h0[k][12];
            acc[0] += f0.x*w; acc[1] += f0.y*w; acc[2] += f0.z*w; acc[3] += f0.w*w;
            acc[4] += f1.x*w; acc[5] += f1.y*w; acc[6] += f1.z*w; acc[7] += f1.w*w;
            acc[8] += f2.x*w; acc[9] += f2.y*w; acc[10]+= f2.z*w; acc[11]+= f2.w*w;
            acc[12]+= f3.x*w; acc[13]+= f3.y*w; acc[14]+= f3.z*w; acc[15]+= f3.w*w;
        }
        #pragma unroll
        for (int i = 0; i < 16; ++i) s_h1[tx][i] = fmaxf(acc[i], 0.f);
    }
    __syncthreads();
    {
        float bv = b2[tx];
        #pragma unroll
        for (int i = 0; i < 16; ++i) acc[i] = bv;
        for (int k = 0; k < HID; ++k) {
            float w = W2[k * HID + tx];
            float4 f0 = *(const float4*)&s_h1[k][0];
            float4 f1 = *(const float4*)&s_h1[k][4];
            float4 f2 = *(const float4*)&s_h1[k][8];
            float4 f3 = *(const float4*)&s_h1[k][12];
            acc[0] += f0.x*w; acc[1] += f0.y*w; acc[2] += f0.z*w; acc[3] += f0.w*w;
            acc[4] += f1.x*w; acc[5] += f1.y*w; acc[6] += f1.z*w; acc[7] += f1.w*w;
            acc[8] += f2.x*w; acc[9] += f2.y*w; acc[10]+= f2.z*w; acc[11]+= f2.w*w;
            acc[12]+= f3.x*w; acc[13]+= f3.y*w; acc[14]+= f3.z*w; acc[15]+= f3.w*w;
        }
        #pragma unroll
        for (int i = 0; i < 16; ++i) h[(n0 + i) * HID + tx] = acc[i];
    }
}

__global__ __launch_bounds__(256) void edge_gemm_fb_kernel(
    const float* __restrict__ h, const float* __restrict__ x,
    const int* __restrict__ edges, const int* __restrict__ etype,
    const float* __restrict__ edge_table,
    const float* __restrict__ We_l, const float* __restrict__ be_l,
    const float* __restrict__ Wx_l, const float* __restrict__ bx_l,
    float* __restrict__ agg_m, float* __restrict__ agg_x)
{
    __shared__ int s_src[TILE_E], s_dst[TILE_E];
    __shared__ float s_diff[TILE_E][3];
    __shared__ float s_tail[TILE_E][36];
    __shared__ float s_Af[TILE_E][36];
    __shared__ float s_Bf[33][HID];
    __shared__ float s_wx[HID];

    int e0 = blockIdx.x * TILE_E;
    int tx = threadIdx.x;
    int tf = tx & 15;
    int te = tx >> 4;

    if (tx < TILE_E) {
        int s = edges[e0 + tx];
        int d = edges[NE + e0 + tx];
        s_src[tx] = s; s_dst[tx] = d;
        float dx = x[s * 3 + 0] - x[d * 3 + 0];
        float dy = x[s * 3 + 1] - x[d * 3 + 1];
        float dz = x[s * 3 + 2] - x[d * 3 + 2];
        s_diff[tx][0] = dx; s_diff[tx][1] = dy; s_diff[tx][2] = dz;
        s_tail[tx][0] = dx * dx + dy * dy + dz * dz;
        int et = etype[e0 + tx];
        #pragma unroll
        for (int j = 0; j < 32; ++j) s_tail[tx][1 + j] = edge_table[et * 32 + j];
    }
    if (tx < HID) s_wx[tx] = Wx_l[tx];
    __syncthreads();

    float acc[4][8];
    #pragma unroll
    for (int i = 0; i < 4; ++i)
        #pragma unroll
        for (int j = 0; j < 8; ++j) acc[i][j] = 0.f;

    for (int t = 0; t < 9; ++t) {
        int k0 = t * 32;
        int klen = (t == 8) ? 33 : 32;
        __syncthreads();
        if (t < 8) {
            const bool use_src = (t < 4);
            int kbase = (t & 3) * 32;
            for (int q4 = tx; q4 < TILE_E * 8; q4 += 256) {
                int e = q4 >> 3, q = q4 & 7;
                int row = use_src ? s_src[e] : s_dst[e];
                float4 v = *(const float4*)&h[row * HID + kbase + q * 4];
                *(float4*)&s_Af[e][q * 4] = v;
            }
        }
        for (int q4 = tx; q4 < klen * 32; q4 += 256) {
            int kk = q4 >> 5, c4 = q4 & 31;
            float4 v = *(const float4*)&We_l[(k0 + kk) * HID + c4 * 4];
            *(float4*)&s_Bf[kk][c4 * 4] = v;
        }
        __syncthreads();
        const float (*Asrc)[36] = (t == 8) ? (const float (*)[36])s_tail
                                           : (const float (*)[36])s_Af;
        for (int kk = 0; kk < klen; ++kk) {
            float a0 = Asrc[te * 4 + 0][kk];
            float a1 = Asrc[te * 4 + 1][kk];
            float a2 = Asrc[te * 4 + 2][kk];
            float a3 = Asrc[te * 4 + 3][kk];
            float4 bv0 = *(const float4*)&s_Bf[kk][tf * 8];
            float4 bv1 = *(const float4*)&s_Bf[kk][tf * 8 + 4];
            float b[8] = {bv0.x, bv0.y, bv0.z, bv0.w, bv1.x, bv1.y, bv1.z, bv1.w};
            #pragma unroll
            for (int j = 0; j < 8; ++j) {
                acc[0][j] += a0 * b[j];
                acc[1][j] += a1 * b[j];
                acc[2][j] += a2 * b[j];
                acc[3][j] += a3 * b[j];
            }
        }
    }

    float wsum[4];
    #pragma unroll
    for (int i = 0; i < 4; ++i) {
        float p = 0.f;
        #pragma unroll
        for (int j = 0; j < 8; ++j) {
            int f = tf * 8 + j;
            float v = acc[i][j] + be_l[f];
            float m = silu(v);
            acc[i][j] = m;
            p += m * s_wx[f];
        }
        wsum[i] = p;
    }
    #pragma unroll
    for (int off = 1; off < 16; off <<= 1) {
        #pragma unroll
        for (int i = 0; i < 4; ++i) wsum[i] += __shfl_xor(wsum[i], off);
    }
    float bxv = bx_l[0];
    if (tf < 3) {
        #pragma unroll
        for (int i = 0; i < 4; ++i) {
            int e = te * 4 + i;
            float w2 = wsum[i] + bxv;
            atomicAdd(&agg_x[s_dst[e] * 3 + tf], s_diff[e][tf] * w2);
        }
    }
    #pragma unroll
    for (int i = 0; i < 4; ++i) {
        int d = s_dst[te * 4 + i];
        #pragma unroll
        for (int j = 0; j < 8; ++j)
            atomicAdd(&agg_m[d * HID + tf * 8 + j], acc[i][j]);
    }
}

__global__ __launch_bounds__(128) void node_update_fb_kernel(
    float* __restrict__ h, float* __restrict__ x,
    const float* __restrict__ agg_m, const float* __restrict__ agg_x,
    const float* __restrict__ cnt,
    const float* __restrict__ Wh_l, const float* __restrict__ bh_l)
{
    __shared__ float s_in[256][20];
    int n0 = blockIdx.x * 16;
    int tx = threadIdx.x;
    for (int idx = tx; idx < 16 * HID; idx += 128) {
        int i = idx >> 7, k = idx & 127;
        s_in[k][i] = h[(n0 + i) * HID + k];
    }
    for (int idx = tx; idx < 16 * HID; idx += 128) {
        int i = idx >> 7, k = idx & 127;
        s_in[HID + k][i] = agg_m[(n0 + i) * HID + k];
    }
    __syncthreads();
    float acc[16];
    float bv = bh_l[tx];
    #pragma unroll
    for (int i = 0; i < 16; ++i) acc[i] = bv;
    for (int k = 0; k < 256; ++k) {
        float w = Wh_l[k * HID + tx];
        float4 f0 = *(const float4*)&s_in[k][0];
        float4 f1 = *(const float4*)&s_in[k][4];
        float4 f2 = *(const float4*)&s_in[k][8];
        float4 f3 = *(const float4*)&s_in[k][12];
        acc[0] += f0.x*w; acc[1] += f0.y*w; acc[2] += f0.z*w; acc[3] += f0.w*w;
        acc[4] += f1.x*w; acc[5] += f1.y*w; acc[6] += f1.z*w; acc[7] += f1.w*w;
        acc[8] += f2.x*w; acc[9] += f2.y*w; acc[10]+= f2.z*w; acc[11]+= f2.w*w;
        acc[12]+= f3.x*w; acc[13]+= f3.y*w; acc[14]+= f3.z*w; acc[15]+= f3.w*w;
    }
    #pragma unroll
    for (int i = 0; i < 16; ++i) {
        float v = acc[i];
        h[(n0 + i) * HID + tx] = s_in[tx][i] + silu(v);
    }
    if (tx < 48) {
        int i = tx / 3, c = tx % 3;
        int n = n0 + i;
        x[n * 3 + c] += agg_x[n * 3 + c] / (cnt[n] + 1.f);
    }
}

__global__ __launch_bounds__(64) void final_fb_kernel(
    const float* __restrict__ h, const float* __restrict__ x,
    const int* __restrict__ gmask,
    const float* __restrict__ W, const float* __restrict__ b,
    float* __restrict__ out)
{
    __shared__ float s_h[8][HID];
    int n0 = blockIdx.x * 8;
    int tx = threadIdx.x;
    for (int idx = tx; idx < 8 * HID; idx += 64) {
        int i = idx >> 7, k = idx & 127;
        s_h[i][k] = h[(n0 + i) * HID + k];
    }
    __syncthreads();
    float acc[8];
    float bv = b[tx];
    #pragma unroll
    for (int i = 0; i < 8; ++i) acc[i] = bv;
    for (int k = 0; k < HID; ++k) {
        float w = W[k * IN_DIM + tx];
        #pragma unroll
        for (int i = 0; i < 8; ++i) acc[i] += s_h[i][k] * w;
    }
    #pragma unroll
    for (int i = 0; i < 8; ++i) {
        int n = n0 + i;
        out[n * IN_DIM + tx] = gmask[n] ? acc[i] : 0.f;
    }
    if (tx < 24) {
        int i = tx / 3, c = tx % 3;
        int n = n0 + i;
        out[NN * IN_DIM + n * 3 + c] = gmask[n] ? x[n * 3 + c] : 0.f;
    }
}

extern "C" void kernel_launch(void* const* d_in, const int* in_sizes, int n_in,
                              void* d_out, int out_size, void* d_ws, size_t ws_size,
                              hipStream_t stream) {
    const float* H_t   = (const float*)d_in[0];
    const float* X_t   = (const float*)d_in[1];
    const float* cond  = (const float*)d_in[2];
    const float* t_in  = (const float*)d_in[3];
    const int*   edges = (const int*)d_in[4];
    const int*   etype = (const int*)d_in[5];
    const int*   gmask = (const int*)d_in[6];
    const float* W0 = (const float*)d_in[8];
    const float* b0 = (const float*)d_in[9];
    const float* W1 = (const float*)d_in[10];
    const float* b1 = (const float*)d_in[11];
    const float* W2 = (const float*)d_in[12];
    const float* b2 = (const float*)d_in[13];
    const float* edge_table = (const float*)d_in[14];
    const float* We = (const float*)d_in[15];
    const float* be = (const float*)d_in[16];
    const float* Wx = (const float*)d_in[17];
    const float* bx = (const float*)d_in[18];
    const float* Wh = (const float*)d_in[19];
    const float* bh = (const float*)d_in[20];
    const float* h2i_W = (const float*)d_in[21];
    const float* h2i_b = (const float*)d_in[22];

    char* p = (char*)d_ws;
    float* h = (float*)p;           p += (size_t)NN * HID * 4;
    u16* h_bf = (u16*)p;            p += (size_t)NN * HID * 2;
    float* xa = (float*)p;          p += (size_t)NN * 3 * 4;
    float* xb = (float*)p;          p += (size_t)NN * 3 * 4;
    u16* Ca_s = (u16*)p;            p += (size_t)NN * 128 * 2;
    u16* Ca_d = (u16*)p;            p += (size_t)NN * 128 * 2;
    u16* Cb_s = (u16*)p;            p += (size_t)NN * 128 * 2;
    u16* Cb_d = (u16*)p;            p += (size_t)NN * 128 * 2;
    u16* Bpack = (u16*)p;           p += (size_t)PACK_TOT * 2;
    float* tv = (float*)p;          p += (size_t)768 * 4;
    float* wed2 = (float*)p;        p += (size_t)384 * 4;
    int* row_start = (int*)p;       p += (size_t)(NN + 4) * 4;
    int* deg = (int*)p;             p += (size_t)NN * 4;
    int* head = (int*)p;            p += (size_t)NN * 4;
    int* bsum = (int*)p;            p += (size_t)128 * 4;
    int* src_s = (int*)p;           p += (size_t)NE * 4;
    size_t need = (size_t)(p - (char*)d_ws);

    if (ws_size >= need) {
        prep_kernel<<<(PREP_TOT + 255) / 256, 256, 0, stream>>>(
            We, W0, W1, W2, Wh, h2i_W, edge_table, be, Bpack, tv, wed2, deg);
        hist_kernel<<<256, 256, 0, stream>>>(X_t, edges, xa, deg);
        scan1_kernel<<<SCB, 256, 0, stream>>>(deg, row_start, bsum);
        scan2_kernel<<<1, 128, 0, stream>>>(bsum, row_start);
        scan3_kernel<<<SCB, 256, 0, stream>>>(row_start, bsum, head);
        scatter_kernel<<<256, 256, 0, stream>>>(edges, etype, head, src_s);
        node_mlp_mfma_kernel<<<NB64, 256, 0, stream>>>(
            H_t, cond, t_in,
            Bpack + OFF_W0, b0, Bpack + OFF_W1, b1, Bpack + OFF_W2, b2,
            Bpack + OFF_WE, Ca_s, Ca_d,
            h, h_bf);
        for (int l = 0; l < 3; ++l) {
            const float* xin = (l & 1) ? xb : xa;
            float* xout = (l & 1) ? xa : xb;
            const u16* cs_in = (l & 1) ? Cb_s : Ca_s;
            const u16* cd_in = (l & 1) ? Cb_d : Ca_d;
            u16* cs_out = (l & 1) ? Ca_s : Cb_s;
            u16* cd_out = (l & 1) ? Ca_d : Cb_d;
            int mode = (l == 2) ? 1 : 0;
            const u16* Wnext = mode ? (Bpack + OFF_H2I)
                                    : (Bpack + OFF_WE + (size_t)(l + 1) * 40960);
            node_fused_kernel<<<NN / NUB, 512, 0, stream>>>(
                h, h_bf, xin, xout, cs_in, cd_in, cs_out, cd_out,
                Wnext, h2i_b, gmask, (float*)d_out,
                src_s, row_start,
                tv + (size_t)l * 256, wed2 + (size_t)l * 128,
                Wx + l * HID, bx + l,
                Bpack + OFF_WH + (size_t)l * 32768, bh + l * HID,
                mode);
        }
    } else {
        // fallback: scalar atomic path (~21 MB)
        float* ws    = (float*)d_ws;
        float* fh    = ws;
        float* fx    = fh + NN * HID;
        float* cnt   = fx + NN * 3;
        float* fagg_m = cnt + NN;
        float* fagg_x = fagg_m + NN * HID;

        hipMemsetAsync(cnt, 0, NN * sizeof(float), stream);
        init_fb_kernel<<<256, 256, 0, stream>>>(X_t, edges, fx, cnt);
        node_mlp_kernel<<<NN / 16, 128, 0, stream>>>(H_t, cond, t_in,
                                                     W0, b0, W1, b1, W2, b2, fh);
        for (int l = 0; l < 3; ++l) {
            hipMemsetAsync(fagg_m, 0, (size_t)NN * 131 * sizeof(float), stream);
            edge_gemm_fb_kernel<<<NE / TILE_E, 256, 0, stream>>>(
                fh, fx, edges, etype, edge_table,
                We + (size_t)l * DE * HID, be + l * HID,
                Wx + l * HID, bx + l, fagg_m, fagg_x);
            node_update_fb_kernel<<<NN / 16, 128, 0, stream>>>(
                fh, fx, fagg_m, fagg_x, cnt,
                Wh + (size_t)l * 256 * HID, bh + l * HID);
        }
        final_fb_kernel<<<NN / 8, 64, 0, stream>>>(fh, fx, gmask, h2i_W, h2i_b, (float*)d_out);
    }
}